// Round 2
// baseline (417.175 us; speedup 1.0000x reference)
//
#include <hip/hip_runtime.h>
#include <hip/hip_bf16.h>
#include <math.h>

typedef __hip_bfloat16 bf16;
typedef __attribute__((ext_vector_type(8))) short short8;
typedef __attribute__((ext_vector_type(4))) float floatx4;

#define B_   2
#define S_   2048
#define D_   1024
#define H_   16
#define DH_  64
#define BS_  4096   // B_*S_
#define D3_  3072   // 3*D_
#define DF_  4096   // 4*D_

__device__ __forceinline__ float tof(float v) { return v; }
__device__ __forceinline__ float tof(bf16 v) { return __bfloat162float(v); }

// async global->LDS 16B copy: lane's data lands at readfirstlane(lds)+lane*16
__device__ __forceinline__ void gload_lds16(const bf16* g, bf16* l) {
  __builtin_amdgcn_global_load_lds(
      (const __attribute__((address_space(1))) unsigned int*)g,
      (__attribute__((address_space(3))) unsigned int*)l, 16, 0, 0);
}

#define VMCNT(n) asm volatile("s_waitcnt vmcnt(" #n ")" ::: "memory")

// ---------------------------------------------------------------------------
// fp32 -> bf16 weight conversion (vectorized x4)
// ---------------------------------------------------------------------------
__global__ __launch_bounds__(256) void cvt_f32_bf16(
    const float* __restrict__ in, bf16* __restrict__ out, int n4) {
  int i = blockIdx.x * 256 + threadIdx.x;
  if (i >= n4) return;
  float4 v = ((const float4*)in)[i];
  bf16 o[4] = {__float2bfloat16(v.x), __float2bfloat16(v.y),
               __float2bfloat16(v.z), __float2bfloat16(v.w)};
  ((ulong1*)out)[i] = *(ulong1*)o;
}

// ---------------------------------------------------------------------------
// Fused convert: w_qkv fp32->bf16 with ROW PERMUTE n=d*48+z*16+h -> n2=
// z*1024+h*64+d (so QKV gemm emits [b,s][z,h,d]), plus plain convert of w_o.
// ---------------------------------------------------------------------------
__global__ __launch_bounds__(256) void cvt_qkv_o(
    const float* __restrict__ wqkv, const float* __restrict__ wo,
    bf16* __restrict__ wqb, bf16* __restrict__ wob) {
  const int g = blockIdx.x * 256 + threadIdx.x;  // 4-el group
  if (g < 786432) {                              // 3072*1024/4 : permute+cvt
    const int n2 = g >> 8;                       // dest row (z,h,d)
    const int col = (g & 255) * 4;
    const int z = n2 >> 10, hh = (n2 >> 6) & 15, d = n2 & 63;
    const int n = d * 48 + z * 16 + hh;          // src row
    float4 v = *(const float4*)(wqkv + (size_t)n * 1024 + col);
    bf16 o[4] = {__float2bfloat16(v.x), __float2bfloat16(v.y),
                 __float2bfloat16(v.z), __float2bfloat16(v.w)};
    *(unsigned long long*)(wqb + (size_t)n2 * 1024 + col) =
        *(unsigned long long*)o;
  } else {
    const int g2 = g - 786432;                   // w_o: 1024*1024/4 groups
    float4 v = ((const float4*)wo)[g2];
    bf16 o[4] = {__float2bfloat16(v.x), __float2bfloat16(v.y),
                 __float2bfloat16(v.z), __float2bfloat16(v.w)};
    ((unsigned long long*)wob)[g2] = *(unsigned long long*)o;
  }
}

// ---------------------------------------------------------------------------
// LayerNorm; FUSE: residual add st*a+s1t*skip first. INIT: also pre-init the
// FFN2 output with the linear part of its epilogue:
//   oinit = cs*xv + cb*b2[col]   (cs=SQRT_1MT, cb=SQRT_TAU*w2_scale)
// so the split-K FFN2 gemm can pure-atomicAdd into it.
// ---------------------------------------------------------------------------
template <bool FUSE, bool INIT, typename TA, typename TS>
__global__ __launch_bounds__(256) void resid_ln_kernel(
    const TA* __restrict__ a, const TS* __restrict__ skip,
    const float* __restrict__ w, const float* __restrict__ bias,
    bf16* __restrict__ hout, float st, float s1t,
    float* __restrict__ oinit, const float* __restrict__ b2,
    float cb, float cs) {
  const int row = blockIdx.x;
  const int tid = threadIdx.x;
  const int base = tid * 4;
  const size_t roff = (size_t)row * D_;

  float xv[4];
#pragma unroll
  for (int i = 0; i < 4; i++) {
    float v = tof(a[roff + base + i]);
    if (FUSE) v = st * v + s1t * tof(skip[roff + base + i]);
    xv[i] = v;
  }
  if (INIT) {
#pragma unroll
    for (int i = 0; i < 4; i++)
      oinit[roff + base + i] = cs * xv[i] + cb * b2[base + i];
  }

  float ls = 0.f, lq = 0.f;
#pragma unroll
  for (int i = 0; i < 4; i++) { ls += xv[i]; lq += xv[i] * xv[i]; }

  __shared__ float ssum[256];
  __shared__ float ssq[256];
  ssum[tid] = ls; ssq[tid] = lq;
  __syncthreads();
  for (int off = 128; off > 0; off >>= 1) {
    if (tid < off) { ssum[tid] += ssum[tid + off]; ssq[tid] += ssq[tid + off]; }
    __syncthreads();
  }
  const float mean = ssum[0] * (1.0f / D_);
  const float var  = ssq[0] * (1.0f / D_) - mean * mean;
  const float rstd = rsqrtf(var + 1e-5f);

#pragma unroll
  for (int i = 0; i < 4; i++) {
    float v = (xv[i] - mean) * rstd * w[base + i] + bias[base + i];
    hout[roff + base + i] = __float2bfloat16(v);
  }
}

// ---------------------------------------------------------------------------
// 256x256 8-phase MFMA GEMM (T1+T2+T3+T4+T5). 512 thr = 8 waves (2Mx4N),
// BK=64, LDS 128 KiB. NSPLIT>1: split-K decode, epilogue = atomicAdd fp32.
// EPI: 0 = scale,store bf16; 1 = bias+GELU(tanh),store bf16;
//      2 = dual-scale (Q columns bn<1024 use st), store bf16;
//      3 = atomicAdd(C, v*scale) fp32.
// K param = per-split extent; row stride lda = K*NSPLIT.
// ---------------------------------------------------------------------------
template <int EPI, int NSPLIT, typename TC>
__global__ __launch_bounds__(512, 2) void gemm_mfma256(
    const bf16* __restrict__ A, const bf16* __restrict__ Bw,
    TC* __restrict__ C, int M, int N, int K, float scale,
    const float* __restrict__ bias, float st) {
  __shared__ __align__(16) bf16 As[2][2][128][64];  // [buf][chunk h][row][k]
  __shared__ __align__(16) bf16 Bs[2][2][128][64];  // [buf][chunk bh][row][k]

  const int tid = threadIdx.x;
  const int lane = tid & 63;
  const int w = tid >> 6;          // 0..7
  const int wm = w >> 2;           // 0..1  (M half)
  const int wn = w & 3;            // 0..3  (N quarter)
  const int quad = lane >> 4;
  const int l16 = lane & 15;

  // T1: XCD-aware block swizzle (nwg % 8 == 0 at every call site)
  const int nbx = N >> 8;
  const int nwg = nbx * (M >> 8) * NSPLIT;
  int bid = blockIdx.x;
  bid = (bid & 7) * (nwg >> 3) + (bid >> 3);
  const int split = bid & (NSPLIT - 1);
  const int tile = bid / NSPLIT;
  const size_t bm = (size_t)(tile / nbx) * 256;
  const size_t bn = (size_t)(tile % nbx) * 256;
  const int lda = K * NSPLIT;
  const int koff = split * K;

  // staging: chunk c in {0:A.h0, 1:B.bh0, 2:A.h1, 3:B.bh1}, 2 x 16B/thread
  const bf16* gsrc[4][2];
  bf16* ldsp[4][2];
#pragma unroll
  for (int i = 0; i < 2; i++) {
    const int G = tid + i * 512;               // granule 0..1023 within chunk
    const int cr = G >> 3;                     // chunk row 0..127
    const int gs8 = ((G & 7) ^ (cr & 7)) * 8;  // pre-swizzled source column
    const int ra = ((cr >> 6) << 7) + (cr & 63);       // A: + h*64
    const int rb = ((cr >> 5) << 6) + (cr & 31);       // B: + bh*32
    gsrc[0][i] = A  + (bm + ra) * (size_t)lda + koff + gs8;
    gsrc[2][i] = A  + (bm + ra + 64) * (size_t)lda + koff + gs8;
    gsrc[1][i] = Bw + (bn + rb) * (size_t)lda + koff + gs8;
    gsrc[3][i] = Bw + (bn + rb + 32) * (size_t)lda + koff + gs8;
    ldsp[0][i] = &As[0][0][0][0] + G * 8;
    ldsp[2][i] = &As[0][1][0][0] + G * 8;
    ldsp[1][i] = &Bs[0][0][0][0] + G * 8;
    ldsp[3][i] = &Bs[0][1][0][0] + G * 8;
  }

  auto STAGE = [&](int c, int tn) {
    const int boff = (tn & 1) * 16384;  // els between buf0/buf1
    gload_lds16(gsrc[c][0] + (size_t)tn * 64, ldsp[c][0] + boff);
    gload_lds16(gsrc[c][1] + (size_t)tn * 64, ldsp[c][1] + boff);
  };

  // swizzled k-granule offsets for ds_read
  const int ksw0 = (quad ^ (l16 & 7)) * 8;
  const int ksw1 = ((4 + quad) ^ (l16 & 7)) * 8;

  floatx4 acc[8][4];
#pragma unroll
  for (int i = 0; i < 8; i++)
#pragma unroll
    for (int j = 0; j < 4; j++) acc[i][j] = {0.f, 0.f, 0.f, 0.f};

  short8 af[4][2], bv[2][2];

  auto READ_A = [&](int b, int h) {
#pragma unroll
    for (int mf = 0; mf < 4; mf++) {
      const bf16* p = &As[b][h][wm * 64 + mf * 16 + l16][0];
      af[mf][0] = *(const short8*)(p + ksw0);
      af[mf][1] = *(const short8*)(p + ksw1);
    }
  };
  auto READ_B = [&](int b, int bh) {
#pragma unroll
    for (int nf = 0; nf < 2; nf++) {
      const bf16* p = &Bs[b][bh][wn * 32 + nf * 16 + l16][0];
      bv[nf][0] = *(const short8*)(p + ksw0);
      bv[nf][1] = *(const short8*)(p + ksw1);
    }
  };
  auto MFMA16 = [&](int mb, int nb) {
#pragma unroll
    for (int mf = 0; mf < 4; mf++)
#pragma unroll
      for (int nf = 0; nf < 2; nf++) {
        floatx4 c = acc[mb + mf][nb + nf];
        c = __builtin_amdgcn_mfma_f32_16x16x32_bf16(af[mf][0], bv[nf][0], c, 0, 0, 0);
        c = __builtin_amdgcn_mfma_f32_16x16x32_bf16(af[mf][1], bv[nf][1], c, 0, 0, 0);
        acc[mb + mf][nb + nf] = c;
      }
  };

  // prologue: full tile 0
  STAGE(0, 0); STAGE(1, 0); STAGE(2, 0); STAGE(3, 0);
  VMCNT(4);
  __builtin_amdgcn_s_barrier();
  __builtin_amdgcn_sched_barrier(0);

  const int NT = K >> 6;
#pragma unroll 1
  for (int t = 0; t < NT; t++) {
    const int b = t & 1;
    const bool nl = (t + 1 < NT);
    // ---- phase 1: Q00 ----
    READ_A(b, 0);
    READ_B(b, 0);
    if (nl) STAGE(0, t + 1);
    __builtin_amdgcn_s_barrier();
    __builtin_amdgcn_sched_barrier(0);
    __builtin_amdgcn_s_setprio(1);
    MFMA16(0, 0);
    __builtin_amdgcn_s_setprio(0);
    if (nl) { VMCNT(2); } else { VMCNT(0); }
    __builtin_amdgcn_s_barrier();
    __builtin_amdgcn_sched_barrier(0);
    // ---- phase 2: Q01 ----
    READ_B(b, 1);
    if (nl) STAGE(1, t + 1);
    __builtin_amdgcn_s_barrier();
    __builtin_amdgcn_sched_barrier(0);
    __builtin_amdgcn_s_setprio(1);
    MFMA16(0, 2);
    __builtin_amdgcn_s_setprio(0);
    __builtin_amdgcn_s_barrier();
    __builtin_amdgcn_sched_barrier(0);
    // ---- phase 3: Q11 ----
    READ_A(b, 1);
    if (nl) STAGE(2, t + 1);
    __builtin_amdgcn_s_barrier();
    __builtin_amdgcn_sched_barrier(0);
    __builtin_amdgcn_s_setprio(1);
    MFMA16(4, 2);
    __builtin_amdgcn_s_setprio(0);
    __builtin_amdgcn_s_barrier();
    __builtin_amdgcn_sched_barrier(0);
    // ---- phase 4: Q10 ----
    READ_B(b, 0);
    if (nl) STAGE(3, t + 1);
    __builtin_amdgcn_s_barrier();
    __builtin_amdgcn_sched_barrier(0);
    __builtin_amdgcn_s_setprio(1);
    MFMA16(4, 0);
    __builtin_amdgcn_s_setprio(0);
    if (nl) { VMCNT(4); } else { VMCNT(0); }
    __builtin_amdgcn_s_barrier();
    __builtin_amdgcn_sched_barrier(0);
  }

  // epilogue
  float sc_eff = scale;
  if (EPI == 2) sc_eff = (bn < 1024) ? st : scale;  // Q columns pre-scaled
  float bias4[4];
  if (EPI == 1) {
#pragma unroll
    for (int j = 0; j < 4; j++) bias4[j] = bias[bn + wn * 64 + j * 16 + l16];
  }
#pragma unroll
  for (int mi = 0; mi < 8; mi++) {
    const size_t r0 = bm + wm * 128 + (mi >> 2) * 64 + (mi & 3) * 16 + quad * 4;
#pragma unroll
    for (int r = 0; r < 4; r++) {
      const size_t rowoff = (r0 + r) * (size_t)N + bn + wn * 64 + l16;
#pragma unroll
      for (int j = 0; j < 4; j++) {
        float v = acc[mi][j][r];
        if (EPI == 0 || EPI == 2) {
          ((bf16*)C)[rowoff + j * 16] = __float2bfloat16(v * sc_eff);
        } else if (EPI == 1) {
          // GELU (tanh form) via raw v_exp_f32 / v_rcp_f32
          float u = (v + bias4[j]) * scale;
          float tt = u * (0.7978845608f + 0.0356774081f * u * u);
          float e = __builtin_amdgcn_exp2f(tt * 2.8853900818f);  // exp(2*tt)
          float th = 1.0f - 2.0f * __builtin_amdgcn_rcpf(e + 1.0f);
          ((bf16*)C)[rowoff + j * 16] =
              __float2bfloat16(0.5f * u * (1.0f + th) * st);
        } else {
          atomicAdd((float*)C + rowoff + j * 16, v * scale);
        }
      }
    }
  }
}

// ---------------------------------------------------------------------------
// MFMA flash attention, S^T scheme, 512 threads = 8 waves, QT=128, KT=64.
// FIXED-MAX softmax: Q is pre-scaled by MM_SCALE*LOG2E in the QKV gemm, and
// unit-scaling bounds |score*log2e| << 1, so P = exp2(S^T) directly — no
// online max, no rescale, no per-tile l-reduce (per-lane partial, reduced
// once at the end). Ps is [128][64] with XOR swizzle (both sides, LDS-only).
// ---------------------------------------------------------------------------
__global__ __launch_bounds__(512) void flash_attn_mfma(
    const bf16* __restrict__ qkv, bf16* __restrict__ att, float out_scale) {
  const int qb = blockIdx.x * 128;
  const int h = blockIdx.y, b = blockIdx.z;
  const int tid = threadIdx.x;
  const int lane = tid & 63;
  const int wv = tid >> 6;           // 0..7
  const int quad = lane >> 4;
  const int l16 = lane & 15;

  __shared__ __align__(16) bf16 Ks[2][64][72];
  __shared__ __align__(16) bf16 Vt[2][64][72];  // Vt[d][j] = V[j][d]
  __shared__ __align__(16) bf16 Ps[128][64];    // P [query][key], XOR-swizzled

  const bf16* Qb_ = qkv + (size_t)b * S_ * D3_ + h * DH_;
  const bf16* Kb_ = Qb_ + 1024;
  const bf16* Vb_ = Qb_ + 2048;

  // Q as B-operand frag: queries qb + wv*16 + l16 (already scaled)
  short8 bq0, bq1;
  {
    const bf16* qrow = Qb_ + (size_t)(qb + wv * 16 + l16) * D3_ + quad * 8;
    bq0 = *(const short8*)(qrow);
    bq1 = *(const short8*)(qrow + 32);
  }

  float l_part = 0.f;
  floatx4 o[4];
#pragma unroll
  for (int fd = 0; fd < 4; fd++) o[fd] = {0.f, 0.f, 0.f, 0.f};

  // P LDS addressing (per-wave private rows, XOR swizzle on byte bit 4-6)
  const int prow = wv * 16 + l16;
  const int psw = (prow & 7) << 4;
  char* pbase = (char*)&Ps[0][0] + prow * 128;

  // staging (512 threads): K chunk = 1 x 16B; V = 1 uint4 -> 8 b16 scatters
  const int kr = tid >> 3, ko = (tid & 7) * 8;
  const int vj = tid & 63, vd = (tid >> 6) * 8;

  // prologue: prefetch tile 0 into registers
  uint4 kreg = *(const uint4*)(Kb_ + (size_t)kr * D3_ + ko);
  uint4 vreg = *(const uint4*)(Vb_ + (size_t)vj * D3_ + vd);

  int cur = 0;
  for (int t = 0; t < S_ / 64; t++) {
    // commit prefetched tile into buf[cur]
    *(uint4*)&Ks[cur][kr][ko] = kreg;
    {
      bf16 tmp[8];
      *(uint4*)tmp = vreg;
#pragma unroll
      for (int e = 0; e < 8; e++) Vt[cur][vd + e][vj] = tmp[e];
    }
    __syncthreads();

    // prefetch tile t+1 (clamped; redundant reload on last iter)
    {
      const int tn = (t + 1 < S_ / 64) ? t + 1 : t;
      kreg = *(const uint4*)(Kb_ + (size_t)(tn * 64 + kr) * D3_ + ko);
      vreg = *(const uint4*)(Vb_ + (size_t)(tn * 64 + vj) * D3_ + vd);
    }

    // S^T = K Q^T : lane holds keys fk*16 + quad*4 + r for query wv*16+l16
    float st[4][4];
    __builtin_amdgcn_s_setprio(1);
#pragma unroll
    for (int fk = 0; fk < 4; fk++) {
      short8 ak0 = *(const short8*)&Ks[cur][fk * 16 + l16][quad * 8];
      short8 ak1 = *(const short8*)&Ks[cur][fk * 16 + l16][32 + quad * 8];
      floatx4 acc = {0.f, 0.f, 0.f, 0.f};
      acc = __builtin_amdgcn_mfma_f32_16x16x32_bf16(ak0, bq0, acc, 0, 0, 0);
      acc = __builtin_amdgcn_mfma_f32_16x16x32_bf16(ak1, bq1, acc, 0, 0, 0);
#pragma unroll
      for (int r = 0; r < 4; r++) st[fk][r] = acc[r];
    }
    __builtin_amdgcn_s_setprio(0);

    // P = exp2(S^T) (fixed max = 0), per-lane l partial
#pragma unroll
    for (int fk = 0; fk < 4; fk++) {
      bf16 pk[4];
#pragma unroll
      for (int r = 0; r < 4; r++) {
        const float p = exp2f(st[fk][r]);
        l_part += p;
        pk[r] = __float2bfloat16(p);
      }
      *(uint2*)(pbase + ((fk * 32 + quad * 8) ^ psw)) = *(uint2*)pk;
    }

    // O += P V
    short8 ap0 = *(const short8*)(pbase + ((quad * 16) ^ psw));
    short8 ap1 = *(const short8*)(pbase + ((64 + quad * 16) ^ psw));
    __builtin_amdgcn_s_setprio(1);
#pragma unroll
    for (int fd = 0; fd < 4; fd++) {
      short8 bv0 = *(const short8*)&Vt[cur][fd * 16 + l16][quad * 8];
      short8 bv1 = *(const short8*)&Vt[cur][fd * 16 + l16][32 + quad * 8];
      o[fd] = __builtin_amdgcn_mfma_f32_16x16x32_bf16(ap0, bv0, o[fd], 0, 0, 0);
      o[fd] = __builtin_amdgcn_mfma_f32_16x16x32_bf16(ap1, bv1, o[fd], 0, 0, 0);
    }
    __builtin_amdgcn_s_setprio(0);

    cur ^= 1;
  }

  // final l: sum quads (butterfly), then pick query quad*4+r's value
  l_part += __shfl_xor(l_part, 16);
  l_part += __shfl_xor(l_part, 32);
#pragma unroll
  for (int r = 0; r < 4; r++) {
    const float lq = __shfl(l_part, quad * 4 + r, 64);
    const float sc = out_scale / lq;
    const size_t base =
        ((size_t)(b * S_ + qb + wv * 16 + quad * 4 + r)) * D_ + h * DH_;
#pragma unroll
    for (int fd = 0; fd < 4; fd++)
      att[base + fd * 16 + l16] = __float2bfloat16(o[fd][r] * sc);
  }
}

// ---------------------------------------------------------------------------
extern "C" void kernel_launch(void* const* d_in, const int* in_sizes, int n_in,
                              void* d_out, int out_size, void* d_ws, size_t ws_size,
                              hipStream_t stream) {
  const float* x     = (const float*)d_in[0];
  const float* w_qkv = (const float*)d_in[1];
  const float* w_o   = (const float*)d_in[2];
  const float* w1    = (const float*)d_in[3];
  const float* b1    = (const float*)d_in[4];
  const float* w2    = (const float*)d_in[5];
  const float* b2    = (const float*)d_in[6];
  const float* ln1w  = (const float*)d_in[7];
  const float* ln1b  = (const float*)d_in[8];
  const float* ln2w  = (const float*)d_in[9];
  const float* ln2b  = (const float*)d_in[10];
  float* out = (float*)d_out;
  bf16* ws  = (bf16*)d_ws;

  // workspace layout (bf16 els), liveness-audited, peak 29,360,128 els (58.7MB)
  bf16* h1        = ws;                 // [0,4.19M)      live LN1->QKV
  bf16* att       = ws;                 //                live flash->Oproj
  bf16* wqb       = ws + 4194304;       // [4.19,7.34M)   live cvt->QKV
  bf16* wob       = ws + 7340032;       // [7.34,8.39M)   live cvt->Oproj
  float* attn_f32 = (float*)(ws + 8388608);  // [8.39,16.78M) fp32 4.19M, memset->LN2
  bf16* qkv       = ws + 16777216;      // [16.78,29.36M) live QKV->flash
  bf16* w1b       = ws + 16777216;      // [16.78,20.97M) live cvt->FFN1 (qkv dead)
  bf16* w2b       = ws + 16777216;      // [16.78,20.97M) live cvt->FFN2 (w1b dead)
  bf16* h2        = ws + 20971520;      // [20.97,25.17M) live LN2->FFN1
  bf16* g         = ws;                 // [0,16.78M)     live FFN1->FFN2

  const float MM_SCALE   = (float)pow((double)S_ * S_ * DH_, -1.0 / 6.0);
  const float SM_SCALE   = (float)((double)S_ / sqrt(1.31 * 1.65));
  const float GELU_SCALE = (float)pow(0.588 * 0.675, -0.5);
  const float SQRT_TAU   = (float)sqrt(0.2);
  const float SQRT_1MT   = (float)sqrt(0.8);
  const float LOG2E      = 1.4426950408889634f;
  const float qkv_scale  = (float)pow((double)D_ * D3_, -0.25);
  const float o_scale    = (float)pow((double)D_ * D_, -0.25);
  const float w1_scale   = (float)pow((double)D_ * DF_, -0.25);
  const float w2_scale   = (float)pow((double)DF_ * D_, -0.25);

  // 0. zero the fp32 out-proj accumulator (overlaps with converts/LN1)
  hipMemsetAsync(attn_f32, 0, (size_t)BS_ * D_ * 4, stream);
  // 1. convert w_qkv (permuted) + w_o
  cvt_qkv_o<<<4096, 256, 0, stream>>>(w_qkv, w_o, wqb, wob);
  // 2. LN1
  resid_ln_kernel<false, false, float, float><<<BS_, 256, 0, stream>>>(
      x, nullptr, ln1w, ln1b, h1, 0.f, 0.f, nullptr, nullptr, 0.f, 0.f);
  // 3. QKV gemm -> head-major qkv (Q columns folded with MM_SCALE*LOG2E)
  gemm_mfma256<2, 1, bf16><<<dim3(192), 512, 0, stream>>>(
      h1, wqb, qkv, BS_, D3_, D_, qkv_scale, nullptr,
      qkv_scale * MM_SCALE * LOG2E);
  // 4. MFMA flash attention (fixed-max), reads qkv directly
  flash_attn_mfma<<<dim3(S_ / 128, H_, B_), 512, 0, stream>>>(
      qkv, att, SM_SCALE * MM_SCALE);
  // 5. out-proj: split-K=4 8-phase, atomicAdd into attn_f32 (256 blocks)
  gemm_mfma256<3, 4, float><<<dim3(256), 512, 0, stream>>>(
      att, wob, attn_f32, BS_, D_, D_ / 4, o_scale, nullptr, 0.f);
  // 6. residual + LN2; also pre-init d_out = SQRT_1MT*x2 + SQRT_TAU*w2s*b2
  resid_ln_kernel<true, true, float, float><<<BS_, 256, 0, stream>>>(
      attn_f32, x, ln2w, ln2b, h2, SQRT_TAU, SQRT_1MT,
      out, b2, SQRT_TAU * w2_scale, SQRT_1MT);
  // 6.5 convert w1; 7. FFN1 + GELU (256 blocks)
  cvt_f32_bf16<<<(DF_ * D_ / 4 + 255) / 256, 256, 0, stream>>>(w1, w1b, DF_ * D_ / 4);
  gemm_mfma256<1, 1, bf16><<<dim3(256), 512, 0, stream>>>(
      h2, w1b, g, BS_, DF_, D_, w1_scale, b1, GELU_SCALE);
  // 7.5 convert w2; 8. FFN2: split-K=4 8-phase, atomicAdd into d_out
  cvt_f32_bf16<<<(D_ * DF_ / 4 + 255) / 256, 256, 0, stream>>>(w2, w2b, D_ * DF_ / 4);
  gemm_mfma256<3, 4, float><<<dim3(256), 512, 0, stream>>>(
      g, w2b, out, BS_, D_, DF_ / 4, SQRT_TAU * w2_scale, nullptr, 0.f);
}

// Round 3
// 371.494 us; speedup vs baseline: 1.1230x; 1.1230x over previous
//
#include <hip/hip_runtime.h>
#include <hip/hip_bf16.h>
#include <math.h>

typedef __hip_bfloat16 bf16;
typedef __attribute__((ext_vector_type(8))) short short8;
typedef __attribute__((ext_vector_type(4))) float floatx4;

#define B_   2
#define S_   2048
#define D_   1024
#define H_   16
#define DH_  64
#define BS_  4096   // B_*S_
#define D3_  3072   // 3*D_
#define DF_  4096   // 4*D_

__device__ __forceinline__ float tof(float v) { return v; }
__device__ __forceinline__ float tof(bf16 v) { return __bfloat162float(v); }

// async global->LDS 16B copy: lane's data lands at readfirstlane(lds)+lane*16
__device__ __forceinline__ void gload_lds16(const bf16* g, bf16* l) {
  __builtin_amdgcn_global_load_lds(
      (const __attribute__((address_space(1))) unsigned int*)g,
      (__attribute__((address_space(3))) unsigned int*)l, 16, 0, 0);
}

#define VMCNT(n) asm volatile("s_waitcnt vmcnt(" #n ")" ::: "memory")

// ---------------------------------------------------------------------------
// fp32 -> bf16 weight conversion (vectorized x4)
// ---------------------------------------------------------------------------
__global__ __launch_bounds__(256) void cvt_f32_bf16(
    const float* __restrict__ in, bf16* __restrict__ out, int n4) {
  int i = blockIdx.x * 256 + threadIdx.x;
  if (i >= n4) return;
  float4 v = ((const float4*)in)[i];
  bf16 o[4] = {__float2bfloat16(v.x), __float2bfloat16(v.y),
               __float2bfloat16(v.z), __float2bfloat16(v.w)};
  ((ulong1*)out)[i] = *(ulong1*)o;
}

// ---------------------------------------------------------------------------
// Fused convert: w_qkv fp32->bf16 with ROW PERMUTE n=d*48+z*16+h -> n2=
// z*1024+h*64+d (so QKV gemm emits [b,s][z,h,d]), plus plain convert of w_o.
// ---------------------------------------------------------------------------
__global__ __launch_bounds__(256) void cvt_qkv_o(
    const float* __restrict__ wqkv, const float* __restrict__ wo,
    bf16* __restrict__ wqb, bf16* __restrict__ wob) {
  const int g = blockIdx.x * 256 + threadIdx.x;  // 4-el group
  if (g < 786432) {                              // 3072*1024/4 : permute+cvt
    const int n2 = g >> 8;                       // dest row (z,h,d)
    const int col = (g & 255) * 4;
    const int z = n2 >> 10, hh = (n2 >> 6) & 15, d = n2 & 63;
    const int n = d * 48 + z * 16 + hh;          // src row
    float4 v = *(const float4*)(wqkv + (size_t)n * 1024 + col);
    bf16 o[4] = {__float2bfloat16(v.x), __float2bfloat16(v.y),
                 __float2bfloat16(v.z), __float2bfloat16(v.w)};
    *(unsigned long long*)(wqb + (size_t)n2 * 1024 + col) =
        *(unsigned long long*)o;
  } else {
    const int g2 = g - 786432;                   // w_o: 1024*1024/4 groups
    float4 v = ((const float4*)wo)[g2];
    bf16 o[4] = {__float2bfloat16(v.x), __float2bfloat16(v.y),
                 __float2bfloat16(v.z), __float2bfloat16(v.w)};
    ((unsigned long long*)wob)[g2] = *(unsigned long long*)o;
  }
}

// ---------------------------------------------------------------------------
// LayerNorm. FUSE: xv = st*(a[i]+a2[i]) + s1t*skip[i]  (a,a2 = fp32 split-K
// partials of the out-proj, already o_scale'd). INIT: pre-init the FFN2
// output with the linear epilogue part: oinit = cs*xv + cb*b2[col].
// ---------------------------------------------------------------------------
template <bool FUSE, bool INIT, typename TA, typename TS>
__global__ __launch_bounds__(256) void resid_ln_kernel(
    const TA* __restrict__ a, const TA* __restrict__ a2,
    const TS* __restrict__ skip,
    const float* __restrict__ w, const float* __restrict__ bias,
    bf16* __restrict__ hout, float st, float s1t,
    float* __restrict__ oinit, const float* __restrict__ b2,
    float cb, float cs) {
  const int row = blockIdx.x;
  const int tid = threadIdx.x;
  const int base = tid * 4;
  const size_t roff = (size_t)row * D_;

  float xv[4];
#pragma unroll
  for (int i = 0; i < 4; i++) {
    float v = tof(a[roff + base + i]);
    if (FUSE) v = st * (v + tof(a2[roff + base + i]))
                  + s1t * tof(skip[roff + base + i]);
    xv[i] = v;
  }
  if (INIT) {
#pragma unroll
    for (int i = 0; i < 4; i++)
      oinit[roff + base + i] = cs * xv[i] + cb * b2[base + i];
  }

  float ls = 0.f, lq = 0.f;
#pragma unroll
  for (int i = 0; i < 4; i++) { ls += xv[i]; lq += xv[i] * xv[i]; }

  __shared__ float ssum[256];
  __shared__ float ssq[256];
  ssum[tid] = ls; ssq[tid] = lq;
  __syncthreads();
  for (int off = 128; off > 0; off >>= 1) {
    if (tid < off) { ssum[tid] += ssum[tid + off]; ssq[tid] += ssq[tid + off]; }
    __syncthreads();
  }
  const float mean = ssum[0] * (1.0f / D_);
  const float var  = ssq[0] * (1.0f / D_) - mean * mean;
  const float rstd = rsqrtf(var + 1e-5f);

#pragma unroll
  for (int i = 0; i < 4; i++) {
    float v = (xv[i] - mean) * rstd * w[base + i] + bias[base + i];
    hout[roff + base + i] = __float2bfloat16(v);
  }
}

// ---------------------------------------------------------------------------
// FFN2 split-K reduce: out += sc*(p0[i] + p1[i]); out was pre-init'd by LN2.
// Memory-bound: 50 MB total traffic.
// ---------------------------------------------------------------------------
__global__ __launch_bounds__(256) void reduce_ffn2(
    const bf16* __restrict__ p0, const bf16* __restrict__ p1,
    float* __restrict__ out, float sc) {
  const size_t i = ((size_t)blockIdx.x * 256 + threadIdx.x) * 8;
  short8 a = *(const short8*)(p0 + i);
  short8 b = *(const short8*)(p1 + i);
  bf16 t0[8], t1[8];
  *(short8*)t0 = a; *(short8*)t1 = b;
  float4 o0 = *(float4*)(out + i);
  float4 o1 = *(float4*)(out + i + 4);
#pragma unroll
  for (int e = 0; e < 4; e++) {
    ((float*)&o0)[e] += sc * (__bfloat162float(t0[e]) + __bfloat162float(t1[e]));
    ((float*)&o1)[e] += sc * (__bfloat162float(t0[e + 4]) + __bfloat162float(t1[e + 4]));
  }
  *(float4*)(out + i) = o0;
  *(float4*)(out + i + 4) = o1;
}

// ---------------------------------------------------------------------------
// 256x256 8-phase MFMA GEMM (T1+T2+T3+T4+T5). 512 thr = 8 waves (2Mx4N),
// BK=64, LDS 128 KiB. NSPLIT>1: split-K; partial stores (non-atomic).
// EPI: 0 = scale,store bf16; 1 = bias+GELU(tanh),store bf16;
//      2 = dual-scale (Q columns bn<1024 use st), store bf16;
//      3 = store fp32 partial v*scale at C + split*M*N;
//      4 = store bf16 partial (raw v) at C + split*M*N.
// K param = per-split extent; row stride lda = K*NSPLIT.
// ---------------------------------------------------------------------------
template <int EPI, int NSPLIT, typename TC>
__global__ __launch_bounds__(512, 2) void gemm_mfma256(
    const bf16* __restrict__ A, const bf16* __restrict__ Bw,
    TC* __restrict__ C, int M, int N, int K, float scale,
    const float* __restrict__ bias, float st) {
  __shared__ __align__(16) bf16 As[2][2][128][64];  // [buf][chunk h][row][k]
  __shared__ __align__(16) bf16 Bs[2][2][128][64];  // [buf][chunk bh][row][k]

  const int tid = threadIdx.x;
  const int lane = tid & 63;
  const int w = tid >> 6;          // 0..7
  const int wm = w >> 2;           // 0..1  (M half)
  const int wn = w & 3;            // 0..3  (N quarter)
  const int quad = lane >> 4;
  const int l16 = lane & 15;

  // T1: XCD-aware block swizzle (nwg % 8 == 0 at every call site)
  const int nbx = N >> 8;
  const int nwg = nbx * (M >> 8) * NSPLIT;
  int bid = blockIdx.x;
  bid = (bid & 7) * (nwg >> 3) + (bid >> 3);
  const int split = bid & (NSPLIT - 1);
  const int tile = bid / NSPLIT;
  const size_t bm = (size_t)(tile / nbx) * 256;
  const size_t bn = (size_t)(tile % nbx) * 256;
  const int lda = K * NSPLIT;
  const int koff = split * K;

  // staging: chunk c in {0:A.h0, 1:B.bh0, 2:A.h1, 3:B.bh1}, 2 x 16B/thread
  const bf16* gsrc[4][2];
  bf16* ldsp[4][2];
#pragma unroll
  for (int i = 0; i < 2; i++) {
    const int G = tid + i * 512;               // granule 0..1023 within chunk
    const int cr = G >> 3;                     // chunk row 0..127
    const int gs8 = ((G & 7) ^ (cr & 7)) * 8;  // pre-swizzled source column
    const int ra = ((cr >> 6) << 7) + (cr & 63);       // A: + h*64
    const int rb = ((cr >> 5) << 6) + (cr & 31);       // B: + bh*32
    gsrc[0][i] = A  + (bm + ra) * (size_t)lda + koff + gs8;
    gsrc[2][i] = A  + (bm + ra + 64) * (size_t)lda + koff + gs8;
    gsrc[1][i] = Bw + (bn + rb) * (size_t)lda + koff + gs8;
    gsrc[3][i] = Bw + (bn + rb + 32) * (size_t)lda + koff + gs8;
    ldsp[0][i] = &As[0][0][0][0] + G * 8;
    ldsp[2][i] = &As[0][1][0][0] + G * 8;
    ldsp[1][i] = &Bs[0][0][0][0] + G * 8;
    ldsp[3][i] = &Bs[0][1][0][0] + G * 8;
  }

  auto STAGE = [&](int c, int tn) {
    const int boff = (tn & 1) * 16384;  // els between buf0/buf1
    gload_lds16(gsrc[c][0] + (size_t)tn * 64, ldsp[c][0] + boff);
    gload_lds16(gsrc[c][1] + (size_t)tn * 64, ldsp[c][1] + boff);
  };

  // swizzled k-granule offsets for ds_read
  const int ksw0 = (quad ^ (l16 & 7)) * 8;
  const int ksw1 = ((4 + quad) ^ (l16 & 7)) * 8;

  floatx4 acc[8][4];
#pragma unroll
  for (int i = 0; i < 8; i++)
#pragma unroll
    for (int j = 0; j < 4; j++) acc[i][j] = {0.f, 0.f, 0.f, 0.f};

  short8 af[4][2], bv[2][2];

  auto READ_A = [&](int b, int h) {
#pragma unroll
    for (int mf = 0; mf < 4; mf++) {
      const bf16* p = &As[b][h][wm * 64 + mf * 16 + l16][0];
      af[mf][0] = *(const short8*)(p + ksw0);
      af[mf][1] = *(const short8*)(p + ksw1);
    }
  };
  auto READ_B = [&](int b, int bh) {
#pragma unroll
    for (int nf = 0; nf < 2; nf++) {
      const bf16* p = &Bs[b][bh][wn * 32 + nf * 16 + l16][0];
      bv[nf][0] = *(const short8*)(p + ksw0);
      bv[nf][1] = *(const short8*)(p + ksw1);
    }
  };
  auto MFMA16 = [&](int mb, int nb) {
#pragma unroll
    for (int mf = 0; mf < 4; mf++)
#pragma unroll
      for (int nf = 0; nf < 2; nf++) {
        floatx4 c = acc[mb + mf][nb + nf];
        c = __builtin_amdgcn_mfma_f32_16x16x32_bf16(af[mf][0], bv[nf][0], c, 0, 0, 0);
        c = __builtin_amdgcn_mfma_f32_16x16x32_bf16(af[mf][1], bv[nf][1], c, 0, 0, 0);
        acc[mb + mf][nb + nf] = c;
      }
  };

  // prologue: full tile 0
  STAGE(0, 0); STAGE(1, 0); STAGE(2, 0); STAGE(3, 0);
  VMCNT(4);
  __builtin_amdgcn_s_barrier();
  __builtin_amdgcn_sched_barrier(0);

  const int NT = K >> 6;
#pragma unroll 1
  for (int t = 0; t < NT; t++) {
    const int b = t & 1;
    const bool nl = (t + 1 < NT);
    // ---- phase 1: Q00 ----
    READ_A(b, 0);
    READ_B(b, 0);
    if (nl) STAGE(0, t + 1);
    __builtin_amdgcn_s_barrier();
    __builtin_amdgcn_sched_barrier(0);
    __builtin_amdgcn_s_setprio(1);
    MFMA16(0, 0);
    __builtin_amdgcn_s_setprio(0);
    if (nl) { VMCNT(2); } else { VMCNT(0); }
    __builtin_amdgcn_s_barrier();
    __builtin_amdgcn_sched_barrier(0);
    // ---- phase 2: Q01 ----
    READ_B(b, 1);
    if (nl) STAGE(1, t + 1);
    __builtin_amdgcn_s_barrier();
    __builtin_amdgcn_sched_barrier(0);
    __builtin_amdgcn_s_setprio(1);
    MFMA16(0, 2);
    __builtin_amdgcn_s_setprio(0);
    __builtin_amdgcn_s_barrier();
    __builtin_amdgcn_sched_barrier(0);
    // ---- phase 3: Q11 ----
    READ_A(b, 1);
    if (nl) STAGE(2, t + 1);
    __builtin_amdgcn_s_barrier();
    __builtin_amdgcn_sched_barrier(0);
    __builtin_amdgcn_s_setprio(1);
    MFMA16(4, 2);
    __builtin_amdgcn_s_setprio(0);
    __builtin_amdgcn_s_barrier();
    __builtin_amdgcn_sched_barrier(0);
    // ---- phase 4: Q10 ----
    READ_B(b, 0);
    if (nl) STAGE(3, t + 1);
    __builtin_amdgcn_s_barrier();
    __builtin_amdgcn_sched_barrier(0);
    __builtin_amdgcn_s_setprio(1);
    MFMA16(4, 0);
    __builtin_amdgcn_s_setprio(0);
    if (nl) { VMCNT(4); } else { VMCNT(0); }
    __builtin_amdgcn_s_barrier();
    __builtin_amdgcn_sched_barrier(0);
  }

  // epilogue
  float sc_eff = scale;
  if (EPI == 2) sc_eff = (bn < 1024) ? st : scale;  // Q columns pre-scaled
  float bias4[4];
  if (EPI == 1) {
#pragma unroll
    for (int j = 0; j < 4; j++) bias4[j] = bias[bn + wn * 64 + j * 16 + l16];
  }
  const size_t poff = (size_t)split * M * N;
#pragma unroll
  for (int mi = 0; mi < 8; mi++) {
    const size_t r0 = bm + wm * 128 + (mi >> 2) * 64 + (mi & 3) * 16 + quad * 4;
#pragma unroll
    for (int r = 0; r < 4; r++) {
      const size_t rowoff = (r0 + r) * (size_t)N + bn + wn * 64 + l16;
#pragma unroll
      for (int j = 0; j < 4; j++) {
        float v = acc[mi][j][r];
        if (EPI == 0 || EPI == 2) {
          ((bf16*)C)[rowoff + j * 16] = __float2bfloat16(v * sc_eff);
        } else if (EPI == 1) {
          // GELU (tanh form) via raw v_exp_f32 / v_rcp_f32
          float u = (v + bias4[j]) * scale;
          float tt = u * (0.7978845608f + 0.0356774081f * u * u);
          float e = __builtin_amdgcn_exp2f(tt * 2.8853900818f);  // exp(2*tt)
          float th = 1.0f - 2.0f * __builtin_amdgcn_rcpf(e + 1.0f);
          ((bf16*)C)[rowoff + j * 16] =
              __float2bfloat16(0.5f * u * (1.0f + th) * st);
        } else if (EPI == 3) {
          ((float*)C)[poff + rowoff + j * 16] = v * scale;
        } else {  // EPI == 4
          ((bf16*)C)[poff + rowoff + j * 16] = __float2bfloat16(v);
        }
      }
    }
  }
}

// ---------------------------------------------------------------------------
// MFMA flash attention, S^T scheme, 512 threads = 8 waves, QT=128, KT=64.
// FIXED-MAX softmax: Q is pre-scaled by MM_SCALE*LOG2E in the QKV gemm, and
// unit-scaling bounds |score*log2e| << 1, so P = exp2(S^T) directly — no
// online max, no rescale, no per-tile l-reduce (per-lane partial, reduced
// once at the end). Ps is [128][64] with XOR swizzle (both sides, LDS-only).
// ---------------------------------------------------------------------------
__global__ __launch_bounds__(512) void flash_attn_mfma(
    const bf16* __restrict__ qkv, bf16* __restrict__ att, float out_scale) {
  const int qb = blockIdx.x * 128;
  const int h = blockIdx.y, b = blockIdx.z;
  const int tid = threadIdx.x;
  const int lane = tid & 63;
  const int wv = tid >> 6;           // 0..7
  const int quad = lane >> 4;
  const int l16 = lane & 15;

  __shared__ __align__(16) bf16 Ks[2][64][72];
  __shared__ __align__(16) bf16 Vt[2][64][72];  // Vt[d][j] = V[j][d]
  __shared__ __align__(16) bf16 Ps[128][64];    // P [query][key], XOR-swizzled

  const bf16* Qb_ = qkv + (size_t)b * S_ * D3_ + h * DH_;
  const bf16* Kb_ = Qb_ + 1024;
  const bf16* Vb_ = Qb_ + 2048;

  // Q as B-operand frag: queries qb + wv*16 + l16 (already scaled)
  short8 bq0, bq1;
  {
    const bf16* qrow = Qb_ + (size_t)(qb + wv * 16 + l16) * D3_ + quad * 8;
    bq0 = *(const short8*)(qrow);
    bq1 = *(const short8*)(qrow + 32);
  }

  float l_part = 0.f;
  floatx4 o[4];
#pragma unroll
  for (int fd = 0; fd < 4; fd++) o[fd] = {0.f, 0.f, 0.f, 0.f};

  // P LDS addressing (per-wave private rows, XOR swizzle on byte bit 4-6)
  const int prow = wv * 16 + l16;
  const int psw = (prow & 7) << 4;
  char* pbase = (char*)&Ps[0][0] + prow * 128;

  // staging (512 threads): K chunk = 1 x 16B; V = 1 uint4 -> 8 b16 scatters
  const int kr = tid >> 3, ko = (tid & 7) * 8;
  const int vj = tid & 63, vd = (tid >> 6) * 8;

  // prologue: prefetch tile 0 into registers
  uint4 kreg = *(const uint4*)(Kb_ + (size_t)kr * D3_ + ko);
  uint4 vreg = *(const uint4*)(Vb_ + (size_t)vj * D3_ + vd);

  int cur = 0;
  for (int t = 0; t < S_ / 64; t++) {
    // commit prefetched tile into buf[cur]
    *(uint4*)&Ks[cur][kr][ko] = kreg;
    {
      bf16 tmp[8];
      *(uint4*)tmp = vreg;
#pragma unroll
      for (int e = 0; e < 8; e++) Vt[cur][vd + e][vj] = tmp[e];
    }
    __syncthreads();

    // prefetch tile t+1 (clamped; redundant reload on last iter)
    {
      const int tn = (t + 1 < S_ / 64) ? t + 1 : t;
      kreg = *(const uint4*)(Kb_ + (size_t)(tn * 64 + kr) * D3_ + ko);
      vreg = *(const uint4*)(Vb_ + (size_t)(tn * 64 + vj) * D3_ + vd);
    }

    // S^T = K Q^T : lane holds keys fk*16 + quad*4 + r for query wv*16+l16
    float st[4][4];
    __builtin_amdgcn_s_setprio(1);
#pragma unroll
    for (int fk = 0; fk < 4; fk++) {
      short8 ak0 = *(const short8*)&Ks[cur][fk * 16 + l16][quad * 8];
      short8 ak1 = *(const short8*)&Ks[cur][fk * 16 + l16][32 + quad * 8];
      floatx4 acc = {0.f, 0.f, 0.f, 0.f};
      acc = __builtin_amdgcn_mfma_f32_16x16x32_bf16(ak0, bq0, acc, 0, 0, 0);
      acc = __builtin_amdgcn_mfma_f32_16x16x32_bf16(ak1, bq1, acc, 0, 0, 0);
#pragma unroll
      for (int r = 0; r < 4; r++) st[fk][r] = acc[r];
    }
    __builtin_amdgcn_s_setprio(0);

    // P = exp2(S^T) (fixed max = 0), per-lane l partial
#pragma unroll
    for (int fk = 0; fk < 4; fk++) {
      bf16 pk[4];
#pragma unroll
      for (int r = 0; r < 4; r++) {
        const float p = exp2f(st[fk][r]);
        l_part += p;
        pk[r] = __float2bfloat16(p);
      }
      *(uint2*)(pbase + ((fk * 32 + quad * 8) ^ psw)) = *(uint2*)pk;
    }

    // O += P V
    short8 ap0 = *(const short8*)(pbase + ((quad * 16) ^ psw));
    short8 ap1 = *(const short8*)(pbase + ((64 + quad * 16) ^ psw));
    __builtin_amdgcn_s_setprio(1);
#pragma unroll
    for (int fd = 0; fd < 4; fd++) {
      short8 bv0 = *(const short8*)&Vt[cur][fd * 16 + l16][quad * 8];
      short8 bv1 = *(const short8*)&Vt[cur][fd * 16 + l16][32 + quad * 8];
      o[fd] = __builtin_amdgcn_mfma_f32_16x16x32_bf16(ap0, bv0, o[fd], 0, 0, 0);
      o[fd] = __builtin_amdgcn_mfma_f32_16x16x32_bf16(ap1, bv1, o[fd], 0, 0, 0);
    }
    __builtin_amdgcn_s_setprio(0);

    cur ^= 1;
  }

  // final l: sum quads (butterfly), then pick query quad*4+r's value
  l_part += __shfl_xor(l_part, 16);
  l_part += __shfl_xor(l_part, 32);
#pragma unroll
  for (int r = 0; r < 4; r++) {
    const float lq = __shfl(l_part, quad * 4 + r, 64);
    const float sc = out_scale / lq;
    const size_t base =
        ((size_t)(b * S_ + qb + wv * 16 + quad * 4 + r)) * D_ + h * DH_;
#pragma unroll
    for (int fd = 0; fd < 4; fd++)
      att[base + fd * 16 + l16] = __float2bfloat16(o[fd][r] * sc);
  }
}

// ---------------------------------------------------------------------------
extern "C" void kernel_launch(void* const* d_in, const int* in_sizes, int n_in,
                              void* d_out, int out_size, void* d_ws, size_t ws_size,
                              hipStream_t stream) {
  const float* x     = (const float*)d_in[0];
  const float* w_qkv = (const float*)d_in[1];
  const float* w_o   = (const float*)d_in[2];
  const float* w1    = (const float*)d_in[3];
  const float* b1    = (const float*)d_in[4];
  const float* w2    = (const float*)d_in[5];
  const float* b2    = (const float*)d_in[6];
  const float* ln1w  = (const float*)d_in[7];
  const float* ln1b  = (const float*)d_in[8];
  const float* ln2w  = (const float*)d_in[9];
  const float* ln2b  = (const float*)d_in[10];
  float* out = (float*)d_out;
  bf16* ws  = (bf16*)d_ws;

  // workspace layout (bf16 els), liveness-audited, peak 29,360,128 els (58.7MB)
  // stage order: cvt_qo, LN1, QKV, flash, cvt_w1, oproj, LN2, FFN1, cvt_w2,
  //              FFN2, reduce
  bf16* h1   = ws;                 // [0,4.19M)       live LN1->QKV
  bf16* wqb  = ws + 4194304;       // [4.19,7.34M)    live cvt->QKV
  bf16* qkv  = ws + 8388608;       // [8.39,20.97M)   live QKV->flash
  bf16* att  = ws + 20971520;      // [20.97,25.17M)  live flash->oproj
  bf16* wob  = ws + 25165824;      // [25.17,26.21M)  live cvt->oproj
  float* Po  = (float*)ws;         // [0,16.78M) = 8.39M f32, oproj->LN2 (h1/wqb dead)
  bf16* w1b  = ws + 16777216;      // [16.78,20.97M)  live cvt_w1->FFN1 (qkv dead)
  bf16* h2   = ws + 20971520;      // [20.97,25.17M)  live LN2->FFN1 (att dead)
  bf16* g    = ws;                 // [0,16.78M)      live FFN1->FFN2 (Po dead)
  bf16* w2b  = ws + 16777216;      // [16.78,20.97M)  live cvt_w2->FFN2 (w1b dead)
  bf16* Pf   = ws + 20971520;      // [20.97,29.36M)  live FFN2->reduce (h2 dead)

  const float MM_SCALE   = (float)pow((double)S_ * S_ * DH_, -1.0 / 6.0);
  const float SM_SCALE   = (float)((double)S_ / sqrt(1.31 * 1.65));
  const float GELU_SCALE = (float)pow(0.588 * 0.675, -0.5);
  const float SQRT_TAU   = (float)sqrt(0.2);
  const float SQRT_1MT   = (float)sqrt(0.8);
  const float LOG2E      = 1.4426950408889634f;
  const float qkv_scale  = (float)pow((double)D_ * D3_, -0.25);
  const float o_scale    = (float)pow((double)D_ * D_, -0.25);
  const float w1_scale   = (float)pow((double)D_ * DF_, -0.25);
  const float w2_scale   = (float)pow((double)DF_ * D_, -0.25);

  // 1. convert w_qkv (permuted) + w_o
  cvt_qkv_o<<<4096, 256, 0, stream>>>(w_qkv, w_o, wqb, wob);
  // 2. LN1
  resid_ln_kernel<false, false, float, float><<<BS_, 256, 0, stream>>>(
      x, nullptr, nullptr, ln1w, ln1b, h1, 0.f, 0.f, nullptr, nullptr, 0.f, 0.f);
  // 3. QKV gemm -> head-major qkv (Q columns folded with MM_SCALE*LOG2E)
  gemm_mfma256<2, 1, bf16><<<dim3(192), 512, 0, stream>>>(
      h1, wqb, qkv, BS_, D3_, D_, qkv_scale, nullptr,
      qkv_scale * MM_SCALE * LOG2E);
  // 4. MFMA flash attention (fixed-max), reads qkv directly
  flash_attn_mfma<<<dim3(S_ / 128, H_, B_), 512, 0, stream>>>(
      qkv, att, SM_SCALE * MM_SCALE);
  // 4.5 convert w1 (qkv dead after flash)
  cvt_f32_bf16<<<(DF_ * D_ / 4 + 255) / 256, 256, 0, stream>>>(w1, w1b, DF_ * D_ / 4);
  // 5. out-proj: split-K=2 8-phase, fp32 partial stores (128 blocks)
  gemm_mfma256<3, 2, float><<<dim3(128), 512, 0, stream>>>(
      att, wob, Po, BS_, D_, D_ / 2, o_scale, nullptr, 0.f);
  // 6. residual(sum of 2 partials) + LN2; pre-init out = cs*xv + cb*b2
  resid_ln_kernel<true, true, float, float><<<BS_, 256, 0, stream>>>(
      Po, Po + (size_t)BS_ * D_, x, ln2w, ln2b, h2, SQRT_TAU, SQRT_1MT,
      out, b2, SQRT_TAU * w2_scale, SQRT_1MT);
  // 7. FFN1 + GELU (256 blocks)
  gemm_mfma256<1, 1, bf16><<<dim3(256), 512, 0, stream>>>(
      h2, w1b, g, BS_, DF_, D_, w1_scale, b1, GELU_SCALE);
  // 7.5 convert w2 (w1b dead after FFN1)
  cvt_f32_bf16<<<(D_ * DF_ / 4 + 255) / 256, 256, 0, stream>>>(w2, w2b, D_ * DF_ / 4);
  // 8. FFN2: split-K=2 8-phase, bf16 partial stores (128 blocks)
  gemm_mfma256<4, 2, bf16><<<dim3(128), 512, 0, stream>>>(
      g, w2b, Pf, BS_, D_, DF_ / 2, 1.f, nullptr, 0.f);
  // 9. reduce partials into pre-init'd out
  reduce_ffn2<<<2048, 256, 0, stream>>>(
      Pf, Pf + (size_t)BS_ * D_, out, SQRT_TAU * w2_scale);
}

// Round 4
// 348.406 us; speedup vs baseline: 1.1974x; 1.0663x over previous
//
#include <hip/hip_runtime.h>
#include <hip/hip_bf16.h>
#include <math.h>

typedef __hip_bfloat16 bf16;
typedef __attribute__((ext_vector_type(8))) short short8;
typedef __attribute__((ext_vector_type(4))) float floatx4;

#define B_   2
#define S_   2048
#define D_   1024
#define H_   16
#define DH_  64
#define BS_  4096   // B_*S_
#define D3_  3072   // 3*D_
#define DF_  4096   // 4*D_

__device__ __forceinline__ float tof(float v) { return v; }
__device__ __forceinline__ float tof(bf16 v) { return __bfloat162float(v); }

// async global->LDS 16B copy: lane's data lands at readfirstlane(lds)+lane*16
__device__ __forceinline__ void gload_lds16(const bf16* g, bf16* l) {
  __builtin_amdgcn_global_load_lds(
      (const __attribute__((address_space(1))) unsigned int*)g,
      (__attribute__((address_space(3))) unsigned int*)l, 16, 0, 0);
}

#define VMCNT(n) asm volatile("s_waitcnt vmcnt(" #n ")" ::: "memory")

// ---------------------------------------------------------------------------
// fp32 -> bf16 weight conversion (vectorized x4)
// ---------------------------------------------------------------------------
__global__ __launch_bounds__(256) void cvt_f32_bf16(
    const float* __restrict__ in, bf16* __restrict__ out, int n4) {
  int i = blockIdx.x * 256 + threadIdx.x;
  if (i >= n4) return;
  float4 v = ((const float4*)in)[i];
  bf16 o[4] = {__float2bfloat16(v.x), __float2bfloat16(v.y),
               __float2bfloat16(v.z), __float2bfloat16(v.w)};
  ((ulong1*)out)[i] = *(ulong1*)o;
}

// ---------------------------------------------------------------------------
// Fused convert: w_qkv fp32->bf16 with ROW PERMUTE n=d*48+z*16+h -> n2=
// z*1024+h*64+d (so QKV gemm emits [b,s][z,h,d]), plus plain convert of w_o.
// ---------------------------------------------------------------------------
__global__ __launch_bounds__(256) void cvt_qkv_o(
    const float* __restrict__ wqkv, const float* __restrict__ wo,
    bf16* __restrict__ wqb, bf16* __restrict__ wob) {
  const int g = blockIdx.x * 256 + threadIdx.x;  // 4-el group
  if (g < 786432) {                              // 3072*1024/4 : permute+cvt
    const int n2 = g >> 8;                       // dest row (z,h,d)
    const int col = (g & 255) * 4;
    const int z = n2 >> 10, hh = (n2 >> 6) & 15, d = n2 & 63;
    const int n = d * 48 + z * 16 + hh;          // src row
    float4 v = *(const float4*)(wqkv + (size_t)n * 1024 + col);
    bf16 o[4] = {__float2bfloat16(v.x), __float2bfloat16(v.y),
                 __float2bfloat16(v.z), __float2bfloat16(v.w)};
    *(unsigned long long*)(wqb + (size_t)n2 * 1024 + col) =
        *(unsigned long long*)o;
  } else {
    const int g2 = g - 786432;                   // w_o: 1024*1024/4 groups
    float4 v = ((const float4*)wo)[g2];
    bf16 o[4] = {__float2bfloat16(v.x), __float2bfloat16(v.y),
                 __float2bfloat16(v.z), __float2bfloat16(v.w)};
    ((unsigned long long*)wob)[g2] = *(unsigned long long*)o;
  }
}

// ---------------------------------------------------------------------------
// LayerNorm. FUSE: xv = st*(a[i]+a2[i]) + s1t*skip[i]  (a,a2 = fp32 split-K
// partials of the out-proj, already o_scale'd). INIT: pre-init the FFN2
// output with the linear epilogue part: oinit = cs*xv + cb*b2[col].
// ---------------------------------------------------------------------------
template <bool FUSE, bool INIT, typename TA, typename TS>
__global__ __launch_bounds__(256) void resid_ln_kernel(
    const TA* __restrict__ a, const TA* __restrict__ a2,
    const TS* __restrict__ skip,
    const float* __restrict__ w, const float* __restrict__ bias,
    bf16* __restrict__ hout, float st, float s1t,
    float* __restrict__ oinit, const float* __restrict__ b2,
    float cb, float cs) {
  const int row = blockIdx.x;
  const int tid = threadIdx.x;
  const int base = tid * 4;
  const size_t roff = (size_t)row * D_;

  float xv[4];
#pragma unroll
  for (int i = 0; i < 4; i++) {
    float v = tof(a[roff + base + i]);
    if (FUSE) v = st * (v + tof(a2[roff + base + i]))
                  + s1t * tof(skip[roff + base + i]);
    xv[i] = v;
  }
  if (INIT) {
#pragma unroll
    for (int i = 0; i < 4; i++)
      oinit[roff + base + i] = cs * xv[i] + cb * b2[base + i];
  }

  float ls = 0.f, lq = 0.f;
#pragma unroll
  for (int i = 0; i < 4; i++) { ls += xv[i]; lq += xv[i] * xv[i]; }

  __shared__ float ssum[256];
  __shared__ float ssq[256];
  ssum[tid] = ls; ssq[tid] = lq;
  __syncthreads();
  for (int off = 128; off > 0; off >>= 1) {
    if (tid < off) { ssum[tid] += ssum[tid + off]; ssq[tid] += ssq[tid + off]; }
    __syncthreads();
  }
  const float mean = ssum[0] * (1.0f / D_);
  const float var  = ssq[0] * (1.0f / D_) - mean * mean;
  const float rstd = rsqrtf(var + 1e-5f);

#pragma unroll
  for (int i = 0; i < 4; i++) {
    float v = (xv[i] - mean) * rstd * w[base + i] + bias[base + i];
    hout[roff + base + i] = __float2bfloat16(v);
  }
}

// ---------------------------------------------------------------------------
// FFN2 split-K reduce: out += sc*(p0[i] + p1[i]); out was pre-init'd by LN2.
// ---------------------------------------------------------------------------
__global__ __launch_bounds__(256) void reduce_ffn2(
    const bf16* __restrict__ p0, const bf16* __restrict__ p1,
    float* __restrict__ out, float sc) {
  const size_t i = ((size_t)blockIdx.x * 256 + threadIdx.x) * 8;
  short8 a = *(const short8*)(p0 + i);
  short8 b = *(const short8*)(p1 + i);
  bf16 t0[8], t1[8];
  *(short8*)t0 = a; *(short8*)t1 = b;
  float4 o0 = *(float4*)(out + i);
  float4 o1 = *(float4*)(out + i + 4);
#pragma unroll
  for (int e = 0; e < 4; e++) {
    ((float*)&o0)[e] += sc * (__bfloat162float(t0[e]) + __bfloat162float(t1[e]));
    ((float*)&o1)[e] += sc * (__bfloat162float(t0[e + 4]) + __bfloat162float(t1[e + 4]));
  }
  *(float4*)(out + i) = o0;
  *(float4*)(out + i + 4) = o1;
}

// ---------------------------------------------------------------------------
// 256x256 8-phase MFMA GEMM (T1+T2+T3+T4+T5). 512 thr = 8 waves (2Mx4N),
// BK=64, LDS 128 KiB. Used for the big-N GEMMs (QKV, FFN1).
// EPI: 1 = bias+GELU(tanh),store bf16; 2 = dual-scale (Q cols bn<1024 -> st).
// ---------------------------------------------------------------------------
template <int EPI, int NSPLIT, typename TC>
__global__ __launch_bounds__(512, 2) void gemm_mfma256(
    const bf16* __restrict__ A, const bf16* __restrict__ Bw,
    TC* __restrict__ C, int M, int N, int K, float scale,
    const float* __restrict__ bias, float st) {
  __shared__ __align__(16) bf16 As[2][2][128][64];  // [buf][chunk h][row][k]
  __shared__ __align__(16) bf16 Bs[2][2][128][64];  // [buf][chunk bh][row][k]

  const int tid = threadIdx.x;
  const int lane = tid & 63;
  const int w = tid >> 6;          // 0..7
  const int wm = w >> 2;           // 0..1  (M half)
  const int wn = w & 3;            // 0..3  (N quarter)
  const int quad = lane >> 4;
  const int l16 = lane & 15;

  // T1: XCD-aware block swizzle (nwg % 8 == 0 at every call site)
  const int nbx = N >> 8;
  const int nwg = nbx * (M >> 8) * NSPLIT;
  int bid = blockIdx.x;
  bid = (bid & 7) * (nwg >> 3) + (bid >> 3);
  const int split = bid & (NSPLIT - 1);
  const int tile = bid / NSPLIT;
  const size_t bm = (size_t)(tile / nbx) * 256;
  const size_t bn = (size_t)(tile % nbx) * 256;
  const int lda = K * NSPLIT;
  const int koff = split * K;

  // staging: chunk c in {0:A.h0, 1:B.bh0, 2:A.h1, 3:B.bh1}, 2 x 16B/thread
  const bf16* gsrc[4][2];
  bf16* ldsp[4][2];
#pragma unroll
  for (int i = 0; i < 2; i++) {
    const int G = tid + i * 512;               // granule 0..1023 within chunk
    const int cr = G >> 3;                     // chunk row 0..127
    const int gs8 = ((G & 7) ^ (cr & 7)) * 8;  // pre-swizzled source column
    const int ra = ((cr >> 6) << 7) + (cr & 63);       // A: + h*64
    const int rb = ((cr >> 5) << 6) + (cr & 31);       // B: + bh*32
    gsrc[0][i] = A  + (bm + ra) * (size_t)lda + koff + gs8;
    gsrc[2][i] = A  + (bm + ra + 64) * (size_t)lda + koff + gs8;
    gsrc[1][i] = Bw + (bn + rb) * (size_t)lda + koff + gs8;
    gsrc[3][i] = Bw + (bn + rb + 32) * (size_t)lda + koff + gs8;
    ldsp[0][i] = &As[0][0][0][0] + G * 8;
    ldsp[2][i] = &As[0][1][0][0] + G * 8;
    ldsp[1][i] = &Bs[0][0][0][0] + G * 8;
    ldsp[3][i] = &Bs[0][1][0][0] + G * 8;
  }

  auto STAGE = [&](int c, int tn) {
    const int boff = (tn & 1) * 16384;  // els between buf0/buf1
    gload_lds16(gsrc[c][0] + (size_t)tn * 64, ldsp[c][0] + boff);
    gload_lds16(gsrc[c][1] + (size_t)tn * 64, ldsp[c][1] + boff);
  };

  // swizzled k-granule offsets for ds_read
  const int ksw0 = (quad ^ (l16 & 7)) * 8;
  const int ksw1 = ((4 + quad) ^ (l16 & 7)) * 8;

  floatx4 acc[8][4];
#pragma unroll
  for (int i = 0; i < 8; i++)
#pragma unroll
    for (int j = 0; j < 4; j++) acc[i][j] = {0.f, 0.f, 0.f, 0.f};

  short8 af[4][2], bv[2][2];

  auto READ_A = [&](int b, int h) {
#pragma unroll
    for (int mf = 0; mf < 4; mf++) {
      const bf16* p = &As[b][h][wm * 64 + mf * 16 + l16][0];
      af[mf][0] = *(const short8*)(p + ksw0);
      af[mf][1] = *(const short8*)(p + ksw1);
    }
  };
  auto READ_B = [&](int b, int bh) {
#pragma unroll
    for (int nf = 0; nf < 2; nf++) {
      const bf16* p = &Bs[b][bh][wn * 32 + nf * 16 + l16][0];
      bv[nf][0] = *(const short8*)(p + ksw0);
      bv[nf][1] = *(const short8*)(p + ksw1);
    }
  };
  auto MFMA16 = [&](int mb, int nb) {
#pragma unroll
    for (int mf = 0; mf < 4; mf++)
#pragma unroll
      for (int nf = 0; nf < 2; nf++) {
        floatx4 c = acc[mb + mf][nb + nf];
        c = __builtin_amdgcn_mfma_f32_16x16x32_bf16(af[mf][0], bv[nf][0], c, 0, 0, 0);
        c = __builtin_amdgcn_mfma_f32_16x16x32_bf16(af[mf][1], bv[nf][1], c, 0, 0, 0);
        acc[mb + mf][nb + nf] = c;
      }
  };

  // prologue: full tile 0
  STAGE(0, 0); STAGE(1, 0); STAGE(2, 0); STAGE(3, 0);
  VMCNT(4);
  __builtin_amdgcn_s_barrier();
  __builtin_amdgcn_sched_barrier(0);

  const int NT = K >> 6;
#pragma unroll 1
  for (int t = 0; t < NT; t++) {
    const int b = t & 1;
    const bool nl = (t + 1 < NT);
    // ---- phase 1: Q00 ----
    READ_A(b, 0);
    READ_B(b, 0);
    if (nl) STAGE(0, t + 1);
    __builtin_amdgcn_s_barrier();
    __builtin_amdgcn_sched_barrier(0);
    __builtin_amdgcn_s_setprio(1);
    MFMA16(0, 0);
    __builtin_amdgcn_s_setprio(0);
    if (nl) { VMCNT(2); } else { VMCNT(0); }
    __builtin_amdgcn_s_barrier();
    __builtin_amdgcn_sched_barrier(0);
    // ---- phase 2: Q01 ----
    READ_B(b, 1);
    if (nl) STAGE(1, t + 1);
    __builtin_amdgcn_s_barrier();
    __builtin_amdgcn_sched_barrier(0);
    __builtin_amdgcn_s_setprio(1);
    MFMA16(0, 2);
    __builtin_amdgcn_s_setprio(0);
    __builtin_amdgcn_s_barrier();
    __builtin_amdgcn_sched_barrier(0);
    // ---- phase 3: Q11 ----
    READ_A(b, 1);
    if (nl) STAGE(2, t + 1);
    __builtin_amdgcn_s_barrier();
    __builtin_amdgcn_sched_barrier(0);
    __builtin_amdgcn_s_setprio(1);
    MFMA16(4, 2);
    __builtin_amdgcn_s_setprio(0);
    __builtin_amdgcn_s_barrier();
    __builtin_amdgcn_sched_barrier(0);
    // ---- phase 4: Q10 ----
    READ_B(b, 0);
    if (nl) STAGE(3, t + 1);
    __builtin_amdgcn_s_barrier();
    __builtin_amdgcn_sched_barrier(0);
    __builtin_amdgcn_s_setprio(1);
    MFMA16(4, 0);
    __builtin_amdgcn_s_setprio(0);
    if (nl) { VMCNT(4); } else { VMCNT(0); }
    __builtin_amdgcn_s_barrier();
    __builtin_amdgcn_sched_barrier(0);
  }

  // epilogue
  float sc_eff = scale;
  if (EPI == 2) sc_eff = (bn < 1024) ? st : scale;  // Q columns pre-scaled
  float bias4[4];
  if (EPI == 1) {
#pragma unroll
    for (int j = 0; j < 4; j++) bias4[j] = bias[bn + wn * 64 + j * 16 + l16];
  }
#pragma unroll
  for (int mi = 0; mi < 8; mi++) {
    const size_t r0 = bm + wm * 128 + (mi >> 2) * 64 + (mi & 3) * 16 + quad * 4;
#pragma unroll
    for (int r = 0; r < 4; r++) {
      const size_t rowoff = (r0 + r) * (size_t)N + bn + wn * 64 + l16;
#pragma unroll
      for (int j = 0; j < 4; j++) {
        float v = acc[mi][j][r];
        if (EPI == 2 || EPI == 0) {
          ((bf16*)C)[rowoff + j * 16] = __float2bfloat16(v * sc_eff);
        } else {
          // GELU (tanh form) via raw v_exp_f32 / v_rcp_f32
          float u = (v + bias4[j]) * scale;
          float tt = u * (0.7978845608f + 0.0356774081f * u * u);
          float e = __builtin_amdgcn_exp2f(tt * 2.8853900818f);  // exp(2*tt)
          float th = 1.0f - 2.0f * __builtin_amdgcn_rcpf(e + 1.0f);
          ((bf16*)C)[rowoff + j * 16] =
              __float2bfloat16(0.5f * u * (1.0f + th) * st);
        }
      }
    }
  }
}

// ---------------------------------------------------------------------------
// 256x128 8-phase MFMA GEMM, split-K=2 with partial stores. For the N=1024
// GEMMs (out-proj, FFN2): tiles = (M/256)*(N/128) = 128, x2 splits = 256
// blocks -> FULL chip (the BN=256 variant left half the CUs idle).
// 8 waves 2Mx4N, per-wave C = 128x32, acc[8][2]. LDS 96 KiB.
// Chunk stage order per tile: C0=A.h0(2 loads), C1=B.bh0(1), C2=B.bh1(1),
// C3=A.h1(2). Phases: p1 (A.h0 x nf0), p2 (A.h0 x nf1), p3 (A.h1 x nf1),
// p4 (A.h1 x nf0, bv[0] reused). Waits: end-p2 vmcnt(3) [drain C3(t)],
// end-p4 vmcnt(2) [drain C0..C2(t+1)].
// EPI: 3 = fp32 partial v*scale at C+split*M*N; 4 = bf16 raw partial.
// ---------------------------------------------------------------------------
template <int EPI, typename TC>
__global__ __launch_bounds__(512, 2) void gemm_mfma128(
    const bf16* __restrict__ A, const bf16* __restrict__ Bw,
    TC* __restrict__ C, int M, int N, int K, float scale) {
  __shared__ __align__(16) bf16 As[2][2][128][64];  // 64 KiB
  __shared__ __align__(16) bf16 Bs[2][2][64][64];   // 32 KiB

  const int tid = threadIdx.x;
  const int lane = tid & 63;
  const int w = tid >> 6;
  const int wm = w >> 2;           // 0..1
  const int wn = w & 3;            // 0..3 (32-col slice)
  const int quad = lane >> 4;
  const int l16 = lane & 15;

  const int nbx = N >> 7;
  const int nwg = nbx * (M >> 8) * 2;
  int bid = blockIdx.x;
  bid = (bid & 7) * (nwg >> 3) + (bid >> 3);
  const int split = bid & 1;
  const int tile = bid >> 1;
  const size_t bm = (size_t)(tile / nbx) * 256;
  const size_t bn = (size_t)(tile % nbx) * 128;
  const int lda = K * 2;
  const int koff = split * K;

  // A staging (2 chunks x 128 rows, 2 gloads each)
  const bf16* gA[2][2];
  bf16* lA[2][2];
#pragma unroll
  for (int i = 0; i < 2; i++) {
    const int G = tid + i * 512;
    const int cr = G >> 3;
    const int gs8 = ((G & 7) ^ (cr & 7)) * 8;
    const int ra = ((cr >> 6) << 7) + (cr & 63);
    gA[0][i] = A + (bm + ra) * (size_t)lda + koff + gs8;
    gA[1][i] = A + (bm + ra + 64) * (size_t)lda + koff + gs8;
    lA[0][i] = &As[0][0][0][0] + G * 8;
    lA[1][i] = &As[0][1][0][0] + G * 8;
  }
  // B staging (2 chunks x 64 rows, 1 gload each)
  const bf16* gB[2];
  bf16* lB[2];
  {
    const int cr = tid >> 3;
    const int gs8 = ((tid & 7) ^ (cr & 7)) * 8;
    gB[0] = Bw + (bn + cr) * (size_t)lda + koff + gs8;
    gB[1] = Bw + (bn + 64 + cr) * (size_t)lda + koff + gs8;
    lB[0] = &Bs[0][0][0][0] + tid * 8;
    lB[1] = &Bs[0][1][0][0] + tid * 8;
  }

  auto STAGE_A = [&](int h, int tn) {
    const int boff = (tn & 1) * 16384;
    gload_lds16(gA[h][0] + (size_t)tn * 64, lA[h][0] + boff);
    gload_lds16(gA[h][1] + (size_t)tn * 64, lA[h][1] + boff);
  };
  auto STAGE_B = [&](int bh, int tn) {
    const int boff = (tn & 1) * 8192;
    gload_lds16(gB[bh] + (size_t)tn * 64, lB[bh] + boff);
  };

  const int ksw0 = (quad ^ (l16 & 7)) * 8;
  const int ksw1 = ((4 + quad) ^ (l16 & 7)) * 8;

  floatx4 acc[8][2];
#pragma unroll
  for (int i = 0; i < 8; i++)
#pragma unroll
    for (int j = 0; j < 2; j++) acc[i][j] = {0.f, 0.f, 0.f, 0.f};

  short8 af[4][2], bv[2][2];

  auto READ_A = [&](int b, int h) {
#pragma unroll
    for (int mf = 0; mf < 4; mf++) {
      const bf16* p = &As[b][h][wm * 64 + mf * 16 + l16][0];
      af[mf][0] = *(const short8*)(p + ksw0);
      af[mf][1] = *(const short8*)(p + ksw1);
    }
  };
  // wave wn's cols live entirely in B chunk wn>>1, sub-rows (wn&1)*32
  auto READ_BNF = [&](int b, int nf) {
    const bf16* p = &Bs[b][wn >> 1][(wn & 1) * 32 + nf * 16 + l16][0];
    bv[nf][0] = *(const short8*)(p + ksw0);
    bv[nf][1] = *(const short8*)(p + ksw1);
  };
  auto MFMA8 = [&](int mb, int nf) {
#pragma unroll
    for (int mf = 0; mf < 4; mf++) {
      floatx4 c = acc[mb + mf][nf];
      c = __builtin_amdgcn_mfma_f32_16x16x32_bf16(af[mf][0], bv[nf][0], c, 0, 0, 0);
      c = __builtin_amdgcn_mfma_f32_16x16x32_bf16(af[mf][1], bv[nf][1], c, 0, 0, 0);
      acc[mb + mf][nf] = c;
    }
  };

  // prologue: tile 0 (6 loads); p1 needs C0,C1,C2 -> leave C3 (2) in flight
  STAGE_A(0, 0); STAGE_B(0, 0); STAGE_B(1, 0); STAGE_A(1, 0);
  VMCNT(2);
  __builtin_amdgcn_s_barrier();
  __builtin_amdgcn_sched_barrier(0);

  const int NT = K >> 6;
#pragma unroll 1
  for (int t = 0; t < NT; t++) {
    const int b = t & 1;
    const bool nl = (t + 1 < NT);
    // ---- p1: A.h0 x nf0 ----
    READ_A(b, 0);
    READ_BNF(b, 0);
    if (nl) STAGE_A(0, t + 1);
    __builtin_amdgcn_s_barrier();
    __builtin_amdgcn_sched_barrier(0);
    __builtin_amdgcn_s_setprio(1);
    MFMA8(0, 0);
    __builtin_amdgcn_s_setprio(0);
    __builtin_amdgcn_s_barrier();
    __builtin_amdgcn_sched_barrier(0);
    // ---- p2: A.h0 x nf1 ----
    READ_BNF(b, 1);
    if (nl) STAGE_B(0, t + 1);
    __builtin_amdgcn_s_barrier();
    __builtin_amdgcn_sched_barrier(0);
    __builtin_amdgcn_s_setprio(1);
    MFMA8(0, 1);
    __builtin_amdgcn_s_setprio(0);
    if (nl) { VMCNT(3); } else { VMCNT(0); }
    __builtin_amdgcn_s_barrier();
    __builtin_amdgcn_sched_barrier(0);
    // ---- p3: A.h1 x nf1 ----
    READ_A(b, 1);
    if (nl) STAGE_B(1, t + 1);
    __builtin_amdgcn_s_barrier();
    __builtin_amdgcn_sched_barrier(0);
    __builtin_amdgcn_s_setprio(1);
    MFMA8(4, 1);
    __builtin_amdgcn_s_setprio(0);
    __builtin_amdgcn_s_barrier();
    __builtin_amdgcn_sched_barrier(0);
    // ---- p4: A.h1 x nf0 (bv[0] reused from p1) ----
    if (nl) STAGE_A(1, t + 1);
    __builtin_amdgcn_s_barrier();
    __builtin_amdgcn_sched_barrier(0);
    __builtin_amdgcn_s_setprio(1);
    MFMA8(4, 0);
    __builtin_amdgcn_s_setprio(0);
    if (nl) { VMCNT(2); } else { VMCNT(0); }
    __builtin_amdgcn_s_barrier();
    __builtin_amdgcn_sched_barrier(0);
  }

  // epilogue: partial stores at C + split*M*N
  const size_t poff = (size_t)split * M * N;
#pragma unroll
  for (int mi = 0; mi < 8; mi++) {
    const size_t r0 = bm + wm * 128 + (mi >> 2) * 64 + (mi & 3) * 16 + quad * 4;
#pragma unroll
    for (int r = 0; r < 4; r++) {
      const size_t rowoff = (r0 + r) * (size_t)N + bn + wn * 32 + l16;
#pragma unroll
      for (int j = 0; j < 2; j++) {
        float v = acc[mi][j][r];
        if (EPI == 3) {
          ((float*)C)[poff + rowoff + j * 16] = v * scale;
        } else {
          ((bf16*)C)[poff + rowoff + j * 16] = __float2bfloat16(v);
        }
      }
    }
  }
}

// ---------------------------------------------------------------------------
// MFMA flash attention, S^T scheme, 512 threads = 8 waves, QT=128, KT=64.
// FIXED-MAX softmax (Q pre-scaled by MM_SCALE*LOG2E in the QKV gemm).
// - XCD-locality remap: 4 (b,h) pairs per XCD so each XCD's L2 holds its
//   own KV working set (2MB < 4MB L2) instead of re-fetching from HBM.
// - K staged via gload_lds16 (async, linear dest) with T2 XOR swizzle
//   applied on the global source column + the ds_read offset.
// - l computed BY THE MATRIX PIPE: Vt row 64 = all-ones, 5th PV fragment's
//   l16=0 column = row-sums of P. No per-tile VALU l accumulation.
// ---------------------------------------------------------------------------
__global__ __launch_bounds__(512) void flash_attn_mfma(
    const bf16* __restrict__ qkv, bf16* __restrict__ att, float out_scale) {
  const int flat = (blockIdx.z * H_ + blockIdx.y) * (S_ / 128) + blockIdx.x;
  const int g8 = flat & 7, slot = flat >> 3;
  const int hf = g8 * 4 + (slot >> 4);   // (b,h) flat index 0..31
  const int qb = (slot & 15) * 128;
  const int h = hf & 15, b = hf >> 4;

  const int tid = threadIdx.x;
  const int lane = tid & 63;
  const int wv = tid >> 6;           // 0..7
  const int quad = lane >> 4;
  const int l16 = lane & 15;

  __shared__ __align__(16) bf16 Ks[2][64][64];  // linear, col-swizzled
  __shared__ __align__(16) bf16 Vt[2][80][72];  // [d][j]; row 64 = ones
  __shared__ __align__(16) bf16 Ps[128][64];    // P, XOR-swizzled

  const bf16* Qb_ = qkv + (size_t)b * S_ * D3_ + h * DH_;
  const bf16* Kb_ = Qb_ + 1024;
  const bf16* Vb_ = Qb_ + 2048;

  // init Vt extra rows (row 64 = 1, rows 65..79 = 0), both buffers
  for (int i = tid; i < 2 * 16 * 72; i += 512) {
    const int bb = i / (16 * 72), rr = (i / 72) % 16, cc = i % 72;
    Vt[bb][64 + rr][cc] = __float2bfloat16(rr == 0 ? 1.f : 0.f);
  }

  // Q as B-operand frag: queries qb + wv*16 + l16 (already scaled)
  short8 bq0, bq1;
  {
    const bf16* qrow = Qb_ + (size_t)(qb + wv * 16 + l16) * D3_ + quad * 8;
    bq0 = *(const short8*)(qrow);
    bq1 = *(const short8*)(qrow + 32);
  }

  floatx4 o[5];
#pragma unroll
  for (int fd = 0; fd < 5; fd++) o[fd] = {0.f, 0.f, 0.f, 0.f};

  // P LDS addressing (per-wave private rows, XOR swizzle on byte bits 4-6)
  const int prow = wv * 16 + l16;
  const int psw = (prow & 7) << 4;
  char* pbase = (char*)&Ps[0][0] + prow * 128;

  // K staging: thread covers Ks row tid>>3, slot tid&7 <- src col slot^ (row&7)
  const bf16* ksrc =
      Kb_ + (size_t)(tid >> 3) * D3_ + (((tid & 7) ^ ((tid >> 3) & 7)) * 8);
  bf16* kdst = &Ks[0][0][0] + tid * 8;
  // V staging: 1 uint4 -> 8 b16 scatters (transpose)
  const int vj = tid & 63, vd = (tid >> 6) * 8;

  const int ksw0 = (quad ^ (l16 & 7)) * 8;
  const int ksw1 = ((4 + quad) ^ (l16 & 7)) * 8;

  // prologue: issue K(0) gload, then V(0) register load (FIFO order matters:
  // the commit's implicit vmcnt wait on vreg also drains the older K gload)
  gload_lds16(ksrc, kdst);
  uint4 vreg = *(const uint4*)(Vb_ + (size_t)vj * D3_ + vd);

  int cur = 0;
  for (int t = 0; t < S_ / 64; t++) {
    // commit V(t) (auto vmcnt covers K(t) gload too)
    {
      bf16 tmp[8];
      *(uint4*)tmp = vreg;
#pragma unroll
      for (int e = 0; e < 8; e++) Vt[cur][vd + e][vj] = tmp[e];
    }
    __syncthreads();

    // prefetch tile t+1 (K async into LDS buf cur^1; V into registers)
    if (t + 1 < S_ / 64) {
      gload_lds16(ksrc + (size_t)(t + 1) * 64 * D3_, kdst + (cur ^ 1) * 4096);
      vreg = *(const uint4*)(Vb_ + (size_t)((t + 1) * 64 + vj) * D3_ + vd);
    }

    // S^T = K Q^T : lane holds keys fk*16 + quad*4 + r for query wv*16+l16
    float st[4][4];
    __builtin_amdgcn_s_setprio(1);
#pragma unroll
    for (int fk = 0; fk < 4; fk++) {
      const bf16* kp = &Ks[cur][fk * 16 + l16][0];
      short8 ak0 = *(const short8*)(kp + ksw0);
      short8 ak1 = *(const short8*)(kp + ksw1);
      floatx4 acc = {0.f, 0.f, 0.f, 0.f};
      acc = __builtin_amdgcn_mfma_f32_16x16x32_bf16(ak0, bq0, acc, 0, 0, 0);
      acc = __builtin_amdgcn_mfma_f32_16x16x32_bf16(ak1, bq1, acc, 0, 0, 0);
#pragma unroll
      for (int r = 0; r < 4; r++) st[fk][r] = acc[r];
    }
    __builtin_amdgcn_s_setprio(0);

    // P = exp2(S^T) (fixed max = 0)
#pragma unroll
    for (int fk = 0; fk < 4; fk++) {
      bf16 pk[4];
#pragma unroll
      for (int r = 0; r < 4; r++)
        pk[r] = __float2bfloat16(__builtin_amdgcn_exp2f(st[fk][r]));
      *(uint2*)(pbase + ((fk * 32 + quad * 8) ^ psw)) = *(uint2*)pk;
    }

    // O += P V  (fd=4 fragment vs ones-row computes l in o[4], col l16=0)
    short8 ap0 = *(const short8*)(pbase + ((quad * 16) ^ psw));
    short8 ap1 = *(const short8*)(pbase + ((64 + quad * 16) ^ psw));
    __builtin_amdgcn_s_setprio(1);
#pragma unroll
    for (int fd = 0; fd < 5; fd++) {
      short8 bv0 = *(const short8*)&Vt[cur][fd * 16 + l16][quad * 8];
      short8 bv1 = *(const short8*)&Vt[cur][fd * 16 + l16][32 + quad * 8];
      o[fd] = __builtin_amdgcn_mfma_f32_16x16x32_bf16(ap0, bv0, o[fd], 0, 0, 0);
      o[fd] = __builtin_amdgcn_mfma_f32_16x16x32_bf16(ap1, bv1, o[fd], 0, 0, 0);
    }
    __builtin_amdgcn_s_setprio(0);

    cur ^= 1;
  }

  // epilogue: l(q) sits in o[4][r] at lane quad*16 (l16=0)
#pragma unroll
  for (int r = 0; r < 4; r++) {
    const float lq = __shfl(o[4][r], quad << 4, 64);
    const float sc = out_scale / lq;
    const size_t base =
        ((size_t)(b * S_ + qb + wv * 16 + quad * 4 + r)) * D_ + h * DH_;
#pragma unroll
    for (int fd = 0; fd < 4; fd++)
      att[base + fd * 16 + l16] = __float2bfloat16(o[fd][r] * sc);
  }
}

// ---------------------------------------------------------------------------
extern "C" void kernel_launch(void* const* d_in, const int* in_sizes, int n_in,
                              void* d_out, int out_size, void* d_ws, size_t ws_size,
                              hipStream_t stream) {
  const float* x     = (const float*)d_in[0];
  const float* w_qkv = (const float*)d_in[1];
  const float* w_o   = (const float*)d_in[2];
  const float* w1    = (const float*)d_in[3];
  const float* b1    = (const float*)d_in[4];
  const float* w2    = (const float*)d_in[5];
  const float* b2    = (const float*)d_in[6];
  const float* ln1w  = (const float*)d_in[7];
  const float* ln1b  = (const float*)d_in[8];
  const float* ln2w  = (const float*)d_in[9];
  const float* ln2b  = (const float*)d_in[10];
  float* out = (float*)d_out;
  bf16* ws  = (bf16*)d_ws;

  // workspace layout (bf16 els), liveness-audited, peak 29,360,128 els (58.7MB)
  bf16* h1   = ws;                 // [0,4.19M)       live LN1->QKV
  bf16* wqb  = ws + 4194304;       // [4.19,7.34M)    live cvt->QKV
  bf16* qkv  = ws + 8388608;       // [8.39,20.97M)   live QKV->flash
  bf16* att  = ws + 20971520;      // [20.97,25.17M)  live flash->oproj
  bf16* wob  = ws + 25165824;      // [25.17,26.21M)  live cvt->oproj
  float* Po  = (float*)ws;         // [0,16.78M) = 8.39M f32, oproj->LN2
  bf16* w1b  = ws + 16777216;      // [16.78,20.97M)  live cvt_w1->FFN1 (qkv dead)
  bf16* h2   = ws + 20971520;      // [20.97,25.17M)  live LN2->FFN1 (att dead)
  bf16* g    = ws;                 // [0,16.78M)      live FFN1->FFN2 (Po dead)
  bf16* w2b  = ws + 16777216;      // [16.78,20.97M)  live cvt_w2->FFN2 (w1b dead)
  bf16* Pf   = ws + 20971520;      // [20.97,29.36M)  live FFN2->reduce (h2 dead)

  const float MM_SCALE   = (float)pow((double)S_ * S_ * DH_, -1.0 / 6.0);
  const float SM_SCALE   = (float)((double)S_ / sqrt(1.31 * 1.65));
  const float GELU_SCALE = (float)pow(0.588 * 0.675, -0.5);
  const float SQRT_TAU   = (float)sqrt(0.2);
  const float SQRT_1MT   = (float)sqrt(0.8);
  const float LOG2E      = 1.4426950408889634f;
  const float qkv_scale  = (float)pow((double)D_ * D3_, -0.25);
  const float o_scale    = (float)pow((double)D_ * D_, -0.25);
  const float w1_scale   = (float)pow((double)D_ * DF_, -0.25);
  const float w2_scale   = (float)pow((double)DF_ * D_, -0.25);

  // 1. convert w_qkv (permuted) + w_o
  cvt_qkv_o<<<4096, 256, 0, stream>>>(w_qkv, w_o, wqb, wob);
  // 2. LN1
  resid_ln_kernel<false, false, float, float><<<BS_, 256, 0, stream>>>(
      x, nullptr, nullptr, ln1w, ln1b, h1, 0.f, 0.f, nullptr, nullptr, 0.f, 0.f);
  // 3. QKV gemm -> head-major qkv (Q columns folded with MM_SCALE*LOG2E)
  gemm_mfma256<2, 1, bf16><<<dim3(192), 512, 0, stream>>>(
      h1, wqb, qkv, BS_, D3_, D_, qkv_scale, nullptr,
      qkv_scale * MM_SCALE * LOG2E);
  // 4. MFMA flash attention (fixed-max, XCD-local KV)
  flash_attn_mfma<<<dim3(S_ / 128, H_, B_), 512, 0, stream>>>(
      qkv, att, SM_SCALE * MM_SCALE);
  // 4.5 convert w1 (qkv dead after flash)
  cvt_f32_bf16<<<(DF_ * D_ / 4 + 255) / 256, 256, 0, stream>>>(w1, w1b, DF_ * D_ / 4);
  // 5. out-proj: 256x128 split-K=2, fp32 partial stores (256 blocks, full chip)
  gemm_mfma128<3, float><<<dim3(256), 512, 0, stream>>>(
      att, wob, Po, BS_, D_, D_ / 2, o_scale);
  // 6. residual(sum of 2 partials) + LN2; pre-init out = cs*xv + cb*b2
  resid_ln_kernel<true, true, float, float><<<BS_, 256, 0, stream>>>(
      Po, Po + (size_t)BS_ * D_, x, ln2w, ln2b, h2, SQRT_TAU, SQRT_1MT,
      out, b2, SQRT_TAU * w2_scale, SQRT_1MT);
  // 7. FFN1 + GELU (256 blocks)
  gemm_mfma256<1, 1, bf16><<<dim3(256), 512, 0, stream>>>(
      h2, w1b, g, BS_, DF_, D_, w1_scale, b1, GELU_SCALE);
  // 7.5 convert w2 (w1b dead after FFN1)
  cvt_f32_bf16<<<(D_ * DF_ / 4 + 255) / 256, 256, 0, stream>>>(w2, w2b, D_ * DF_ / 4);
  // 8. FFN2: 256x128 split-K=2, bf16 partial stores (256 blocks, full chip)
  gemm_mfma128<4, bf16><<<dim3(256), 512, 0, stream>>>(
      g, w2b, Pf, BS_, D_, DF_ / 2, 1.f);
  // 9. reduce partials into pre-init'd out
  reduce_ffn2<<<2048, 256, 0, stream>>>(
      Pf, Pf + (size_t)BS_ * D_, out, SQRT_TAU * w2_scale);
}

// Round 5
// 338.746 us; speedup vs baseline: 1.2315x; 1.0285x over previous
//
#include <hip/hip_runtime.h>
#include <hip/hip_bf16.h>
#include <math.h>

typedef __hip_bfloat16 bf16;
typedef __attribute__((ext_vector_type(8))) short short8;
typedef __attribute__((ext_vector_type(4))) float floatx4;

#define B_   2
#define S_   2048
#define D_   1024
#define H_   16
#define DH_  64
#define BS_  4096   // B_*S_
#define D3_  3072   // 3*D_
#define DF_  4096   // 4*D_

__device__ __forceinline__ float tof(float v) { return v; }
__device__ __forceinline__ float tof(bf16 v) { return __bfloat162float(v); }

// async global->LDS 16B copy: lane's data lands at readfirstlane(lds)+lane*16
__device__ __forceinline__ void gload_lds16(const bf16* g, bf16* l) {
  __builtin_amdgcn_global_load_lds(
      (const __attribute__((address_space(1))) unsigned int*)g,
      (__attribute__((address_space(3))) unsigned int*)l, 16, 0, 0);
}

#define VMCNT(n) asm volatile("s_waitcnt vmcnt(" #n ")" ::: "memory")

// ---------------------------------------------------------------------------
// fp32 -> bf16 weight conversion (vectorized x4)
// ---------------------------------------------------------------------------
__global__ __launch_bounds__(256) void cvt_f32_bf16(
    const float* __restrict__ in, bf16* __restrict__ out, int n4) {
  int i = blockIdx.x * 256 + threadIdx.x;
  if (i >= n4) return;
  float4 v = ((const float4*)in)[i];
  bf16 o[4] = {__float2bfloat16(v.x), __float2bfloat16(v.y),
               __float2bfloat16(v.z), __float2bfloat16(v.w)};
  ((ulong1*)out)[i] = *(ulong1*)o;
}

// ---------------------------------------------------------------------------
// Upfront fused convert: w_qkv fp32->bf16 with ROW PERMUTE n=d*48+z*16+h ->
// n2=z*1024+h*64+d (QKV gemm emits [b,s][z,h,d]), + plain w_o + plain w1.
// 2,097,152 groups of 4 els.
// ---------------------------------------------------------------------------
__global__ __launch_bounds__(256) void cvt_all(
    const float* __restrict__ wqkv, const float* __restrict__ wo,
    const float* __restrict__ w1, bf16* __restrict__ wqb,
    bf16* __restrict__ wob, bf16* __restrict__ w1b) {
  const int g = blockIdx.x * 256 + threadIdx.x;  // 4-el group
  if (g < 786432) {                              // 3072*1024/4 : permute+cvt
    const int n2 = g >> 8;                       // dest row (z,h,d)
    const int col = (g & 255) * 4;
    const int z = n2 >> 10, hh = (n2 >> 6) & 15, d = n2 & 63;
    const int n = d * 48 + z * 16 + hh;          // src row
    float4 v = *(const float4*)(wqkv + (size_t)n * 1024 + col);
    bf16 o[4] = {__float2bfloat16(v.x), __float2bfloat16(v.y),
                 __float2bfloat16(v.z), __float2bfloat16(v.w)};
    *(unsigned long long*)(wqb + (size_t)n2 * 1024 + col) =
        *(unsigned long long*)o;
  } else if (g < 1048576) {                      // w_o: 1024*1024/4 groups
    const int g2 = g - 786432;
    float4 v = ((const float4*)wo)[g2];
    bf16 o[4] = {__float2bfloat16(v.x), __float2bfloat16(v.y),
                 __float2bfloat16(v.z), __float2bfloat16(v.w)};
    ((unsigned long long*)wob)[g2] = *(unsigned long long*)o;
  } else {                                       // w1: 4096*1024/4 groups
    const int g2 = g - 1048576;
    float4 v = ((const float4*)w1)[g2];
    bf16 o[4] = {__float2bfloat16(v.x), __float2bfloat16(v.y),
                 __float2bfloat16(v.z), __float2bfloat16(v.w)};
    ((unsigned long long*)w1b)[g2] = *(unsigned long long*)o;
  }
}

// ---------------------------------------------------------------------------
// LayerNorm. FUSE: xv = st*(a[i]+a2[i]) + s1t*skip[i]  (a,a2 = bf16 raw
// split-K partials of the out-proj; st carries SQRT_TAU*o_scale).
// INIT: pre-init FFN2 output with the linear epilogue part:
//   oinit = cs*xv + cb*b2[col].
// ---------------------------------------------------------------------------
template <bool FUSE, bool INIT, typename TA, typename TS>
__global__ __launch_bounds__(256) void resid_ln_kernel(
    const TA* __restrict__ a, const TA* __restrict__ a2,
    const TS* __restrict__ skip,
    const float* __restrict__ w, const float* __restrict__ bias,
    bf16* __restrict__ hout, float st, float s1t,
    float* __restrict__ oinit, const float* __restrict__ b2,
    float cb, float cs) {
  const int row = blockIdx.x;
  const int tid = threadIdx.x;
  const int base = tid * 4;
  const size_t roff = (size_t)row * D_;

  float xv[4];
#pragma unroll
  for (int i = 0; i < 4; i++) {
    float v = tof(a[roff + base + i]);
    if (FUSE) v = st * (v + tof(a2[roff + base + i]))
                  + s1t * tof(skip[roff + base + i]);
    xv[i] = v;
  }
  if (INIT) {
#pragma unroll
    for (int i = 0; i < 4; i++)
      oinit[roff + base + i] = cs * xv[i] + cb * b2[base + i];
  }

  float ls = 0.f, lq = 0.f;
#pragma unroll
  for (int i = 0; i < 4; i++) { ls += xv[i]; lq += xv[i] * xv[i]; }

  __shared__ float ssum[256];
  __shared__ float ssq[256];
  ssum[tid] = ls; ssq[tid] = lq;
  __syncthreads();
  for (int off = 128; off > 0; off >>= 1) {
    if (tid < off) { ssum[tid] += ssum[tid + off]; ssq[tid] += ssq[tid + off]; }
    __syncthreads();
  }
  const float mean = ssum[0] * (1.0f / D_);
  const float var  = ssq[0] * (1.0f / D_) - mean * mean;
  const float rstd = rsqrtf(var + 1e-5f);

#pragma unroll
  for (int i = 0; i < 4; i++) {
    float v = (xv[i] - mean) * rstd * w[base + i] + bias[base + i];
    hout[roff + base + i] = __float2bfloat16(v);
  }
}

// ---------------------------------------------------------------------------
// FFN2 split-K reduce: out += sc*(p0[i] + p1[i]); out was pre-init'd by LN2.
// ---------------------------------------------------------------------------
__global__ __launch_bounds__(256) void reduce_ffn2(
    const bf16* __restrict__ p0, const bf16* __restrict__ p1,
    float* __restrict__ out, float sc) {
  const size_t i = ((size_t)blockIdx.x * 256 + threadIdx.x) * 8;
  short8 a = *(const short8*)(p0 + i);
  short8 b = *(const short8*)(p1 + i);
  bf16 t0[8], t1[8];
  *(short8*)t0 = a; *(short8*)t1 = b;
  float4 o0 = *(float4*)(out + i);
  float4 o1 = *(float4*)(out + i + 4);
#pragma unroll
  for (int e = 0; e < 4; e++) {
    ((float*)&o0)[e] += sc * (__bfloat162float(t0[e]) + __bfloat162float(t1[e]));
    ((float*)&o1)[e] += sc * (__bfloat162float(t0[e + 4]) + __bfloat162float(t1[e + 4]));
  }
  *(float4*)(out + i) = o0;
  *(float4*)(out + i + 4) = o1;
}

// ---------------------------------------------------------------------------
// 256x256 8-phase MFMA GEMM (T1+T2+T3+T4+T5). 512 thr = 8 waves (2Mx4N),
// BK=64, LDS 128 KiB. Used for the big-N GEMMs (QKV, FFN1).
// EPI: 1 = bias+GELU(tanh),store bf16; 2 = dual-scale (Q cols bn<1024 -> st).
// ---------------------------------------------------------------------------
template <int EPI, typename TC>
__global__ __launch_bounds__(512, 2) void gemm_mfma256(
    const bf16* __restrict__ A, const bf16* __restrict__ Bw,
    TC* __restrict__ C, int M, int N, int K, float scale,
    const float* __restrict__ bias, float st) {
  __shared__ __align__(16) bf16 As[2][2][128][64];  // [buf][chunk h][row][k]
  __shared__ __align__(16) bf16 Bs[2][2][128][64];  // [buf][chunk bh][row][k]

  const int tid = threadIdx.x;
  const int lane = tid & 63;
  const int w = tid >> 6;          // 0..7
  const int wm = w >> 2;           // 0..1  (M half)
  const int wn = w & 3;            // 0..3  (N quarter)
  const int quad = lane >> 4;
  const int l16 = lane & 15;

  // T1: XCD-aware block swizzle (nwg % 8 == 0 at every call site)
  const int nbx = N >> 8;
  const int nwg = nbx * (M >> 8);
  int bid = blockIdx.x;
  bid = (bid & 7) * (nwg >> 3) + (bid >> 3);
  const size_t bm = (size_t)(bid / nbx) * 256;
  const size_t bn = (size_t)(bid % nbx) * 256;

  // staging: chunk c in {0:A.h0, 1:B.bh0, 2:A.h1, 3:B.bh1}, 2 x 16B/thread
  const bf16* gsrc[4][2];
  bf16* ldsp[4][2];
#pragma unroll
  for (int i = 0; i < 2; i++) {
    const int G = tid + i * 512;               // granule 0..1023 within chunk
    const int cr = G >> 3;                     // chunk row 0..127
    const int gs8 = ((G & 7) ^ (cr & 7)) * 8;  // pre-swizzled source column
    const int ra = ((cr >> 6) << 7) + (cr & 63);       // A: + h*64
    const int rb = ((cr >> 5) << 6) + (cr & 31);       // B: + bh*32
    gsrc[0][i] = A  + (bm + ra) * (size_t)K + gs8;
    gsrc[2][i] = A  + (bm + ra + 64) * (size_t)K + gs8;
    gsrc[1][i] = Bw + (bn + rb) * (size_t)K + gs8;
    gsrc[3][i] = Bw + (bn + rb + 32) * (size_t)K + gs8;
    ldsp[0][i] = &As[0][0][0][0] + G * 8;
    ldsp[2][i] = &As[0][1][0][0] + G * 8;
    ldsp[1][i] = &Bs[0][0][0][0] + G * 8;
    ldsp[3][i] = &Bs[0][1][0][0] + G * 8;
  }

  auto STAGE = [&](int c, int tn) {
    const int boff = (tn & 1) * 16384;  // els between buf0/buf1
    gload_lds16(gsrc[c][0] + (size_t)tn * 64, ldsp[c][0] + boff);
    gload_lds16(gsrc[c][1] + (size_t)tn * 64, ldsp[c][1] + boff);
  };

  // swizzled k-granule offsets for ds_read
  const int ksw0 = (quad ^ (l16 & 7)) * 8;
  const int ksw1 = ((4 + quad) ^ (l16 & 7)) * 8;

  floatx4 acc[8][4];
#pragma unroll
  for (int i = 0; i < 8; i++)
#pragma unroll
    for (int j = 0; j < 4; j++) acc[i][j] = {0.f, 0.f, 0.f, 0.f};

  short8 af[4][2], bv[2][2];

  auto READ_A = [&](int b, int h) {
#pragma unroll
    for (int mf = 0; mf < 4; mf++) {
      const bf16* p = &As[b][h][wm * 64 + mf * 16 + l16][0];
      af[mf][0] = *(const short8*)(p + ksw0);
      af[mf][1] = *(const short8*)(p + ksw1);
    }
  };
  auto READ_B = [&](int b, int bh) {
#pragma unroll
    for (int nf = 0; nf < 2; nf++) {
      const bf16* p = &Bs[b][bh][wn * 32 + nf * 16 + l16][0];
      bv[nf][0] = *(const short8*)(p + ksw0);
      bv[nf][1] = *(const short8*)(p + ksw1);
    }
  };
  auto MFMA16 = [&](int mb, int nb) {
#pragma unroll
    for (int mf = 0; mf < 4; mf++)
#pragma unroll
      for (int nf = 0; nf < 2; nf++) {
        floatx4 c = acc[mb + mf][nb + nf];
        c = __builtin_amdgcn_mfma_f32_16x16x32_bf16(af[mf][0], bv[nf][0], c, 0, 0, 0);
        c = __builtin_amdgcn_mfma_f32_16x16x32_bf16(af[mf][1], bv[nf][1], c, 0, 0, 0);
        acc[mb + mf][nb + nf] = c;
      }
  };

  // prologue: full tile 0
  STAGE(0, 0); STAGE(1, 0); STAGE(2, 0); STAGE(3, 0);
  VMCNT(4);
  __builtin_amdgcn_s_barrier();
  __builtin_amdgcn_sched_barrier(0);

  const int NT = K >> 6;
#pragma unroll 1
  for (int t = 0; t < NT; t++) {
    const int b = t & 1;
    const bool nl = (t + 1 < NT);
    // ---- phase 1: Q00 ----
    READ_A(b, 0);
    READ_B(b, 0);
    if (nl) STAGE(0, t + 1);
    __builtin_amdgcn_s_barrier();
    __builtin_amdgcn_sched_barrier(0);
    __builtin_amdgcn_s_setprio(1);
    MFMA16(0, 0);
    __builtin_amdgcn_s_setprio(0);
    if (nl) { VMCNT(2); } else { VMCNT(0); }
    __builtin_amdgcn_s_barrier();
    __builtin_amdgcn_sched_barrier(0);
    // ---- phase 2: Q01 ----
    READ_B(b, 1);
    if (nl) STAGE(1, t + 1);
    __builtin_amdgcn_s_barrier();
    __builtin_amdgcn_sched_barrier(0);
    __builtin_amdgcn_s_setprio(1);
    MFMA16(0, 2);
    __builtin_amdgcn_s_setprio(0);
    __builtin_amdgcn_s_barrier();
    __builtin_amdgcn_sched_barrier(0);
    // ---- phase 3: Q11 ----
    READ_A(b, 1);
    if (nl) STAGE(2, t + 1);
    __builtin_amdgcn_s_barrier();
    __builtin_amdgcn_sched_barrier(0);
    __builtin_amdgcn_s_setprio(1);
    MFMA16(4, 2);
    __builtin_amdgcn_s_setprio(0);
    __builtin_amdgcn_s_barrier();
    __builtin_amdgcn_sched_barrier(0);
    // ---- phase 4: Q10 ----
    READ_B(b, 0);
    if (nl) STAGE(3, t + 1);
    __builtin_amdgcn_s_barrier();
    __builtin_amdgcn_sched_barrier(0);
    __builtin_amdgcn_s_setprio(1);
    MFMA16(4, 0);
    __builtin_amdgcn_s_setprio(0);
    if (nl) { VMCNT(4); } else { VMCNT(0); }
    __builtin_amdgcn_s_barrier();
    __builtin_amdgcn_sched_barrier(0);
  }

  // epilogue
  float sc_eff = scale;
  if (EPI == 2) sc_eff = (bn < 1024) ? st : scale;  // Q columns pre-scaled
  float bias4[4];
  if (EPI == 1) {
#pragma unroll
    for (int j = 0; j < 4; j++) bias4[j] = bias[bn + wn * 64 + j * 16 + l16];
  }
#pragma unroll
  for (int mi = 0; mi < 8; mi++) {
    const size_t r0 = bm + wm * 128 + (mi >> 2) * 64 + (mi & 3) * 16 + quad * 4;
#pragma unroll
    for (int r = 0; r < 4; r++) {
      const size_t rowoff = (r0 + r) * (size_t)N + bn + wn * 64 + l16;
#pragma unroll
      for (int j = 0; j < 4; j++) {
        float v = acc[mi][j][r];
        if (EPI == 2) {
          ((bf16*)C)[rowoff + j * 16] = __float2bfloat16(v * sc_eff);
        } else {
          // GELU (tanh form) via raw v_exp_f32 / v_rcp_f32
          float u = (v + bias4[j]) * scale;
          float tt = u * (0.7978845608f + 0.0356774081f * u * u);
          float e = __builtin_amdgcn_exp2f(tt * 2.8853900818f);  // exp(2*tt)
          float th = 1.0f - 2.0f * __builtin_amdgcn_rcpf(e + 1.0f);
          ((bf16*)C)[rowoff + j * 16] =
              __float2bfloat16(0.5f * u * (1.0f + th) * st);
        }
      }
    }
  }
}

// ---------------------------------------------------------------------------
// 256x128 8-phase MFMA GEMM, split-K=2 with bf16 raw partial stores (split 0
// -> C, split 1 -> C2; allows non-contiguous partial buffers). For N=1024
// GEMMs (out-proj, FFN2): 128 tiles x 2 splits = 256 blocks = full chip.
// 8 waves 2Mx4N, per-wave C = 128x32, acc[8][2]. LDS 96 KiB.
// ---------------------------------------------------------------------------
__global__ __launch_bounds__(512, 2) void gemm_mfma128(
    const bf16* __restrict__ A, const bf16* __restrict__ Bw,
    bf16* __restrict__ C, bf16* __restrict__ C2, int M, int N, int K) {
  __shared__ __align__(16) bf16 As[2][2][128][64];  // 64 KiB
  __shared__ __align__(16) bf16 Bs[2][2][64][64];   // 32 KiB

  const int tid = threadIdx.x;
  const int lane = tid & 63;
  const int w = tid >> 6;
  const int wm = w >> 2;           // 0..1
  const int wn = w & 3;            // 0..3 (32-col slice)
  const int quad = lane >> 4;
  const int l16 = lane & 15;

  const int nbx = N >> 7;
  const int nwg = nbx * (M >> 8) * 2;
  int bid = blockIdx.x;
  bid = (bid & 7) * (nwg >> 3) + (bid >> 3);
  const int split = bid & 1;
  const int tile = bid >> 1;
  const size_t bm = (size_t)(tile / nbx) * 256;
  const size_t bn = (size_t)(tile % nbx) * 128;
  const int lda = K * 2;
  const int koff = split * K;

  // A staging (2 chunks x 128 rows, 2 gloads each)
  const bf16* gA[2][2];
  bf16* lA[2][2];
#pragma unroll
  for (int i = 0; i < 2; i++) {
    const int G = tid + i * 512;
    const int cr = G >> 3;
    const int gs8 = ((G & 7) ^ (cr & 7)) * 8;
    const int ra = ((cr >> 6) << 7) + (cr & 63);
    gA[0][i] = A + (bm + ra) * (size_t)lda + koff + gs8;
    gA[1][i] = A + (bm + ra + 64) * (size_t)lda + koff + gs8;
    lA[0][i] = &As[0][0][0][0] + G * 8;
    lA[1][i] = &As[0][1][0][0] + G * 8;
  }
  // B staging (2 chunks x 64 rows, 1 gload each)
  const bf16* gB[2];
  bf16* lB[2];
  {
    const int cr = tid >> 3;
    const int gs8 = ((tid & 7) ^ (cr & 7)) * 8;
    gB[0] = Bw + (bn + cr) * (size_t)lda + koff + gs8;
    gB[1] = Bw + (bn + 64 + cr) * (size_t)lda + koff + gs8;
    lB[0] = &Bs[0][0][0][0] + tid * 8;
    lB[1] = &Bs[0][1][0][0] + tid * 8;
  }

  auto STAGE_A = [&](int h, int tn) {
    const int boff = (tn & 1) * 16384;
    gload_lds16(gA[h][0] + (size_t)tn * 64, lA[h][0] + boff);
    gload_lds16(gA[h][1] + (size_t)tn * 64, lA[h][1] + boff);
  };
  auto STAGE_B = [&](int bh, int tn) {
    const int boff = (tn & 1) * 8192;
    gload_lds16(gB[bh] + (size_t)tn * 64, lB[bh] + boff);
  };

  const int ksw0 = (quad ^ (l16 & 7)) * 8;
  const int ksw1 = ((4 + quad) ^ (l16 & 7)) * 8;

  floatx4 acc[8][2];
#pragma unroll
  for (int i = 0; i < 8; i++)
#pragma unroll
    for (int j = 0; j < 2; j++) acc[i][j] = {0.f, 0.f, 0.f, 0.f};

  short8 af[4][2], bv[2][2];

  auto READ_A = [&](int b, int h) {
#pragma unroll
    for (int mf = 0; mf < 4; mf++) {
      const bf16* p = &As[b][h][wm * 64 + mf * 16 + l16][0];
      af[mf][0] = *(const short8*)(p + ksw0);
      af[mf][1] = *(const short8*)(p + ksw1);
    }
  };
  // wave wn's cols live entirely in B chunk wn>>1, sub-rows (wn&1)*32
  auto READ_BNF = [&](int b, int nf) {
    const bf16* p = &Bs[b][wn >> 1][(wn & 1) * 32 + nf * 16 + l16][0];
    bv[nf][0] = *(const short8*)(p + ksw0);
    bv[nf][1] = *(const short8*)(p + ksw1);
  };
  auto MFMA8 = [&](int mb, int nf) {
#pragma unroll
    for (int mf = 0; mf < 4; mf++) {
      floatx4 c = acc[mb + mf][nf];
      c = __builtin_amdgcn_mfma_f32_16x16x32_bf16(af[mf][0], bv[nf][0], c, 0, 0, 0);
      c = __builtin_amdgcn_mfma_f32_16x16x32_bf16(af[mf][1], bv[nf][1], c, 0, 0, 0);
      acc[mb + mf][nf] = c;
    }
  };

  // prologue: tile 0 (6 loads); p1 needs C0,C1,C2 -> leave C3 (2) in flight
  STAGE_A(0, 0); STAGE_B(0, 0); STAGE_B(1, 0); STAGE_A(1, 0);
  VMCNT(2);
  __builtin_amdgcn_s_barrier();
  __builtin_amdgcn_sched_barrier(0);

  const int NT = K >> 6;
#pragma unroll 1
  for (int t = 0; t < NT; t++) {
    const int b = t & 1;
    const bool nl = (t + 1 < NT);
    // ---- p1: A.h0 x nf0 ----
    READ_A(b, 0);
    READ_BNF(b, 0);
    if (nl) STAGE_A(0, t + 1);
    __builtin_amdgcn_s_barrier();
    __builtin_amdgcn_sched_barrier(0);
    __builtin_amdgcn_s_setprio(1);
    MFMA8(0, 0);
    __builtin_amdgcn_s_setprio(0);
    __builtin_amdgcn_s_barrier();
    __builtin_amdgcn_sched_barrier(0);
    // ---- p2: A.h0 x nf1 ----
    READ_BNF(b, 1);
    if (nl) STAGE_B(0, t + 1);
    __builtin_amdgcn_s_barrier();
    __builtin_amdgcn_sched_barrier(0);
    __builtin_amdgcn_s_setprio(1);
    MFMA8(0, 1);
    __builtin_amdgcn_s_setprio(0);
    if (nl) { VMCNT(3); } else { VMCNT(0); }
    __builtin_amdgcn_s_barrier();
    __builtin_amdgcn_sched_barrier(0);
    // ---- p3: A.h1 x nf1 ----
    READ_A(b, 1);
    if (nl) STAGE_B(1, t + 1);
    __builtin_amdgcn_s_barrier();
    __builtin_amdgcn_sched_barrier(0);
    __builtin_amdgcn_s_setprio(1);
    MFMA8(4, 1);
    __builtin_amdgcn_s_setprio(0);
    __builtin_amdgcn_s_barrier();
    __builtin_amdgcn_sched_barrier(0);
    // ---- p4: A.h1 x nf0 (bv[0] reused from p1) ----
    if (nl) STAGE_A(1, t + 1);
    __builtin_amdgcn_s_barrier();
    __builtin_amdgcn_sched_barrier(0);
    __builtin_amdgcn_s_setprio(1);
    MFMA8(4, 0);
    __builtin_amdgcn_s_setprio(0);
    if (nl) { VMCNT(2); } else { VMCNT(0); }
    __builtin_amdgcn_s_barrier();
    __builtin_amdgcn_sched_barrier(0);
  }

  // epilogue: raw bf16 partial store; split 0 -> C, split 1 -> C2
  bf16* dst = split ? C2 : C;
#pragma unroll
  for (int mi = 0; mi < 8; mi++) {
    const size_t r0 = bm + wm * 128 + (mi >> 2) * 64 + (mi & 3) * 16 + quad * 4;
#pragma unroll
    for (int r = 0; r < 4; r++) {
      const size_t rowoff = (r0 + r) * (size_t)N + bn + wn * 32 + l16;
#pragma unroll
      for (int j = 0; j < 2; j++)
        dst[rowoff + j * 16] = __float2bfloat16(acc[mi][j][r]);
    }
  }
}

// ---------------------------------------------------------------------------
// MFMA flash attention, S^T scheme, 512 threads = 8 waves, QT=128, KT=64.
// FIXED-MAX softmax (Q pre-scaled by MM_SCALE*LOG2E in the QKV gemm).
// - XCD-locality remap: 4 (b,h) pairs per XCD (KV 2MB fits 4MB L2).
// - K staged via gload_lds16 with T2 XOR swizzle (source-side + ds_read).
// - l via per-lane VALU partial + xor16/32 butterfly at the end (r2 scheme).
// LDS 50 KiB -> 3 blocks/CU.
// ---------------------------------------------------------------------------
__global__ __launch_bounds__(512) void flash_attn_mfma(
    const bf16* __restrict__ qkv, bf16* __restrict__ att, float out_scale) {
  const int flat = (blockIdx.z * H_ + blockIdx.y) * (S_ / 128) + blockIdx.x;
  const int g8 = flat & 7, slot = flat >> 3;
  const int hf = g8 * 4 + (slot >> 4);   // (b,h) flat index 0..31
  const int qb = (slot & 15) * 128;
  const int h = hf & 15, b = hf >> 4;

  const int tid = threadIdx.x;
  const int lane = tid & 63;
  const int wv = tid >> 6;           // 0..7
  const int quad = lane >> 4;
  const int l16 = lane & 15;

  __shared__ __align__(16) bf16 Ks[2][64][64];  // linear, col-swizzled
  __shared__ __align__(16) bf16 Vt[2][64][72];  // Vt[d][j] = V[j][d]
  __shared__ __align__(16) bf16 Ps[128][64];    // P, XOR-swizzled

  const bf16* Qb_ = qkv + (size_t)b * S_ * D3_ + h * DH_;
  const bf16* Kb_ = Qb_ + 1024;
  const bf16* Vb_ = Qb_ + 2048;

  // Q as B-operand frag: queries qb + wv*16 + l16 (already scaled)
  short8 bq0, bq1;
  {
    const bf16* qrow = Qb_ + (size_t)(qb + wv * 16 + l16) * D3_ + quad * 8;
    bq0 = *(const short8*)(qrow);
    bq1 = *(const short8*)(qrow + 32);
  }

  float l_part = 0.f;
  floatx4 o[4];
#pragma unroll
  for (int fd = 0; fd < 4; fd++) o[fd] = {0.f, 0.f, 0.f, 0.f};

  // P LDS addressing (per-wave private rows, XOR swizzle on byte bits 4-6)
  const int prow = wv * 16 + l16;
  const int psw = (prow & 7) << 4;
  char* pbase = (char*)&Ps[0][0] + prow * 128;

  // K staging: thread covers Ks row tid>>3, slot tid&7 <- src col slot^(row&7)
  const bf16* ksrc =
      Kb_ + (size_t)(tid >> 3) * D3_ + (((tid & 7) ^ ((tid >> 3) & 7)) * 8);
  bf16* kdst = &Ks[0][0][0] + tid * 8;
  // V staging: 1 uint4 -> 8 b16 scatters (transpose)
  const int vj = tid & 63, vd = (tid >> 6) * 8;

  const int ksw0 = (quad ^ (l16 & 7)) * 8;
  const int ksw1 = ((4 + quad) ^ (l16 & 7)) * 8;

  // prologue: issue K(0) gload, then V(0) register load (FIFO order matters:
  // the commit's implicit vmcnt wait on vreg also drains the older K gload)
  gload_lds16(ksrc, kdst);
  uint4 vreg = *(const uint4*)(Vb_ + (size_t)vj * D3_ + vd);

  int cur = 0;
  for (int t = 0; t < S_ / 64; t++) {
    // commit V(t) (auto vmcnt covers K(t) gload too)
    {
      bf16 tmp[8];
      *(uint4*)tmp = vreg;
#pragma unroll
      for (int e = 0; e < 8; e++) Vt[cur][vd + e][vj] = tmp[e];
    }
    __syncthreads();

    // prefetch tile t+1 (K async into LDS buf cur^1; V into registers)
    if (t + 1 < S_ / 64) {
      gload_lds16(ksrc + (size_t)(t + 1) * 64 * D3_, kdst + (cur ^ 1) * 4096);
      vreg = *(const uint4*)(Vb_ + (size_t)((t + 1) * 64 + vj) * D3_ + vd);
    }

    // S^T = K Q^T : lane holds keys fk*16 + quad*4 + r for query wv*16+l16
    float st[4][4];
    __builtin_amdgcn_s_setprio(1);
#pragma unroll
    for (int fk = 0; fk < 4; fk++) {
      const bf16* kp = &Ks[cur][fk * 16 + l16][0];
      short8 ak0 = *(const short8*)(kp + ksw0);
      short8 ak1 = *(const short8*)(kp + ksw1);
      floatx4 acc = {0.f, 0.f, 0.f, 0.f};
      acc = __builtin_amdgcn_mfma_f32_16x16x32_bf16(ak0, bq0, acc, 0, 0, 0);
      acc = __builtin_amdgcn_mfma_f32_16x16x32_bf16(ak1, bq1, acc, 0, 0, 0);
#pragma unroll
      for (int r = 0; r < 4; r++) st[fk][r] = acc[r];
    }
    __builtin_amdgcn_s_setprio(0);

    // P = exp2(S^T), interleaved: fk 0,1 first so ap0's deps resolve early
#pragma unroll
    for (int fk = 0; fk < 2; fk++) {
      bf16 pk[4];
#pragma unroll
      for (int r = 0; r < 4; r++) {
        const float p = __builtin_amdgcn_exp2f(st[fk][r]);
        l_part += p;
        pk[r] = __float2bfloat16(p);
      }
      *(uint2*)(pbase + ((fk * 32 + quad * 8) ^ psw)) = *(uint2*)pk;
    }
    short8 ap0 = *(const short8*)(pbase + ((quad * 16) ^ psw));
#pragma unroll
    for (int fk = 2; fk < 4; fk++) {
      bf16 pk[4];
#pragma unroll
      for (int r = 0; r < 4; r++) {
        const float p = __builtin_amdgcn_exp2f(st[fk][r]);
        l_part += p;
        pk[r] = __float2bfloat16(p);
      }
      *(uint2*)(pbase + ((fk * 32 + quad * 8) ^ psw)) = *(uint2*)pk;
    }
    short8 ap1 = *(const short8*)(pbase + ((64 + quad * 16) ^ psw));

    // O += P V
    __builtin_amdgcn_s_setprio(1);
#pragma unroll
    for (int fd = 0; fd < 4; fd++) {
      short8 bv0 = *(const short8*)&Vt[cur][fd * 16 + l16][quad * 8];
      short8 bv1 = *(const short8*)&Vt[cur][fd * 16 + l16][32 + quad * 8];
      o[fd] = __builtin_amdgcn_mfma_f32_16x16x32_bf16(ap0, bv0, o[fd], 0, 0, 0);
      o[fd] = __builtin_amdgcn_mfma_f32_16x16x32_bf16(ap1, bv1, o[fd], 0, 0, 0);
    }
    __builtin_amdgcn_s_setprio(0);

    cur ^= 1;
  }

  // final l: sum quads (butterfly), then pick query quad*4+r's value
  l_part += __shfl_xor(l_part, 16);
  l_part += __shfl_xor(l_part, 32);
#pragma unroll
  for (int r = 0; r < 4; r++) {
    const float lq = __shfl(l_part, quad * 4 + r, 64);
    const float sc = out_scale / lq;
    const size_t base =
        ((size_t)(b * S_ + qb + wv * 16 + quad * 4 + r)) * D_ + h * DH_;
#pragma unroll
    for (int fd = 0; fd < 4; fd++)
      att[base + fd * 16 + l16] = __float2bfloat16(o[fd][r] * sc);
  }
}

// ---------------------------------------------------------------------------
extern "C" void kernel_launch(void* const* d_in, const int* in_sizes, int n_in,
                              void* d_out, int out_size, void* d_ws, size_t ws_size,
                              hipStream_t stream) {
  const float* x     = (const float*)d_in[0];
  const float* w_qkv = (const float*)d_in[1];
  const float* w_o   = (const float*)d_in[2];
  const float* w1    = (const float*)d_in[3];
  const float* b1    = (const float*)d_in[4];
  const float* w2    = (const float*)d_in[5];
  const float* b2    = (const float*)d_in[6];
  const float* ln1w  = (const float*)d_in[7];
  const float* ln1b  = (const float*)d_in[8];
  const float* ln2w  = (const float*)d_in[9];
  const float* ln2b  = (const float*)d_in[10];
  float* out = (float*)d_out;
  bf16* ws  = (bf16*)d_ws;

  // workspace layout (bf16 els), liveness-audited, peak 29,360,128 els (58.7MB)
  // order: cvt_all, LN1, QKV, cvt_w2, flash, oproj, LN2, FFN1, FFN2, reduce
  bf16* h1   = ws;                 // [0,4.19M)       live LN1->QKV
  bf16* wqb  = ws + 4194304;       // [4.19,7.34M)    live cvt_all->QKV
  bf16* wob  = ws + 7340032;       // [7.34,8.39M)    live cvt_all->oproj
  bf16* qkv  = ws + 8388608;       // [8.39,20.97M)   live QKV->flash
  bf16* att  = ws + 20971520;      // [20.97,25.17M)  live flash->oproj
  bf16* w1b  = ws + 25165824;      // [25.17,29.36M)  live cvt_all->FFN1
  bf16* w2b  = ws;                 // [0,4.19M)       live cvt_w2->FFN2 (h1 dead)
  bf16* Po   = ws + 8388608;       // [8.39,16.78M)   2x4.19M, oproj->LN2 (qkv dead)
  bf16* h2   = ws + 4194304;       // [4.19,8.39M)    live LN2->FFN1 (wqb/wob dead)
  bf16* g    = ws + 8388608;       // [8.39,25.17M)   live FFN1->FFN2 (Po/att dead)
  bf16* Pf0  = ws + 4194304;       // [4.19,8.39M)    live FFN2->reduce (h2 dead)
  bf16* Pf1  = ws + 25165824;      // [25.17,29.36M)  live FFN2->reduce (w1b dead)

  const float MM_SCALE   = (float)pow((double)S_ * S_ * DH_, -1.0 / 6.0);
  const float SM_SCALE   = (float)((double)S_ / sqrt(1.31 * 1.65));
  const float GELU_SCALE = (float)pow(0.588 * 0.675, -0.5);
  const float SQRT_TAU   = (float)sqrt(0.2);
  const float SQRT_1MT   = (float)sqrt(0.8);
  const float LOG2E      = 1.4426950408889634f;
  const float qkv_scale  = (float)pow((double)D_ * D3_, -0.25);
  const float o_scale    = (float)pow((double)D_ * D_, -0.25);
  const float w1_scale   = (float)pow((double)D_ * DF_, -0.25);
  const float w2_scale   = (float)pow((double)DF_ * D_, -0.25);

  // 1. upfront converts: w_qkv (permuted) + w_o + w1
  cvt_all<<<8192, 256, 0, stream>>>(w_qkv, w_o, w1, wqb, wob, w1b);
  // 2. LN1
  resid_ln_kernel<false, false, float, float><<<BS_, 256, 0, stream>>>(
      x, nullptr, nullptr, ln1w, ln1b, h1, 0.f, 0.f, nullptr, nullptr, 0.f, 0.f);
  // 3. QKV gemm -> head-major qkv (Q columns folded with MM_SCALE*LOG2E)
  gemm_mfma256<2, bf16><<<dim3(192), 512, 0, stream>>>(
      h1, wqb, qkv, BS_, D3_, D_, qkv_scale, nullptr,
      qkv_scale * MM_SCALE * LOG2E);
  // 3.5 convert w2 into h1's slot (h1 dead after QKV)
  cvt_f32_bf16<<<4096, 256, 0, stream>>>(w2, w2b, D_ * DF_ / 4);
  // 4. MFMA flash attention (fixed-max, XCD-local KV, 3 blocks/CU)
  flash_attn_mfma<<<dim3(S_ / 128, H_, B_), 512, 0, stream>>>(
      qkv, att, SM_SCALE * MM_SCALE);
  // 5. out-proj: 256x128 split-K=2, bf16 raw partials (256 blocks, full chip)
  gemm_mfma128<<<dim3(256), 512, 0, stream>>>(
      att, wob, Po, Po + (size_t)BS_ * D_, BS_, D_, D_ / 2);
  // 6. residual(o_scale*(p0+p1)) + LN2; pre-init out = cs*xv + cb*b2
  resid_ln_kernel<true, true, bf16, float><<<BS_, 256, 0, stream>>>(
      Po, Po + (size_t)BS_ * D_, x, ln2w, ln2b, h2,
      SQRT_TAU * o_scale, SQRT_1MT, out, b2, SQRT_TAU * w2_scale, SQRT_1MT);
  // 7. FFN1 + GELU (256 blocks)
  gemm_mfma256<1, bf16><<<dim3(256), 512, 0, stream>>>(
      h2, w1b, g, BS_, DF_, D_, w1_scale, b1, GELU_SCALE);
  // 8. FFN2: 256x128 split-K=2, bf16 raw partials (256 blocks, full chip)
  gemm_mfma128<<<dim3(256), 512, 0, stream>>>(
      g, w2b, Pf0, Pf1, BS_, D_, DF_ / 2);
  // 9. reduce partials into pre-init'd out
  reduce_ffn2<<<2048, 256, 0, stream>>>(Pf0, Pf1, out, SQRT_TAU * w2_scale);
}

// Round 6
// 338.436 us; speedup vs baseline: 1.2327x; 1.0009x over previous
//
#include <hip/hip_runtime.h>
#include <hip/hip_bf16.h>
#include <math.h>

typedef __hip_bfloat16 bf16;
typedef __attribute__((ext_vector_type(8))) short short8;
typedef __attribute__((ext_vector_type(4))) float floatx4;

#define B_   2
#define S_   2048
#define D_   1024
#define H_   16
#define DH_  64
#define BS_  4096   // B_*S_
#define D3_  3072   // 3*D_
#define DF_  4096   // 4*D_

__device__ __forceinline__ float tof(float v) { return v; }
__device__ __forceinline__ float tof(bf16 v) { return __bfloat162float(v); }

// async global->LDS 16B copy: lane's data lands at readfirstlane(lds)+lane*16
__device__ __forceinline__ void gload_lds16(const bf16* g, bf16* l) {
  __builtin_amdgcn_global_load_lds(
      (const __attribute__((address_space(1))) unsigned int*)g,
      (__attribute__((address_space(3))) unsigned int*)l, 16, 0, 0);
}

#define VMCNT(n) asm volatile("s_waitcnt vmcnt(" #n ")" ::: "memory")

// ---------------------------------------------------------------------------
// fp32 -> bf16 weight conversion (vectorized x4)
// ---------------------------------------------------------------------------
__global__ __launch_bounds__(256) void cvt_f32_bf16(
    const float* __restrict__ in, bf16* __restrict__ out, int n4) {
  int i = blockIdx.x * 256 + threadIdx.x;
  if (i >= n4) return;
  float4 v = ((const float4*)in)[i];
  bf16 o[4] = {__float2bfloat16(v.x), __float2bfloat16(v.y),
               __float2bfloat16(v.z), __float2bfloat16(v.w)};
  ((ulong1*)out)[i] = *(ulong1*)o;
}

// ---------------------------------------------------------------------------
// Upfront fused convert: w_qkv fp32->bf16 with ROW PERMUTE n=d*48+z*16+h ->
// n2=z*1024+h*64+d (QKV gemm emits [b,s][z,h,d]), + plain w_o + plain w1.
// ---------------------------------------------------------------------------
__global__ __launch_bounds__(256) void cvt_all(
    const float* __restrict__ wqkv, const float* __restrict__ wo,
    const float* __restrict__ w1, bf16* __restrict__ wqb,
    bf16* __restrict__ wob, bf16* __restrict__ w1b) {
  const int g = blockIdx.x * 256 + threadIdx.x;  // 4-el group
  if (g < 786432) {                              // 3072*1024/4 : permute+cvt
    const int n2 = g >> 8;                       // dest row (z,h,d)
    const int col = (g & 255) * 4;
    const int z = n2 >> 10, hh = (n2 >> 6) & 15, d = n2 & 63;
    const int n = d * 48 + z * 16 + hh;          // src row
    float4 v = *(const float4*)(wqkv + (size_t)n * 1024 + col);
    bf16 o[4] = {__float2bfloat16(v.x), __float2bfloat16(v.y),
                 __float2bfloat16(v.z), __float2bfloat16(v.w)};
    *(unsigned long long*)(wqb + (size_t)n2 * 1024 + col) =
        *(unsigned long long*)o;
  } else if (g < 1048576) {                      // w_o: 1024*1024/4 groups
    const int g2 = g - 786432;
    float4 v = ((const float4*)wo)[g2];
    bf16 o[4] = {__float2bfloat16(v.x), __float2bfloat16(v.y),
                 __float2bfloat16(v.z), __float2bfloat16(v.w)};
    ((unsigned long long*)wob)[g2] = *(unsigned long long*)o;
  } else {                                       // w1: 4096*1024/4 groups
    const int g2 = g - 1048576;
    float4 v = ((const float4*)w1)[g2];
    bf16 o[4] = {__float2bfloat16(v.x), __float2bfloat16(v.y),
                 __float2bfloat16(v.z), __float2bfloat16(v.w)};
    ((unsigned long long*)w1b)[g2] = *(unsigned long long*)o;
  }
}

// ---------------------------------------------------------------------------
// LayerNorm. FUSE: xv = st*(a[i]+a2[i]) + s1t*skip[i]  (a,a2 = bf16 raw
// split-K partials of the out-proj; st carries SQRT_TAU*o_scale).
// INIT: pre-init FFN2 output with the linear epilogue part.
// ---------------------------------------------------------------------------
template <bool FUSE, bool INIT, typename TA, typename TS>
__global__ __launch_bounds__(256) void resid_ln_kernel(
    const TA* __restrict__ a, const TA* __restrict__ a2,
    const TS* __restrict__ skip,
    const float* __restrict__ w, const float* __restrict__ bias,
    bf16* __restrict__ hout, float st, float s1t,
    float* __restrict__ oinit, const float* __restrict__ b2,
    float cb, float cs) {
  const int row = blockIdx.x;
  const int tid = threadIdx.x;
  const int base = tid * 4;
  const size_t roff = (size_t)row * D_;

  float xv[4];
#pragma unroll
  for (int i = 0; i < 4; i++) {
    float v = tof(a[roff + base + i]);
    if (FUSE) v = st * (v + tof(a2[roff + base + i]))
                  + s1t * tof(skip[roff + base + i]);
    xv[i] = v;
  }
  if (INIT) {
#pragma unroll
    for (int i = 0; i < 4; i++)
      oinit[roff + base + i] = cs * xv[i] + cb * b2[base + i];
  }

  float ls = 0.f, lq = 0.f;
#pragma unroll
  for (int i = 0; i < 4; i++) { ls += xv[i]; lq += xv[i] * xv[i]; }

  __shared__ float ssum[256];
  __shared__ float ssq[256];
  ssum[tid] = ls; ssq[tid] = lq;
  __syncthreads();
  for (int off = 128; off > 0; off >>= 1) {
    if (tid < off) { ssum[tid] += ssum[tid + off]; ssq[tid] += ssq[tid + off]; }
    __syncthreads();
  }
  const float mean = ssum[0] * (1.0f / D_);
  const float var  = ssq[0] * (1.0f / D_) - mean * mean;
  const float rstd = rsqrtf(var + 1e-5f);

#pragma unroll
  for (int i = 0; i < 4; i++) {
    float v = (xv[i] - mean) * rstd * w[base + i] + bias[base + i];
    hout[roff + base + i] = __float2bfloat16(v);
  }
}

// ---------------------------------------------------------------------------
// FFN2 split-K reduce: out += sc*(p0[i] + p1[i]); out was pre-init'd by LN2.
// ---------------------------------------------------------------------------
__global__ __launch_bounds__(256) void reduce_ffn2(
    const bf16* __restrict__ p0, const bf16* __restrict__ p1,
    float* __restrict__ out, float sc) {
  const size_t i = ((size_t)blockIdx.x * 256 + threadIdx.x) * 8;
  short8 a = *(const short8*)(p0 + i);
  short8 b = *(const short8*)(p1 + i);
  bf16 t0[8], t1[8];
  *(short8*)t0 = a; *(short8*)t1 = b;
  float4 o0 = *(float4*)(out + i);
  float4 o1 = *(float4*)(out + i + 4);
#pragma unroll
  for (int e = 0; e < 4; e++) {
    ((float*)&o0)[e] += sc * (__bfloat162float(t0[e]) + __bfloat162float(t1[e]));
    ((float*)&o1)[e] += sc * (__bfloat162float(t0[e + 4]) + __bfloat162float(t1[e + 4]));
  }
  *(float4*)(out + i) = o0;
  *(float4*)(out + i + 4) = o1;
}

// ---------------------------------------------------------------------------
// Flash KV-split combine: att[i] = (O0[i]+O1[i]) * sc / (l0+l1). In-place
// over O0's buffer is safe (elementwise).
// ---------------------------------------------------------------------------
__global__ __launch_bounds__(256) void combine_attn(
    const bf16* __restrict__ O0, const bf16* __restrict__ O1,
    const float* __restrict__ l0, const float* __restrict__ l1,
    bf16* __restrict__ att, float sc) {
  const size_t i = ((size_t)blockIdx.x * 256 + threadIdx.x) * 8;
  const int srow = (int)(i >> 10);      // (b*S+s), D=1024
  const int h = (int)(i >> 6) & 15;
  const float inv = sc / (l0[srow * H_ + h] + l1[srow * H_ + h]);
  short8 a = *(const short8*)(O0 + i);
  short8 b = *(const short8*)(O1 + i);
  bf16 t0[8], t1[8], o[8];
  *(short8*)t0 = a; *(short8*)t1 = b;
#pragma unroll
  for (int e = 0; e < 8; e++)
    o[e] = __float2bfloat16((tof(t0[e]) + tof(t1[e])) * inv);
  *(short8*)(att + i) = *(short8*)o;
}

// ---------------------------------------------------------------------------
// 256x256 8-phase MFMA GEMM (T1+T2+T3+T4+T5). 512 thr = 8 waves (2Mx4N),
// BK=64, LDS 128 KiB. Used for the big-N GEMMs (QKV, FFN1).
// EPI: 1 = bias+GELU(tanh),store bf16; 2 = dual-scale (Q cols bn<1024 -> st).
// ---------------------------------------------------------------------------
template <int EPI, typename TC>
__global__ __launch_bounds__(512, 2) void gemm_mfma256(
    const bf16* __restrict__ A, const bf16* __restrict__ Bw,
    TC* __restrict__ C, int M, int N, int K, float scale,
    const float* __restrict__ bias, float st) {
  __shared__ __align__(16) bf16 As[2][2][128][64];  // [buf][chunk h][row][k]
  __shared__ __align__(16) bf16 Bs[2][2][128][64];  // [buf][chunk bh][row][k]

  const int tid = threadIdx.x;
  const int lane = tid & 63;
  const int w = tid >> 6;          // 0..7
  const int wm = w >> 2;           // 0..1  (M half)
  const int wn = w & 3;            // 0..3  (N quarter)
  const int quad = lane >> 4;
  const int l16 = lane & 15;

  // T1: XCD-aware block swizzle (nwg % 8 == 0 at every call site)
  const int nbx = N >> 8;
  const int nwg = nbx * (M >> 8);
  int bid = blockIdx.x;
  bid = (bid & 7) * (nwg >> 3) + (bid >> 3);
  const size_t bm = (size_t)(bid / nbx) * 256;
  const size_t bn = (size_t)(bid % nbx) * 256;

  // staging: chunk c in {0:A.h0, 1:B.bh0, 2:A.h1, 3:B.bh1}, 2 x 16B/thread
  const bf16* gsrc[4][2];
  bf16* ldsp[4][2];
#pragma unroll
  for (int i = 0; i < 2; i++) {
    const int G = tid + i * 512;               // granule 0..1023 within chunk
    const int cr = G >> 3;                     // chunk row 0..127
    const int gs8 = ((G & 7) ^ (cr & 7)) * 8;  // pre-swizzled source column
    const int ra = ((cr >> 6) << 7) + (cr & 63);       // A: + h*64
    const int rb = ((cr >> 5) << 6) + (cr & 31);       // B: + bh*32
    gsrc[0][i] = A  + (bm + ra) * (size_t)K + gs8;
    gsrc[2][i] = A  + (bm + ra + 64) * (size_t)K + gs8;
    gsrc[1][i] = Bw + (bn + rb) * (size_t)K + gs8;
    gsrc[3][i] = Bw + (bn + rb + 32) * (size_t)K + gs8;
    ldsp[0][i] = &As[0][0][0][0] + G * 8;
    ldsp[2][i] = &As[0][1][0][0] + G * 8;
    ldsp[1][i] = &Bs[0][0][0][0] + G * 8;
    ldsp[3][i] = &Bs[0][1][0][0] + G * 8;
  }

  auto STAGE = [&](int c, int tn) {
    const int boff = (tn & 1) * 16384;  // els between buf0/buf1
    gload_lds16(gsrc[c][0] + (size_t)tn * 64, ldsp[c][0] + boff);
    gload_lds16(gsrc[c][1] + (size_t)tn * 64, ldsp[c][1] + boff);
  };

  // swizzled k-granule offsets for ds_read
  const int ksw0 = (quad ^ (l16 & 7)) * 8;
  const int ksw1 = ((4 + quad) ^ (l16 & 7)) * 8;

  floatx4 acc[8][4];
#pragma unroll
  for (int i = 0; i < 8; i++)
#pragma unroll
    for (int j = 0; j < 4; j++) acc[i][j] = {0.f, 0.f, 0.f, 0.f};

  short8 af[4][2], bv[2][2];

  auto READ_A = [&](int b, int h) {
#pragma unroll
    for (int mf = 0; mf < 4; mf++) {
      const bf16* p = &As[b][h][wm * 64 + mf * 16 + l16][0];
      af[mf][0] = *(const short8*)(p + ksw0);
      af[mf][1] = *(const short8*)(p + ksw1);
    }
  };
  auto READ_B = [&](int b, int bh) {
#pragma unroll
    for (int nf = 0; nf < 2; nf++) {
      const bf16* p = &Bs[b][bh][wn * 32 + nf * 16 + l16][0];
      bv[nf][0] = *(const short8*)(p + ksw0);
      bv[nf][1] = *(const short8*)(p + ksw1);
    }
  };
  auto MFMA16 = [&](int mb, int nb) {
#pragma unroll
    for (int mf = 0; mf < 4; mf++)
#pragma unroll
      for (int nf = 0; nf < 2; nf++) {
        floatx4 c = acc[mb + mf][nb + nf];
        c = __builtin_amdgcn_mfma_f32_16x16x32_bf16(af[mf][0], bv[nf][0], c, 0, 0, 0);
        c = __builtin_amdgcn_mfma_f32_16x16x32_bf16(af[mf][1], bv[nf][1], c, 0, 0, 0);
        acc[mb + mf][nb + nf] = c;
      }
  };

  // prologue: full tile 0
  STAGE(0, 0); STAGE(1, 0); STAGE(2, 0); STAGE(3, 0);
  VMCNT(4);
  __builtin_amdgcn_s_barrier();
  __builtin_amdgcn_sched_barrier(0);

  const int NT = K >> 6;
#pragma unroll 1
  for (int t = 0; t < NT; t++) {
    const int b = t & 1;
    const bool nl = (t + 1 < NT);
    // ---- phase 1: Q00 ----
    READ_A(b, 0);
    READ_B(b, 0);
    if (nl) STAGE(0, t + 1);
    __builtin_amdgcn_s_barrier();
    __builtin_amdgcn_sched_barrier(0);
    __builtin_amdgcn_s_setprio(1);
    MFMA16(0, 0);
    __builtin_amdgcn_s_setprio(0);
    if (nl) { VMCNT(2); } else { VMCNT(0); }
    __builtin_amdgcn_s_barrier();
    __builtin_amdgcn_sched_barrier(0);
    // ---- phase 2: Q01 ----
    READ_B(b, 1);
    if (nl) STAGE(1, t + 1);
    __builtin_amdgcn_s_barrier();
    __builtin_amdgcn_sched_barrier(0);
    __builtin_amdgcn_s_setprio(1);
    MFMA16(0, 2);
    __builtin_amdgcn_s_setprio(0);
    __builtin_amdgcn_s_barrier();
    __builtin_amdgcn_sched_barrier(0);
    // ---- phase 3: Q11 ----
    READ_A(b, 1);
    if (nl) STAGE(2, t + 1);
    __builtin_amdgcn_s_barrier();
    __builtin_amdgcn_sched_barrier(0);
    __builtin_amdgcn_s_setprio(1);
    MFMA16(4, 2);
    __builtin_amdgcn_s_setprio(0);
    __builtin_amdgcn_s_barrier();
    __builtin_amdgcn_sched_barrier(0);
    // ---- phase 4: Q10 ----
    READ_B(b, 0);
    if (nl) STAGE(3, t + 1);
    __builtin_amdgcn_s_barrier();
    __builtin_amdgcn_sched_barrier(0);
    __builtin_amdgcn_s_setprio(1);
    MFMA16(4, 0);
    __builtin_amdgcn_s_setprio(0);
    if (nl) { VMCNT(4); } else { VMCNT(0); }
    __builtin_amdgcn_s_barrier();
    __builtin_amdgcn_sched_barrier(0);
  }

  // epilogue
  float sc_eff = scale;
  if (EPI == 2) sc_eff = (bn < 1024) ? st : scale;  // Q columns pre-scaled
  float bias4[4];
  if (EPI == 1) {
#pragma unroll
    for (int j = 0; j < 4; j++) bias4[j] = bias[bn + wn * 64 + j * 16 + l16];
  }
#pragma unroll
  for (int mi = 0; mi < 8; mi++) {
    const size_t r0 = bm + wm * 128 + (mi >> 2) * 64 + (mi & 3) * 16 + quad * 4;
#pragma unroll
    for (int r = 0; r < 4; r++) {
      const size_t rowoff = (r0 + r) * (size_t)N + bn + wn * 64 + l16;
#pragma unroll
      for (int j = 0; j < 4; j++) {
        float v = acc[mi][j][r];
        if (EPI == 2) {
          ((bf16*)C)[rowoff + j * 16] = __float2bfloat16(v * sc_eff);
        } else {
          // GELU (tanh form) via raw v_exp_f32 / v_rcp_f32
          float u = (v + bias4[j]) * scale;
          float tt = u * (0.7978845608f + 0.0356774081f * u * u);
          float e = __builtin_amdgcn_exp2f(tt * 2.8853900818f);  // exp(2*tt)
          float th = 1.0f - 2.0f * __builtin_amdgcn_rcpf(e + 1.0f);
          ((bf16*)C)[rowoff + j * 16] =
              __float2bfloat16(0.5f * u * (1.0f + th) * st);
        }
      }
    }
  }
}

// ---------------------------------------------------------------------------
// 256x128 8-phase MFMA GEMM, split-K=2 with bf16 raw partial stores (split 0
// -> C, split 1 -> C2). For N=1024 GEMMs: 128 tiles x 2 splits = 256 blocks.
// ---------------------------------------------------------------------------
__global__ __launch_bounds__(512, 2) void gemm_mfma128(
    const bf16* __restrict__ A, const bf16* __restrict__ Bw,
    bf16* __restrict__ C, bf16* __restrict__ C2, int M, int N, int K) {
  __shared__ __align__(16) bf16 As[2][2][128][64];  // 64 KiB
  __shared__ __align__(16) bf16 Bs[2][2][64][64];   // 32 KiB

  const int tid = threadIdx.x;
  const int lane = tid & 63;
  const int w = tid >> 6;
  const int wm = w >> 2;           // 0..1
  const int wn = w & 3;            // 0..3 (32-col slice)
  const int quad = lane >> 4;
  const int l16 = lane & 15;

  const int nbx = N >> 7;
  const int nwg = nbx * (M >> 8) * 2;
  int bid = blockIdx.x;
  bid = (bid & 7) * (nwg >> 3) + (bid >> 3);
  const int split = bid & 1;
  const int tile = bid >> 1;
  const size_t bm = (size_t)(tile / nbx) * 256;
  const size_t bn = (size_t)(tile % nbx) * 128;
  const int lda = K * 2;
  const int koff = split * K;

  // A staging (2 chunks x 128 rows, 2 gloads each)
  const bf16* gA[2][2];
  bf16* lA[2][2];
#pragma unroll
  for (int i = 0; i < 2; i++) {
    const int G = tid + i * 512;
    const int cr = G >> 3;
    const int gs8 = ((G & 7) ^ (cr & 7)) * 8;
    const int ra = ((cr >> 6) << 7) + (cr & 63);
    gA[0][i] = A + (bm + ra) * (size_t)lda + koff + gs8;
    gA[1][i] = A + (bm + ra + 64) * (size_t)lda + koff + gs8;
    lA[0][i] = &As[0][0][0][0] + G * 8;
    lA[1][i] = &As[0][1][0][0] + G * 8;
  }
  // B staging (2 chunks x 64 rows, 1 gload each)
  const bf16* gB[2];
  bf16* lB[2];
  {
    const int cr = tid >> 3;
    const int gs8 = ((tid & 7) ^ (cr & 7)) * 8;
    gB[0] = Bw + (bn + cr) * (size_t)lda + koff + gs8;
    gB[1] = Bw + (bn + 64 + cr) * (size_t)lda + koff + gs8;
    lB[0] = &Bs[0][0][0][0] + tid * 8;
    lB[1] = &Bs[0][1][0][0] + tid * 8;
  }

  auto STAGE_A = [&](int h, int tn) {
    const int boff = (tn & 1) * 16384;
    gload_lds16(gA[h][0] + (size_t)tn * 64, lA[h][0] + boff);
    gload_lds16(gA[h][1] + (size_t)tn * 64, lA[h][1] + boff);
  };
  auto STAGE_B = [&](int bh, int tn) {
    const int boff = (tn & 1) * 8192;
    gload_lds16(gB[bh] + (size_t)tn * 64, lB[bh] + boff);
  };

  const int ksw0 = (quad ^ (l16 & 7)) * 8;
  const int ksw1 = ((4 + quad) ^ (l16 & 7)) * 8;

  floatx4 acc[8][2];
#pragma unroll
  for (int i = 0; i < 8; i++)
#pragma unroll
    for (int j = 0; j < 2; j++) acc[i][j] = {0.f, 0.f, 0.f, 0.f};

  short8 af[4][2], bv[2][2];

  auto READ_A = [&](int b, int h) {
#pragma unroll
    for (int mf = 0; mf < 4; mf++) {
      const bf16* p = &As[b][h][wm * 64 + mf * 16 + l16][0];
      af[mf][0] = *(const short8*)(p + ksw0);
      af[mf][1] = *(const short8*)(p + ksw1);
    }
  };
  auto READ_BNF = [&](int b, int nf) {
    const bf16* p = &Bs[b][wn >> 1][(wn & 1) * 32 + nf * 16 + l16][0];
    bv[nf][0] = *(const short8*)(p + ksw0);
    bv[nf][1] = *(const short8*)(p + ksw1);
  };
  auto MFMA8 = [&](int mb, int nf) {
#pragma unroll
    for (int mf = 0; mf < 4; mf++) {
      floatx4 c = acc[mb + mf][nf];
      c = __builtin_amdgcn_mfma_f32_16x16x32_bf16(af[mf][0], bv[nf][0], c, 0, 0, 0);
      c = __builtin_amdgcn_mfma_f32_16x16x32_bf16(af[mf][1], bv[nf][1], c, 0, 0, 0);
      acc[mb + mf][nf] = c;
    }
  };

  // prologue: tile 0 (6 loads); p1 needs C0,C1,C2 -> leave C3 (2) in flight
  STAGE_A(0, 0); STAGE_B(0, 0); STAGE_B(1, 0); STAGE_A(1, 0);
  VMCNT(2);
  __builtin_amdgcn_s_barrier();
  __builtin_amdgcn_sched_barrier(0);

  const int NT = K >> 6;
#pragma unroll 1
  for (int t = 0; t < NT; t++) {
    const int b = t & 1;
    const bool nl = (t + 1 < NT);
    // ---- p1: A.h0 x nf0 ----
    READ_A(b, 0);
    READ_BNF(b, 0);
    if (nl) STAGE_A(0, t + 1);
    __builtin_amdgcn_s_barrier();
    __builtin_amdgcn_sched_barrier(0);
    __builtin_amdgcn_s_setprio(1);
    MFMA8(0, 0);
    __builtin_amdgcn_s_setprio(0);
    __builtin_amdgcn_s_barrier();
    __builtin_amdgcn_sched_barrier(0);
    // ---- p2: A.h0 x nf1 ----
    READ_BNF(b, 1);
    if (nl) STAGE_B(0, t + 1);
    __builtin_amdgcn_s_barrier();
    __builtin_amdgcn_sched_barrier(0);
    __builtin_amdgcn_s_setprio(1);
    MFMA8(0, 1);
    __builtin_amdgcn_s_setprio(0);
    if (nl) { VMCNT(3); } else { VMCNT(0); }
    __builtin_amdgcn_s_barrier();
    __builtin_amdgcn_sched_barrier(0);
    // ---- p3: A.h1 x nf1 ----
    READ_A(b, 1);
    if (nl) STAGE_B(1, t + 1);
    __builtin_amdgcn_s_barrier();
    __builtin_amdgcn_sched_barrier(0);
    __builtin_amdgcn_s_setprio(1);
    MFMA8(4, 1);
    __builtin_amdgcn_s_setprio(0);
    __builtin_amdgcn_s_barrier();
    __builtin_amdgcn_sched_barrier(0);
    // ---- p4: A.h1 x nf0 (bv[0] reused from p1) ----
    if (nl) STAGE_A(1, t + 1);
    __builtin_amdgcn_s_barrier();
    __builtin_amdgcn_sched_barrier(0);
    __builtin_amdgcn_s_setprio(1);
    MFMA8(4, 0);
    __builtin_amdgcn_s_setprio(0);
    if (nl) { VMCNT(2); } else { VMCNT(0); }
    __builtin_amdgcn_s_barrier();
    __builtin_amdgcn_sched_barrier(0);
  }

  // epilogue: raw bf16 partial store; split 0 -> C, split 1 -> C2
  bf16* dst = split ? C2 : C;
#pragma unroll
  for (int mi = 0; mi < 8; mi++) {
    const size_t r0 = bm + wm * 128 + (mi >> 2) * 64 + (mi & 3) * 16 + quad * 4;
#pragma unroll
    for (int r = 0; r < 4; r++) {
      const size_t rowoff = (r0 + r) * (size_t)N + bn + wn * 32 + l16;
#pragma unroll
      for (int j = 0; j < 2; j++)
        dst[rowoff + j * 16] = __float2bfloat16(acc[mi][j][r]);
    }
  }
}

// ---------------------------------------------------------------------------
// MFMA flash attention, KV-split=2, 512 threads = 8 waves, QT=128, KT=64.
// FIXED-MAX softmax (Q pre-scaled by MM_SCALE*LOG2E in the QKV gemm).
// Grid = 1024 blocks; LDS = 40 KiB exactly -> 4 blocks/CU (full occupancy).
// - each block handles keys [half*1024, half*1024+1024), writes UNNORMALIZED
//   bf16 O partial + float l partial; combine_attn merges (linear since
//   fixed-max).
// - XCD remap: 4 (b,h) x 32 blocks per XCD (KV L2-local).
// - Ks single-buffered (2nd barrier after QK^T guards the overwrite).
// - Vt [2][64][64] with granule XOR swizzle (replaces the +8 pad).
// ---------------------------------------------------------------------------
__global__ __launch_bounds__(512) void flash_attn_mfma(
    const bf16* __restrict__ qkv, bf16* __restrict__ O0,
    bf16* __restrict__ O1, float* __restrict__ lb0,
    float* __restrict__ lb1) {
  const int flat = (blockIdx.z * H_ + blockIdx.y) * 32 + blockIdx.x;
  const int g8 = flat & 7, slot = flat >> 3;  // 128 slots per XCD
  const int hf = g8 * 4 + (slot >> 5);        // (b,h) flat 0..31, 4 per XCD
  const int rem = slot & 31;
  const int qb = (rem >> 1) * 128;
  const int half = rem & 1;
  const int h = hf & 15, b = hf >> 4;

  const int tid = threadIdx.x;
  const int lane = tid & 63;
  const int wv = tid >> 6;           // 0..7
  const int quad = lane >> 4;
  const int l16 = lane & 15;

  __shared__ __align__(16) bf16 Ks[64][64];     // single buf, col-swizzled
  __shared__ __align__(16) bf16 Vt[2][64][64];  // [d][j], granule-swizzled
  __shared__ __align__(16) bf16 Ps[128][64];    // P, XOR-swizzled

  const bf16* Qb_ = qkv + (size_t)b * S_ * D3_ + h * DH_;
  const bf16* Kb_ = Qb_ + 1024 + (size_t)half * 1024 * D3_;
  const bf16* Vb_ = Qb_ + 2048 + (size_t)half * 1024 * D3_;

  // Q as B-operand frag: queries qb + wv*16 + l16 (already scaled)
  short8 bq0, bq1;
  {
    const bf16* qrow = Qb_ + (size_t)(qb + wv * 16 + l16) * D3_ + quad * 8;
    bq0 = *(const short8*)(qrow);
    bq1 = *(const short8*)(qrow + 32);
  }

  float l_part = 0.f;
  floatx4 o[4];
#pragma unroll
  for (int fd = 0; fd < 4; fd++) o[fd] = {0.f, 0.f, 0.f, 0.f};

  // P LDS addressing (per-wave private rows, XOR swizzle on byte bits 4-6)
  const int prow = wv * 16 + l16;
  const int psw = (prow & 7) << 4;
  char* pbase = (char*)&Ps[0][0] + prow * 128;

  // K staging: thread covers Ks row tid>>3, slot tid&7 <- src col slot^(row&7)
  const bf16* ksrc =
      Kb_ + (size_t)(tid >> 3) * D3_ + (((tid & 7) ^ ((tid >> 3) & 7)) * 8);
  bf16* kdst = &Ks[0][0] + tid * 8;
  // V staging: 1 uint4 -> 8 b16 scatters (transpose + granule swizzle)
  const int vj = tid & 63, vd = (tid >> 6) * 8;
  const int vjg = vj >> 3, vjr = vj & 7;

  const int ksw0 = (quad ^ (l16 & 7)) * 8;
  const int ksw1 = ((4 + quad) ^ (l16 & 7)) * 8;

  // prologue: K(0) gload first, then V(0) reg load (FIFO: vreg's implicit
  // vmcnt wait also drains the older K gload)
  gload_lds16(ksrc, kdst);
  uint4 vreg = *(const uint4*)(Vb_ + (size_t)vj * D3_ + vd);

  const int NT = 1024 / 64;  // 16 tiles per half
#pragma unroll 1
  for (int t = 0; t < NT; t++) {
    const int cur = t & 1;
    // commit V(t); the vreg use forces vmcnt(0) -> K(t) gload also drained
    {
      bf16 tmp[8];
      *(uint4*)tmp = vreg;
#pragma unroll
      for (int e = 0; e < 8; e++)
        Vt[cur][vd + e][((vjg ^ e) << 3) | vjr] = tmp[e];
    }
    __syncthreads();  // sync1: Ks(t) + Vt[cur] visible

    // S^T = K Q^T : lane holds keys fk*16 + quad*4 + r for query wv*16+l16
    float st[4][4];
    __builtin_amdgcn_s_setprio(1);
#pragma unroll
    for (int fk = 0; fk < 4; fk++) {
      const bf16* kp = &Ks[fk * 16 + l16][0];
      short8 ak0 = *(const short8*)(kp + ksw0);
      short8 ak1 = *(const short8*)(kp + ksw1);
      floatx4 acc = {0.f, 0.f, 0.f, 0.f};
      acc = __builtin_amdgcn_mfma_f32_16x16x32_bf16(ak0, bq0, acc, 0, 0, 0);
      acc = __builtin_amdgcn_mfma_f32_16x16x32_bf16(ak1, bq1, acc, 0, 0, 0);
#pragma unroll
      for (int r = 0; r < 4; r++) st[fk][r] = acc[r];
    }
    __builtin_amdgcn_s_setprio(0);
    __syncthreads();  // sync2: all waves done reading Ks -> safe to overwrite

    // prefetch tile t+1 (K async into the single Ks buffer; V into regs)
    if (t + 1 < NT) {
      gload_lds16(ksrc + (size_t)(t + 1) * 64 * D3_, kdst);
      vreg = *(const uint4*)(Vb_ + (size_t)((t + 1) * 64 + vj) * D3_ + vd);
    }

    // P = exp2(S^T), interleaved: fk 0,1 first so ap0's deps resolve early
#pragma unroll
    for (int fk = 0; fk < 2; fk++) {
      bf16 pk[4];
#pragma unroll
      for (int r = 0; r < 4; r++) {
        const float p = __builtin_amdgcn_exp2f(st[fk][r]);
        l_part += p;
        pk[r] = __float2bfloat16(p);
      }
      *(uint2*)(pbase + ((fk * 32 + quad * 8) ^ psw)) = *(uint2*)pk;
    }
    short8 ap0 = *(const short8*)(pbase + ((quad * 16) ^ psw));
#pragma unroll
    for (int fk = 2; fk < 4; fk++) {
      bf16 pk[4];
#pragma unroll
      for (int r = 0; r < 4; r++) {
        const float p = __builtin_amdgcn_exp2f(st[fk][r]);
        l_part += p;
        pk[r] = __float2bfloat16(p);
      }
      *(uint2*)(pbase + ((fk * 32 + quad * 8) ^ psw)) = *(uint2*)pk;
    }
    short8 ap1 = *(const short8*)(pbase + ((64 + quad * 16) ^ psw));

    // O += P V (Vt reads use the same granule swizzle as K)
    __builtin_amdgcn_s_setprio(1);
#pragma unroll
    for (int fd = 0; fd < 4; fd++) {
      const bf16* vp = &Vt[cur][fd * 16 + l16][0];
      short8 bv0 = *(const short8*)(vp + ksw0);
      short8 bv1 = *(const short8*)(vp + ksw1);
      o[fd] = __builtin_amdgcn_mfma_f32_16x16x32_bf16(ap0, bv0, o[fd], 0, 0, 0);
      o[fd] = __builtin_amdgcn_mfma_f32_16x16x32_bf16(ap1, bv1, o[fd], 0, 0, 0);
    }
    __builtin_amdgcn_s_setprio(0);
  }

  // l: butterfly over quads -> every lane holds l(q = wv*16 + l16)
  l_part += __shfl_xor(l_part, 16);
  l_part += __shfl_xor(l_part, 32);

  bf16* Oo = half ? O1 : O0;
  float* lo = half ? lb1 : lb0;
  if (quad == 0)
    lo[(size_t)(b * S_ + qb + wv * 16 + l16) * H_ + h] = l_part;
#pragma unroll
  for (int r = 0; r < 4; r++) {
    const size_t base =
        ((size_t)(b * S_ + qb + wv * 16 + quad * 4 + r)) * D_ + h * DH_;
#pragma unroll
    for (int fd = 0; fd < 4; fd++)
      Oo[base + fd * 16 + l16] = __float2bfloat16(o[fd][r]);
  }
}

// ---------------------------------------------------------------------------
extern "C" void kernel_launch(void* const* d_in, const int* in_sizes, int n_in,
                              void* d_out, int out_size, void* d_ws, size_t ws_size,
                              hipStream_t stream) {
  const float* x     = (const float*)d_in[0];
  const float* w_qkv = (const float*)d_in[1];
  const float* w_o   = (const float*)d_in[2];
  const float* w1    = (const float*)d_in[3];
  const float* b1    = (const float*)d_in[4];
  const float* w2    = (const float*)d_in[5];
  const float* b2    = (const float*)d_in[6];
  const float* ln1w  = (const float*)d_in[7];
  const float* ln1b  = (const float*)d_in[8];
  const float* ln2w  = (const float*)d_in[9];
  const float* ln2b  = (const float*)d_in[10];
  float* out = (float*)d_out;
  bf16* ws  = (bf16*)d_ws;

  // workspace layout (bf16 els), liveness-audited, peak 29,360,128 els (58.7MB)
  // order: cvt_all, LN1, QKV, flash, combine, cvt_w2, oproj, LN2, FFN1,
  //        FFN2, reduce
  bf16* h1   = ws;                 // [0,4.19M)      live LN1->QKV
  bf16* wqb  = ws + 4194304;       // [4.19,7.34M)   live cvt_all->QKV
  bf16* wob  = ws + 7340032;       // [7.34,8.39M)   live cvt_all->oproj
  bf16* qkv  = ws + 8388608;       // [8.39,20.97M)  live QKV->flash
  bf16* w1b  = ws + 25165824;      // [25.17,29.36M) live cvt_all->FFN1
  bf16* Ob0  = ws + 20971520;      // [20.97,25.17M) live flash->combine
  bf16* Ob1  = ws;                 // [0,4.19M)      live flash->combine (h1 dead)
  float* l0f = (float*)(ws + 4194304);  // 65536 f32, flash->combine (wqb dead)
  float* l1f = l0f + 65536;
  bf16* att  = Ob0;                // combine in-place -> live ->oproj
  bf16* w2b  = ws;                 // [0,4.19M)      live cvt_w2->FFN2 (Ob1 dead)
  bf16* Po   = ws + 8388608;       // [8.39,16.78M)  2x4.19M, oproj->LN2 (qkv dead)
  bf16* h2   = ws + 4194304;       // [4.19,8.39M)   live LN2->FFN1 (l/wob dead)
  bf16* g    = ws + 8388608;       // [8.39,25.17M)  live FFN1->FFN2 (Po/att dead)
  bf16* Pf0  = ws + 4194304;       // [4.19,8.39M)   live FFN2->reduce (h2 dead)
  bf16* Pf1  = ws + 25165824;      // [25.17,29.36M) live FFN2->reduce (w1b dead)

  const float MM_SCALE   = (float)pow((double)S_ * S_ * DH_, -1.0 / 6.0);
  const float SM_SCALE   = (float)((double)S_ / sqrt(1.31 * 1.65));
  const float GELU_SCALE = (float)pow(0.588 * 0.675, -0.5);
  const float SQRT_TAU   = (float)sqrt(0.2);
  const float SQRT_1MT   = (float)sqrt(0.8);
  const float LOG2E      = 1.4426950408889634f;
  const float qkv_scale  = (float)pow((double)D_ * D3_, -0.25);
  const float o_scale    = (float)pow((double)D_ * D_, -0.25);
  const float w1_scale   = (float)pow((double)D_ * DF_, -0.25);
  const float w2_scale   = (float)pow((double)DF_ * D_, -0.25);

  // 1. upfront converts: w_qkv (permuted) + w_o + w1
  cvt_all<<<8192, 256, 0, stream>>>(w_qkv, w_o, w1, wqb, wob, w1b);
  // 2. LN1
  resid_ln_kernel<false, false, float, float><<<BS_, 256, 0, stream>>>(
      x, nullptr, nullptr, ln1w, ln1b, h1, 0.f, 0.f, nullptr, nullptr, 0.f, 0.f);
  // 3. QKV gemm -> head-major qkv (Q columns folded with MM_SCALE*LOG2E)
  gemm_mfma256<2, bf16><<<dim3(192), 512, 0, stream>>>(
      h1, wqb, qkv, BS_, D3_, D_, qkv_scale, nullptr,
      qkv_scale * MM_SCALE * LOG2E);
  // 4. flash attention, KV-split=2 (1024 blocks, 4/CU)
  flash_attn_mfma<<<dim3(32, H_, B_), 512, 0, stream>>>(
      qkv, Ob0, Ob1, l0f, l1f);
  // 4.5 combine partials -> att (in-place over Ob0)
  combine_attn<<<2048, 256, 0, stream>>>(
      Ob0, Ob1, l0f, l1f, att, SM_SCALE * MM_SCALE);
  // 4.6 convert w2 (Ob1 dead after combine)
  cvt_f32_bf16<<<4096, 256, 0, stream>>>(w2, w2b, D_ * DF_ / 4);
  // 5. out-proj: 256x128 split-K=2, bf16 raw partials (256 blocks)
  gemm_mfma128<<<dim3(256), 512, 0, stream>>>(
      att, wob, Po, Po + (size_t)BS_ * D_, BS_, D_, D_ / 2);
  // 6. residual(o_scale*(p0+p1)) + LN2; pre-init out = cs*xv + cb*b2
  resid_ln_kernel<true, true, bf16, float><<<BS_, 256, 0, stream>>>(
      Po, Po + (size_t)BS_ * D_, x, ln2w, ln2b, h2,
      SQRT_TAU * o_scale, SQRT_1MT, out, b2, SQRT_TAU * w2_scale, SQRT_1MT);
  // 7. FFN1 + GELU (256 blocks)
  gemm_mfma256<1, bf16><<<dim3(256), 512, 0, stream>>>(
      h2, w1b, g, BS_, DF_, D_, w1_scale, b1, GELU_SCALE);
  // 8. FFN2: 256x128 split-K=2, bf16 raw partials (256 blocks)
  gemm_mfma128<<<dim3(256), 512, 0, stream>>>(
      g, w2b, Pf0, Pf1, BS_, D_, DF_ / 2);
  // 9. reduce partials into pre-init'd out
  reduce_ffn2<<<2048, 256, 0, stream>>>(Pf0, Pf1, out, SQRT_TAU * w2_scale);
}

// Round 7
// 332.278 us; speedup vs baseline: 1.2555x; 1.0185x over previous
//
#include <hip/hip_runtime.h>
#include <hip/hip_bf16.h>
#include <math.h>

typedef __hip_bfloat16 bf16;
typedef __attribute__((ext_vector_type(8))) short short8;
typedef __attribute__((ext_vector_type(4))) float floatx4;

#define B_   2
#define S_   2048
#define D_   1024
#define H_   16
#define DH_  64
#define BS_  4096   // B_*S_
#define D3_  3072   // 3*D_
#define DF_  4096   // 4*D_

__device__ __forceinline__ float tof(float v) { return v; }
__device__ __forceinline__ float tof(bf16 v) { return __bfloat162float(v); }

// async global->LDS 16B copy: lane's data lands at readfirstlane(lds)+lane*16
__device__ __forceinline__ void gload_lds16(const bf16* g, bf16* l) {
  __builtin_amdgcn_global_load_lds(
      (const __attribute__((address_space(1))) unsigned int*)g,
      (__attribute__((address_space(3))) unsigned int*)l, 16, 0, 0);
}

#define VMCNT(n) asm volatile("s_waitcnt vmcnt(" #n ")" ::: "memory")

// ---------------------------------------------------------------------------
// Upfront fused convert: w_qkv fp32->bf16 with ROW PERMUTE n=d*48+z*16+h ->
// n2=z*1024+h*64+d (QKV gemm emits [b,s][z,h,d]), + plain w_o + plain w1.
// ---------------------------------------------------------------------------
__global__ __launch_bounds__(256) void cvt_all(
    const float* __restrict__ wqkv, const float* __restrict__ wo,
    const float* __restrict__ w1, bf16* __restrict__ wqb,
    bf16* __restrict__ wob, bf16* __restrict__ w1b) {
  const int g = blockIdx.x * 256 + threadIdx.x;  // 4-el group
  if (g < 786432) {                              // 3072*1024/4 : permute+cvt
    const int n2 = g >> 8;                       // dest row (z,h,d)
    const int col = (g & 255) * 4;
    const int z = n2 >> 10, hh = (n2 >> 6) & 15, d = n2 & 63;
    const int n = d * 48 + z * 16 + hh;          // src row
    float4 v = *(const float4*)(wqkv + (size_t)n * 1024 + col);
    bf16 o[4] = {__float2bfloat16(v.x), __float2bfloat16(v.y),
                 __float2bfloat16(v.z), __float2bfloat16(v.w)};
    *(unsigned long long*)(wqb + (size_t)n2 * 1024 + col) =
        *(unsigned long long*)o;
  } else if (g < 1048576) {                      // w_o: 1024*1024/4 groups
    const int g2 = g - 786432;
    float4 v = ((const float4*)wo)[g2];
    bf16 o[4] = {__float2bfloat16(v.x), __float2bfloat16(v.y),
                 __float2bfloat16(v.z), __float2bfloat16(v.w)};
    ((unsigned long long*)wob)[g2] = *(unsigned long long*)o;
  } else {                                       // w1: 4096*1024/4 groups
    const int g2 = g - 1048576;
    float4 v = ((const float4*)w1)[g2];
    bf16 o[4] = {__float2bfloat16(v.x), __float2bfloat16(v.y),
                 __float2bfloat16(v.z), __float2bfloat16(v.w)};
    ((unsigned long long*)w1b)[g2] = *(unsigned long long*)o;
  }
}

// ---------------------------------------------------------------------------
// LayerNorm. FUSE: xv = st*(a[i]+a2[i]) + s1t*skip[i]  (a,a2 = bf16 raw
// split-K partials of the out-proj; st carries SQRT_TAU*o_scale).
// INIT: pre-init FFN2 output with the linear epilogue part.
// ---------------------------------------------------------------------------
template <bool FUSE, bool INIT, typename TA, typename TS>
__global__ __launch_bounds__(256) void resid_ln_kernel(
    const TA* __restrict__ a, const TA* __restrict__ a2,
    const TS* __restrict__ skip,
    const float* __restrict__ w, const float* __restrict__ bias,
    bf16* __restrict__ hout, float st, float s1t,
    float* __restrict__ oinit, const float* __restrict__ b2,
    float cb, float cs) {
  const int row = blockIdx.x;
  const int tid = threadIdx.x;
  const int base = tid * 4;
  const size_t roff = (size_t)row * D_;

  float xv[4];
#pragma unroll
  for (int i = 0; i < 4; i++) {
    float v = tof(a[roff + base + i]);
    if (FUSE) v = st * (v + tof(a2[roff + base + i]))
                  + s1t * tof(skip[roff + base + i]);
    xv[i] = v;
  }
  if (INIT) {
#pragma unroll
    for (int i = 0; i < 4; i++)
      oinit[roff + base + i] = cs * xv[i] + cb * b2[base + i];
  }

  float ls = 0.f, lq = 0.f;
#pragma unroll
  for (int i = 0; i < 4; i++) { ls += xv[i]; lq += xv[i] * xv[i]; }

  __shared__ float ssum[256];
  __shared__ float ssq[256];
  ssum[tid] = ls; ssq[tid] = lq;
  __syncthreads();
  for (int off = 128; off > 0; off >>= 1) {
    if (tid < off) { ssum[tid] += ssum[tid + off]; ssq[tid] += ssq[tid + off]; }
    __syncthreads();
  }
  const float mean = ssum[0] * (1.0f / D_);
  const float var  = ssq[0] * (1.0f / D_) - mean * mean;
  const float rstd = rsqrtf(var + 1e-5f);

#pragma unroll
  for (int i = 0; i < 4; i++) {
    float v = (xv[i] - mean) * rstd * w[base + i] + bias[base + i];
    hout[roff + base + i] = __float2bfloat16(v);
  }
}

// ---------------------------------------------------------------------------
// FFN2 split-K reduce: out += sc*(p0[i] + p1[i]); out was pre-init'd by LN2.
// ---------------------------------------------------------------------------
__global__ __launch_bounds__(256) void reduce_ffn2(
    const bf16* __restrict__ p0, const bf16* __restrict__ p1,
    float* __restrict__ out, float sc) {
  const size_t i = ((size_t)blockIdx.x * 256 + threadIdx.x) * 8;
  short8 a = *(const short8*)(p0 + i);
  short8 b = *(const short8*)(p1 + i);
  bf16 t0[8], t1[8];
  *(short8*)t0 = a; *(short8*)t1 = b;
  float4 o0 = *(float4*)(out + i);
  float4 o1 = *(float4*)(out + i + 4);
#pragma unroll
  for (int e = 0; e < 4; e++) {
    ((float*)&o0)[e] += sc * (__bfloat162float(t0[e]) + __bfloat162float(t1[e]));
    ((float*)&o1)[e] += sc * (__bfloat162float(t0[e + 4]) + __bfloat162float(t1[e + 4]));
  }
  *(float4*)(out + i) = o0;
  *(float4*)(out + i + 4) = o1;
}

// ---------------------------------------------------------------------------
// Flash KV-split combine: att[i] = (O0[i]+O1[i]) * sc / (l0+l1).
// ---------------------------------------------------------------------------
__global__ __launch_bounds__(256) void combine_attn(
    const bf16* __restrict__ O0, const bf16* __restrict__ O1,
    const float* __restrict__ l0, const float* __restrict__ l1,
    bf16* __restrict__ att, float sc) {
  const size_t i = ((size_t)blockIdx.x * 256 + threadIdx.x) * 8;
  const int srow = (int)(i >> 10);      // (b*S+s), D=1024
  const int h = (int)(i >> 6) & 15;
  const float inv = sc / (l0[srow * H_ + h] + l1[srow * H_ + h]);
  short8 a = *(const short8*)(O0 + i);
  short8 b = *(const short8*)(O1 + i);
  bf16 t0[8], t1[8], o[8];
  *(short8*)t0 = a; *(short8*)t1 = b;
#pragma unroll
  for (int e = 0; e < 8; e++)
    o[e] = __float2bfloat16((tof(t0[e]) + tof(t1[e])) * inv);
  *(short8*)(att + i) = *(short8*)o;
}

// ---------------------------------------------------------------------------
// 256x256 8-phase MFMA GEMM (T1+T2+T3+T4+T5). 512 thr = 8 waves (2Mx4N),
// BK=64, LDS 128 KiB. For the big-N GEMMs (QKV, FFN1).
// C row-split: rows < 1024 -> C, rows >= 1024 -> Chi (offset by -1024 rows);
// pass Chi = C + 1024*N for a contiguous buffer.
// EPI: 1 = bias+GELU(tanh),store bf16; 2 = dual-scale (Q cols bn<1024 -> st).
// FCVT: blocks >= nwg grid-stride convert cvn4 float4-groups cvsrc->cvdst
// (runs on CUs the gemm grid leaves idle; used to hide the w2 convert).
// ---------------------------------------------------------------------------
template <int EPI, bool FCVT, typename TC>
__global__ __launch_bounds__(512, 2) void gemm_mfma256(
    const bf16* __restrict__ A, const bf16* __restrict__ Bw,
    TC* __restrict__ C, TC* __restrict__ Chi,
    int M, int N, int K, float scale,
    const float* __restrict__ bias, float st,
    const float* __restrict__ cvsrc, bf16* __restrict__ cvdst, int cvn4) {
  const int nbx = N >> 8;
  const int nwg = nbx * (M >> 8);
  if (FCVT && (int)blockIdx.x >= nwg) {
    const int nth = ((int)gridDim.x - nwg) * 512;
    for (int i = ((int)blockIdx.x - nwg) * 512 + (int)threadIdx.x; i < cvn4;
         i += nth) {
      float4 v = ((const float4*)cvsrc)[i];
      bf16 o[4] = {__float2bfloat16(v.x), __float2bfloat16(v.y),
                   __float2bfloat16(v.z), __float2bfloat16(v.w)};
      ((unsigned long long*)cvdst)[i] = *(unsigned long long*)o;
    }
    return;
  }

  __shared__ __align__(16) bf16 As[2][2][128][64];  // [buf][chunk h][row][k]
  __shared__ __align__(16) bf16 Bs[2][2][128][64];  // [buf][chunk bh][row][k]

  const int tid = threadIdx.x;
  const int lane = tid & 63;
  const int w = tid >> 6;          // 0..7
  const int wm = w >> 2;           // 0..1  (M half)
  const int wn = w & 3;            // 0..3  (N quarter)
  const int quad = lane >> 4;
  const int l16 = lane & 15;

  // T1: XCD-aware block swizzle (nwg % 8 == 0 at every call site)
  int bid = blockIdx.x;
  bid = (bid & 7) * (nwg >> 3) + (bid >> 3);
  const size_t bm = (size_t)(bid / nbx) * 256;
  const size_t bn = (size_t)(bid % nbx) * 256;

  // staging: chunk c in {0:A.h0, 1:B.bh0, 2:A.h1, 3:B.bh1}, 2 x 16B/thread
  const bf16* gsrc[4][2];
  bf16* ldsp[4][2];
#pragma unroll
  for (int i = 0; i < 2; i++) {
    const int G = tid + i * 512;               // granule 0..1023 within chunk
    const int cr = G >> 3;                     // chunk row 0..127
    const int gs8 = ((G & 7) ^ (cr & 7)) * 8;  // pre-swizzled source column
    const int ra = ((cr >> 6) << 7) + (cr & 63);       // A: + h*64
    const int rb = ((cr >> 5) << 6) + (cr & 31);       // B: + bh*32
    gsrc[0][i] = A  + (bm + ra) * (size_t)K + gs8;
    gsrc[2][i] = A  + (bm + ra + 64) * (size_t)K + gs8;
    gsrc[1][i] = Bw + (bn + rb) * (size_t)K + gs8;
    gsrc[3][i] = Bw + (bn + rb + 32) * (size_t)K + gs8;
    ldsp[0][i] = &As[0][0][0][0] + G * 8;
    ldsp[2][i] = &As[0][1][0][0] + G * 8;
    ldsp[1][i] = &Bs[0][0][0][0] + G * 8;
    ldsp[3][i] = &Bs[0][1][0][0] + G * 8;
  }

  auto STAGE = [&](int c, int tn) {
    const int boff = (tn & 1) * 16384;  // els between buf0/buf1
    gload_lds16(gsrc[c][0] + (size_t)tn * 64, ldsp[c][0] + boff);
    gload_lds16(gsrc[c][1] + (size_t)tn * 64, ldsp[c][1] + boff);
  };

  // swizzled k-granule offsets for ds_read
  const int ksw0 = (quad ^ (l16 & 7)) * 8;
  const int ksw1 = ((4 + quad) ^ (l16 & 7)) * 8;

  floatx4 acc[8][4];
#pragma unroll
  for (int i = 0; i < 8; i++)
#pragma unroll
    for (int j = 0; j < 4; j++) acc[i][j] = {0.f, 0.f, 0.f, 0.f};

  short8 af[4][2], bv[2][2];

  auto READ_A = [&](int b, int h) {
#pragma unroll
    for (int mf = 0; mf < 4; mf++) {
      const bf16* p = &As[b][h][wm * 64 + mf * 16 + l16][0];
      af[mf][0] = *(const short8*)(p + ksw0);
      af[mf][1] = *(const short8*)(p + ksw1);
    }
  };
  auto READ_B = [&](int b, int bh) {
#pragma unroll
    for (int nf = 0; nf < 2; nf++) {
      const bf16* p = &Bs[b][bh][wn * 32 + nf * 16 + l16][0];
      bv[nf][0] = *(const short8*)(p + ksw0);
      bv[nf][1] = *(const short8*)(p + ksw1);
    }
  };
  auto MFMA16 = [&](int mb, int nb) {
#pragma unroll
    for (int mf = 0; mf < 4; mf++)
#pragma unroll
      for (int nf = 0; nf < 2; nf++) {
        floatx4 c = acc[mb + mf][nb + nf];
        c = __builtin_amdgcn_mfma_f32_16x16x32_bf16(af[mf][0], bv[nf][0], c, 0, 0, 0);
        c = __builtin_amdgcn_mfma_f32_16x16x32_bf16(af[mf][1], bv[nf][1], c, 0, 0, 0);
        acc[mb + mf][nb + nf] = c;
      }
  };

  // prologue: full tile 0
  STAGE(0, 0); STAGE(1, 0); STAGE(2, 0); STAGE(3, 0);
  VMCNT(4);
  __builtin_amdgcn_s_barrier();
  __builtin_amdgcn_sched_barrier(0);

  const int NT = K >> 6;
#pragma unroll 1
  for (int t = 0; t < NT; t++) {
    const int b = t & 1;
    const bool nl = (t + 1 < NT);
    // ---- phase 1: Q00 ----
    READ_A(b, 0);
    READ_B(b, 0);
    if (nl) STAGE(0, t + 1);
    __builtin_amdgcn_s_barrier();
    __builtin_amdgcn_sched_barrier(0);
    __builtin_amdgcn_s_setprio(1);
    MFMA16(0, 0);
    __builtin_amdgcn_s_setprio(0);
    if (nl) { VMCNT(2); } else { VMCNT(0); }
    __builtin_amdgcn_s_barrier();
    __builtin_amdgcn_sched_barrier(0);
    // ---- phase 2: Q01 ----
    READ_B(b, 1);
    if (nl) STAGE(1, t + 1);
    __builtin_amdgcn_s_barrier();
    __builtin_amdgcn_sched_barrier(0);
    __builtin_amdgcn_s_setprio(1);
    MFMA16(0, 2);
    __builtin_amdgcn_s_setprio(0);
    __builtin_amdgcn_s_barrier();
    __builtin_amdgcn_sched_barrier(0);
    // ---- phase 3: Q11 ----
    READ_A(b, 1);
    if (nl) STAGE(2, t + 1);
    __builtin_amdgcn_s_barrier();
    __builtin_amdgcn_sched_barrier(0);
    __builtin_amdgcn_s_setprio(1);
    MFMA16(4, 2);
    __builtin_amdgcn_s_setprio(0);
    __builtin_amdgcn_s_barrier();
    __builtin_amdgcn_sched_barrier(0);
    // ---- phase 4: Q10 ----
    READ_B(b, 0);
    if (nl) STAGE(3, t + 1);
    __builtin_amdgcn_s_barrier();
    __builtin_amdgcn_sched_barrier(0);
    __builtin_amdgcn_s_setprio(1);
    MFMA16(4, 0);
    __builtin_amdgcn_s_setprio(0);
    if (nl) { VMCNT(4); } else { VMCNT(0); }
    __builtin_amdgcn_s_barrier();
    __builtin_amdgcn_sched_barrier(0);
  }

  // epilogue (C row-split at row 1024; per-block uniform)
  TC* Cb = (bm < 1024) ? C : Chi;
  const size_t rsub = (bm < 1024) ? 0 : 1024;
  float sc_eff = scale;
  if (EPI == 2) sc_eff = (bn < 1024) ? st : scale;  // Q columns pre-scaled
  float bias4[4];
  if (EPI == 1) {
#pragma unroll
    for (int j = 0; j < 4; j++) bias4[j] = bias[bn + wn * 64 + j * 16 + l16];
  }
#pragma unroll
  for (int mi = 0; mi < 8; mi++) {
    const size_t r0 =
        bm - rsub + wm * 128 + (mi >> 2) * 64 + (mi & 3) * 16 + quad * 4;
#pragma unroll
    for (int r = 0; r < 4; r++) {
      const size_t rowoff = (r0 + r) * (size_t)N + bn + wn * 64 + l16;
#pragma unroll
      for (int j = 0; j < 4; j++) {
        float v = acc[mi][j][r];
        if (EPI == 2) {
          Cb[rowoff + j * 16] = __float2bfloat16(v * sc_eff);
        } else {
          // GELU (tanh form) via raw v_exp_f32 / v_rcp_f32
          float u = (v + bias4[j]) * scale;
          float tt = u * (0.7978845608f + 0.0356774081f * u * u);
          float e = __builtin_amdgcn_exp2f(tt * 2.8853900818f);  // exp(2*tt)
          float th = 1.0f - 2.0f * __builtin_amdgcn_rcpf(e + 1.0f);
          Cb[rowoff + j * 16] =
              __float2bfloat16(0.5f * u * (1.0f + th) * st);
        }
      }
    }
  }
}

// ---------------------------------------------------------------------------
// 256x128 8-phase MFMA GEMM, split-K=2 with bf16 raw partial stores (split 0
// -> C, split 1 -> C2). A row-split: rows < 1024 -> A, rows >= 1024 -> Ahi
// (offset by -1024 rows); pass Ahi = A + 1024*lda for contiguous A.
// For N=1024 GEMMs: 128 tiles x 2 splits = 256 blocks = full chip.
// ---------------------------------------------------------------------------
__global__ __launch_bounds__(512, 2) void gemm_mfma128(
    const bf16* __restrict__ A, const bf16* __restrict__ Ahi,
    const bf16* __restrict__ Bw,
    bf16* __restrict__ C, bf16* __restrict__ C2, int M, int N, int K) {
  __shared__ __align__(16) bf16 As[2][2][128][64];  // 64 KiB
  __shared__ __align__(16) bf16 Bs[2][2][64][64];   // 32 KiB

  const int tid = threadIdx.x;
  const int lane = tid & 63;
  const int w = tid >> 6;
  const int wm = w >> 2;           // 0..1
  const int wn = w & 3;            // 0..3 (32-col slice)
  const int quad = lane >> 4;
  const int l16 = lane & 15;

  const int nbx = N >> 7;
  const int nwg = nbx * (M >> 8) * 2;
  int bid = blockIdx.x;
  bid = (bid & 7) * (nwg >> 3) + (bid >> 3);
  const int split = bid & 1;
  const int tile = bid >> 1;
  const size_t bm = (size_t)(tile / nbx) * 256;
  const size_t bn = (size_t)(tile % nbx) * 128;
  const int lda = K * 2;
  const int koff = split * K;

  const bf16* Ab = (bm < 1024) ? A : Ahi;
  const size_t bmr = (bm < 1024) ? bm : bm - 1024;

  // A staging (2 chunks x 128 rows, 2 gloads each)
  const bf16* gA[2][2];
  bf16* lA[2][2];
#pragma unroll
  for (int i = 0; i < 2; i++) {
    const int G = tid + i * 512;
    const int cr = G >> 3;
    const int gs8 = ((G & 7) ^ (cr & 7)) * 8;
    const int ra = ((cr >> 6) << 7) + (cr & 63);
    gA[0][i] = Ab + (bmr + ra) * (size_t)lda + koff + gs8;
    gA[1][i] = Ab + (bmr + ra + 64) * (size_t)lda + koff + gs8;
    lA[0][i] = &As[0][0][0][0] + G * 8;
    lA[1][i] = &As[0][1][0][0] + G * 8;
  }
  // B staging (2 chunks x 64 rows, 1 gload each)
  const bf16* gB[2];
  bf16* lB[2];
  {
    const int cr = tid >> 3;
    const int gs8 = ((tid & 7) ^ (cr & 7)) * 8;
    gB[0] = Bw + (bn + cr) * (size_t)lda + koff + gs8;
    gB[1] = Bw + (bn + 64 + cr) * (size_t)lda + koff + gs8;
    lB[0] = &Bs[0][0][0][0] + tid * 8;
    lB[1] = &Bs[0][1][0][0] + tid * 8;
  }

  auto STAGE_A = [&](int h, int tn) {
    const int boff = (tn & 1) * 16384;
    gload_lds16(gA[h][0] + (size_t)tn * 64, lA[h][0] + boff);
    gload_lds16(gA[h][1] + (size_t)tn * 64, lA[h][1] + boff);
  };
  auto STAGE_B = [&](int bh, int tn) {
    const int boff = (tn & 1) * 8192;
    gload_lds16(gB[bh] + (size_t)tn * 64, lB[bh] + boff);
  };

  const int ksw0 = (quad ^ (l16 & 7)) * 8;
  const int ksw1 = ((4 + quad) ^ (l16 & 7)) * 8;

  floatx4 acc[8][2];
#pragma unroll
  for (int i = 0; i < 8; i++)
#pragma unroll
    for (int j = 0; j < 2; j++) acc[i][j] = {0.f, 0.f, 0.f, 0.f};

  short8 af[4][2], bv[2][2];

  auto READ_A = [&](int b, int h) {
#pragma unroll
    for (int mf = 0; mf < 4; mf++) {
      const bf16* p = &As[b][h][wm * 64 + mf * 16 + l16][0];
      af[mf][0] = *(const short8*)(p + ksw0);
      af[mf][1] = *(const short8*)(p + ksw1);
    }
  };
  auto READ_BNF = [&](int b, int nf) {
    const bf16* p = &Bs[b][wn >> 1][(wn & 1) * 32 + nf * 16 + l16][0];
    bv[nf][0] = *(const short8*)(p + ksw0);
    bv[nf][1] = *(const short8*)(p + ksw1);
  };
  auto MFMA8 = [&](int mb, int nf) {
#pragma unroll
    for (int mf = 0; mf < 4; mf++) {
      floatx4 c = acc[mb + mf][nf];
      c = __builtin_amdgcn_mfma_f32_16x16x32_bf16(af[mf][0], bv[nf][0], c, 0, 0, 0);
      c = __builtin_amdgcn_mfma_f32_16x16x32_bf16(af[mf][1], bv[nf][1], c, 0, 0, 0);
      acc[mb + mf][nf] = c;
    }
  };

  // prologue: tile 0 (6 loads); p1 needs C0,C1,C2 -> leave C3 (2) in flight
  STAGE_A(0, 0); STAGE_B(0, 0); STAGE_B(1, 0); STAGE_A(1, 0);
  VMCNT(2);
  __builtin_amdgcn_s_barrier();
  __builtin_amdgcn_sched_barrier(0);

  const int NT = K >> 6;
#pragma unroll 1
  for (int t = 0; t < NT; t++) {
    const int b = t & 1;
    const bool nl = (t + 1 < NT);
    // ---- p1: A.h0 x nf0 ----
    READ_A(b, 0);
    READ_BNF(b, 0);
    if (nl) STAGE_A(0, t + 1);
    __builtin_amdgcn_s_barrier();
    __builtin_amdgcn_sched_barrier(0);
    __builtin_amdgcn_s_setprio(1);
    MFMA8(0, 0);
    __builtin_amdgcn_s_setprio(0);
    __builtin_amdgcn_s_barrier();
    __builtin_amdgcn_sched_barrier(0);
    // ---- p2: A.h0 x nf1 ----
    READ_BNF(b, 1);
    if (nl) STAGE_B(0, t + 1);
    __builtin_amdgcn_s_barrier();
    __builtin_amdgcn_sched_barrier(0);
    __builtin_amdgcn_s_setprio(1);
    MFMA8(0, 1);
    __builtin_amdgcn_s_setprio(0);
    if (nl) { VMCNT(3); } else { VMCNT(0); }
    __builtin_amdgcn_s_barrier();
    __builtin_amdgcn_sched_barrier(0);
    // ---- p3: A.h1 x nf1 ----
    READ_A(b, 1);
    if (nl) STAGE_B(1, t + 1);
    __builtin_amdgcn_s_barrier();
    __builtin_amdgcn_sched_barrier(0);
    __builtin_amdgcn_s_setprio(1);
    MFMA8(4, 1);
    __builtin_amdgcn_s_setprio(0);
    __builtin_amdgcn_s_barrier();
    __builtin_amdgcn_sched_barrier(0);
    // ---- p4: A.h1 x nf0 (bv[0] reused from p1) ----
    if (nl) STAGE_A(1, t + 1);
    __builtin_amdgcn_s_barrier();
    __builtin_amdgcn_sched_barrier(0);
    __builtin_amdgcn_s_setprio(1);
    MFMA8(4, 0);
    __builtin_amdgcn_s_setprio(0);
    if (nl) { VMCNT(2); } else { VMCNT(0); }
    __builtin_amdgcn_s_barrier();
    __builtin_amdgcn_sched_barrier(0);
  }

  // epilogue: raw bf16 partial store; split 0 -> C, split 1 -> C2
  bf16* dst = split ? C2 : C;
#pragma unroll
  for (int mi = 0; mi < 8; mi++) {
    const size_t r0 = bm + wm * 128 + (mi >> 2) * 64 + (mi & 3) * 16 + quad * 4;
#pragma unroll
    for (int r = 0; r < 4; r++) {
      const size_t rowoff = (r0 + r) * (size_t)N + bn + wn * 32 + l16;
#pragma unroll
      for (int j = 0; j < 2; j++)
        dst[rowoff + j * 16] = __float2bfloat16(acc[mi][j][r]);
    }
  }
}

// ---------------------------------------------------------------------------
// MFMA flash attention, KV-split=2, 512 threads = 8 waves, QT=128, KT=64.
// FIXED-MAX softmax (Q pre-scaled by MM_SCALE*LOG2E in the QKV gemm).
// SINGLE barrier per tile: Ks and Vt double-buffered; Ps is PER-WAVE PRIVATE
// (each wave only touches its own 16 rows) so it needs no barrier. Schedule:
//   commit V(t)->Vt[cur] (implicit vmcnt0 drains K(t) gload) ; barrier ;
//   issue K(t+1)->Ks[cur^1] + V(t+1)->regs ; QK^T(Ks[cur]) ; softmax->Ps ;
//   PV(Vt[cur]).
// Race audit: post-barrier(t) all waves are in body t reading only buf[cur];
// prefetch writes buf[cur^1]; a fast wave's commit V(t+1) writes Vt[cur^1].
// LDS 48 KiB -> 3 blocks/CU. XCD remap: 4 (b,h) x 32 blocks per XCD.
// ---------------------------------------------------------------------------
__global__ __launch_bounds__(512) void flash_attn_mfma(
    const bf16* __restrict__ qkv, bf16* __restrict__ O0,
    bf16* __restrict__ O1, float* __restrict__ lb0,
    float* __restrict__ lb1) {
  const int flat = (blockIdx.z * H_ + blockIdx.y) * 32 + blockIdx.x;
  const int g8 = flat & 7, slot = flat >> 3;  // 128 slots per XCD
  const int hf = g8 * 4 + (slot >> 5);        // (b,h) flat 0..31, 4 per XCD
  const int rem = slot & 31;
  const int qb = (rem >> 1) * 128;
  const int half = rem & 1;
  const int h = hf & 15, b = hf >> 4;

  const int tid = threadIdx.x;
  const int lane = tid & 63;
  const int wv = tid >> 6;           // 0..7
  const int quad = lane >> 4;
  const int l16 = lane & 15;

  __shared__ __align__(16) bf16 Ks[2][64][64];  // dbuf, col-swizzled
  __shared__ __align__(16) bf16 Vt[2][64][64];  // [d][j], granule-swizzled
  __shared__ __align__(16) bf16 Ps[128][64];    // per-wave private rows

  const bf16* Qb_ = qkv + (size_t)b * S_ * D3_ + h * DH_;
  const bf16* Kb_ = Qb_ + 1024 + (size_t)half * 1024 * D3_;
  const bf16* Vb_ = Qb_ + 2048 + (size_t)half * 1024 * D3_;

  // Q as B-operand frag: queries qb + wv*16 + l16 (already scaled)
  short8 bq0, bq1;
  {
    const bf16* qrow = Qb_ + (size_t)(qb + wv * 16 + l16) * D3_ + quad * 8;
    bq0 = *(const short8*)(qrow);
    bq1 = *(const short8*)(qrow + 32);
  }

  float l_part = 0.f;
  floatx4 o[4];
#pragma unroll
  for (int fd = 0; fd < 4; fd++) o[fd] = {0.f, 0.f, 0.f, 0.f};

  // P LDS addressing (per-wave private rows, XOR swizzle on byte bits 4-6)
  const int prow = wv * 16 + l16;
  const int psw = (prow & 7) << 4;
  char* pbase = (char*)&Ps[0][0] + prow * 128;

  // K staging: thread covers Ks row tid>>3, slot tid&7 <- src col slot^(row&7)
  const bf16* ksrc =
      Kb_ + (size_t)(tid >> 3) * D3_ + (((tid & 7) ^ ((tid >> 3) & 7)) * 8);
  bf16* kdst = &Ks[0][0][0] + tid * 8;  // + buf*4096
  // V staging: 1 uint4 -> 8 b16 scatters (transpose + granule swizzle)
  const int vj = tid & 63, vd = (tid >> 6) * 8;
  const int vjg = vj >> 3, vjr = vj & 7;

  const int ksw0 = (quad ^ (l16 & 7)) * 8;
  const int ksw1 = ((4 + quad) ^ (l16 & 7)) * 8;

  // prologue: K(0)->Ks[0] gload first, then V(0) reg load (FIFO: waiting on
  // vreg's vmcnt also drains the older K gload)
  gload_lds16(ksrc, kdst);
  uint4 vreg = *(const uint4*)(Vb_ + (size_t)vj * D3_ + vd);

  const int NT = 1024 / 64;  // 16 tiles per half
#pragma unroll 1
  for (int t = 0; t < NT; t++) {
    const int cur = t & 1;
    // commit V(t) -> Vt[cur]; vreg use forces vmcnt(0) -> K(t) gload drained
    {
      bf16 tmp[8];
      *(uint4*)tmp = vreg;
#pragma unroll
      for (int e = 0; e < 8; e++)
        Vt[cur][vd + e][((vjg ^ e) << 3) | vjr] = tmp[e];
    }
    __syncthreads();  // single barrier per tile

    // prefetch tile t+1 into the OTHER buffers (body t only reads buf[cur])
    if (t + 1 < NT) {
      gload_lds16(ksrc + (size_t)(t + 1) * 64 * D3_, kdst + (cur ^ 1) * 4096);
      vreg = *(const uint4*)(Vb_ + (size_t)((t + 1) * 64 + vj) * D3_ + vd);
    }

    // S^T = K Q^T : lane holds keys fk*16 + quad*4 + r for query wv*16+l16
    float st[4][4];
    __builtin_amdgcn_s_setprio(1);
#pragma unroll
    for (int fk = 0; fk < 4; fk++) {
      const bf16* kp = &Ks[cur][fk * 16 + l16][0];
      short8 ak0 = *(const short8*)(kp + ksw0);
      short8 ak1 = *(const short8*)(kp + ksw1);
      floatx4 acc = {0.f, 0.f, 0.f, 0.f};
      acc = __builtin_amdgcn_mfma_f32_16x16x32_bf16(ak0, bq0, acc, 0, 0, 0);
      acc = __builtin_amdgcn_mfma_f32_16x16x32_bf16(ak1, bq1, acc, 0, 0, 0);
#pragma unroll
      for (int r = 0; r < 4; r++) st[fk][r] = acc[r];
    }
    __builtin_amdgcn_s_setprio(0);

    // P = exp2(S^T), interleaved: fk 0,1 first so ap0's deps resolve early
#pragma unroll
    for (int fk = 0; fk < 2; fk++) {
      bf16 pk[4];
#pragma unroll
      for (int r = 0; r < 4; r++) {
        const float p = __builtin_amdgcn_exp2f(st[fk][r]);
        l_part += p;
        pk[r] = __float2bfloat16(p);
      }
      *(uint2*)(pbase + ((fk * 32 + quad * 8) ^ psw)) = *(uint2*)pk;
    }
    short8 ap0 = *(const short8*)(pbase + ((quad * 16) ^ psw));
#pragma unroll
    for (int fk = 2; fk < 4; fk++) {
      bf16 pk[4];
#pragma unroll
      for (int r = 0; r < 4; r++) {
        const float p = __builtin_amdgcn_exp2f(st[fk][r]);
        l_part += p;
        pk[r] = __float2bfloat16(p);
      }
      *(uint2*)(pbase + ((fk * 32 + quad * 8) ^ psw)) = *(uint2*)pk;
    }
    short8 ap1 = *(const short8*)(pbase + ((64 + quad * 16) ^ psw));

    // O += P V (Vt reads use the same granule swizzle as K)
    __builtin_amdgcn_s_setprio(1);
#pragma unroll
    for (int fd = 0; fd < 4; fd++) {
      const bf16* vp = &Vt[cur][fd * 16 + l16][0];
      short8 bv0 = *(const short8*)(vp + ksw0);
      short8 bv1 = *(const short8*)(vp + ksw1);
      o[fd] = __builtin_amdgcn_mfma_f32_16x16x32_bf16(ap0, bv0, o[fd], 0, 0, 0);
      o[fd] = __builtin_amdgcn_mfma_f32_16x16x32_bf16(ap1, bv1, o[fd], 0, 0, 0);
    }
    __builtin_amdgcn_s_setprio(0);
  }

  // l: butterfly over quads -> every lane holds l(q = wv*16 + l16)
  l_part += __shfl_xor(l_part, 16);
  l_part += __shfl_xor(l_part, 32);

  bf16* Oo = half ? O1 : O0;
  float* lo = half ? lb1 : lb0;
  if (quad == 0)
    lo[(size_t)(b * S_ + qb + wv * 16 + l16) * H_ + h] = l_part;
#pragma unroll
  for (int r = 0; r < 4; r++) {
    const size_t base =
        ((size_t)(b * S_ + qb + wv * 16 + quad * 4 + r)) * D_ + h * DH_;
#pragma unroll
    for (int fd = 0; fd < 4; fd++)
      Oo[base + fd * 16 + l16] = __float2bfloat16(o[fd][r]);
  }
}

// ---------------------------------------------------------------------------
extern "C" void kernel_launch(void* const* d_in, const int* in_sizes, int n_in,
                              void* d_out, int out_size, void* d_ws, size_t ws_size,
                              hipStream_t stream) {
  const float* x     = (const float*)d_in[0];
  const float* w_qkv = (const float*)d_in[1];
  const float* w_o   = (const float*)d_in[2];
  const float* w1    = (const float*)d_in[3];
  const float* b1    = (const float*)d_in[4];
  const float* w2    = (const float*)d_in[5];
  const float* b2    = (const float*)d_in[6];
  const float* ln1w  = (const float*)d_in[7];
  const float* ln1b  = (const float*)d_in[8];
  const float* ln2w  = (const float*)d_in[9];
  const float* ln2b  = (const float*)d_in[10];
  float* out = (float*)d_out;
  bf16* ws  = (bf16*)d_ws;

  // workspace layout (bf16 els), liveness re-audited, peak 29,360,128 els.
  // Slots: S1[0,4.19M) S2[4.19,8.39M) S3[8.39,20.97M) S4[20.97,25.17M)
  //        S5[25.17,29.36M). d_out (16.78MB) doubles as flash-partial scratch.
  // S1: h1(LN1->QKV) -> att(combine->oproj) -> g_low rows<1024 (FFN1->FFN2)
  // S2: wqb[4.19,7.34)+wob[7.34,8.39)(cvt->QKV/oproj) -> l0f/l1f(flash->comb)
  //     -> h2(LN2->FFN1) -> Pf0(FFN2->reduce)
  // S3: qkv(QKV->flash) -> Po0+Po1(oproj->LN2) -> g_high rows>=1024(FFN1->FFN2)
  // S4: w2b (QKV-fused cvt -> FFN2)
  // S5: w1b(cvt->FFN1) -> Pf1(FFN2->reduce)
  // d_out: Ob0[0,4.19M)+Ob1[4.19,8.39M) bf16 (flash->combine), then LN2-INIT.
  bf16* h1   = ws;
  bf16* wqb  = ws + 4194304;
  bf16* wob  = ws + 7340032;
  bf16* qkv  = ws + 8388608;
  bf16* w2b  = ws + 20971520;
  bf16* w1b  = ws + 25165824;
  bf16* Ob0  = (bf16*)out;
  bf16* Ob1  = (bf16*)out + 4194304;
  float* l0f = (float*)(ws + 4194304);
  float* l1f = l0f + 65536;
  bf16* att  = ws;                  // S1 (h1 dead after QKV)
  bf16* Po   = ws + 8388608;        // S3: 2 x 4.19M (qkv dead after flash)
  bf16* h2   = ws + 4194304;        // S2 (wqb/wob/l dead by LN2)
  bf16* gl   = ws;                  // S1: g rows 0..1023 (att dead after oproj)
  bf16* gh   = ws + 8388608;        // S3: g rows 1024..4095 (Po dead after LN2)
  bf16* Pf0  = ws + 4194304;        // S2 (h2 dead after FFN1)
  bf16* Pf1  = ws + 25165824;       // S5 (w1b dead after FFN1)

  const float MM_SCALE   = (float)pow((double)S_ * S_ * DH_, -1.0 / 6.0);
  const float SM_SCALE   = (float)((double)S_ / sqrt(1.31 * 1.65));
  const float GELU_SCALE = (float)pow(0.588 * 0.675, -0.5);
  const float SQRT_TAU   = (float)sqrt(0.2);
  const float SQRT_1MT   = (float)sqrt(0.8);
  const float LOG2E      = 1.4426950408889634f;
  const float qkv_scale  = (float)pow((double)D_ * D3_, -0.25);
  const float o_scale    = (float)pow((double)D_ * D_, -0.25);
  const float w1_scale   = (float)pow((double)D_ * DF_, -0.25);
  const float w2_scale   = (float)pow((double)DF_ * D_, -0.25);

  // 1. upfront converts: w_qkv (permuted) + w_o + w1
  cvt_all<<<8192, 256, 0, stream>>>(w_qkv, w_o, w1, wqb, wob, w1b);
  // 2. LN1
  resid_ln_kernel<false, false, float, float><<<BS_, 256, 0, stream>>>(
      x, nullptr, nullptr, ln1w, ln1b, h1, 0.f, 0.f, nullptr, nullptr, 0.f, 0.f);
  // 3. QKV gemm (192 gemm blocks + 64 spare blocks convert w2 -> w2b)
  gemm_mfma256<2, true, bf16><<<dim3(256), 512, 0, stream>>>(
      h1, wqb, qkv, qkv + (size_t)1024 * D3_, BS_, D3_, D_, qkv_scale,
      nullptr, qkv_scale * MM_SCALE * LOG2E, w2, w2b, D_ * DF_ / 4);
  // 4. flash attention, KV-split=2, single-barrier pipeline (1024 blocks)
  flash_attn_mfma<<<dim3(32, H_, B_), 512, 0, stream>>>(
      qkv, Ob0, Ob1, l0f, l1f);
  // 4.5 combine partials -> att (S1)
  combine_attn<<<2048, 256, 0, stream>>>(
      Ob0, Ob1, l0f, l1f, att, SM_SCALE * MM_SCALE);
  // 5. out-proj: 256x128 split-K=2, bf16 raw partials (256 blocks)
  gemm_mfma128<<<dim3(256), 512, 0, stream>>>(
      att, att + (size_t)1024 * D_, wob, Po, Po + (size_t)BS_ * D_,
      BS_, D_, D_ / 2);
  // 6. residual(o_scale*(p0+p1)) + LN2; pre-init out = cs*xv + cb*b2
  resid_ln_kernel<true, true, bf16, float><<<BS_, 256, 0, stream>>>(
      Po, Po + (size_t)BS_ * D_, x, ln2w, ln2b, h2,
      SQRT_TAU * o_scale, SQRT_1MT, out, b2, SQRT_TAU * w2_scale, SQRT_1MT);
  // 7. FFN1 + GELU (256 blocks); C row-split gl/gh
  gemm_mfma256<1, false, bf16><<<dim3(256), 512, 0, stream>>>(
      h2, w1b, gl, gh, BS_, DF_, D_, w1_scale, b1, GELU_SCALE,
      nullptr, nullptr, 0);
  // 8. FFN2: 256x128 split-K=2, A row-split gl/gh, bf16 partials (256 blocks)
  gemm_mfma128<<<dim3(256), 512, 0, stream>>>(
      gl, gh, w2b, Pf0, Pf1, BS_, D_, DF_ / 2);
  // 9. reduce partials into pre-init'd out
  reduce_ffn2<<<2048, 256, 0, stream>>>(Pf0, Pf1, out, SQRT_TAU * w2_scale);
}